// Round 1
// baseline (1994.362 us; speedup 1.0000x reference)
//
#include <hip/hip_runtime.h>
#include <math.h>

#define BB 64
#define SS 512
#define FF 128
#define UU 512
#define NBB 8
#define SIGDIM (FF + FF*FF)   // 16512
#define KSPLIT 43             // 43 * 384 = 16512
#define KCH 384

// ---------------------------------------------------------------------------
// B-spline bases (grid: -1 + 0.4*(i-3), i=0..11; order 3 -> 8 bases)
// ---------------------------------------------------------------------------
__device__ __forceinline__ void bspline8(float x, float* __restrict__ bas) {
    float b0[11], b1[10], b2[9];
#pragma unroll
    for (int i = 0; i < 11; ++i) {
        float g0 = -2.2f + 0.4f * (float)i;
        b0[i] = (x >= g0 && x < g0 + 0.4f) ? 1.0f : 0.0f;
    }
#pragma unroll
    for (int i = 0; i < 10; ++i) {
        float gi = -2.2f + 0.4f * (float)i;
        b1[i] = ((x - gi) * b0[i] + ((gi + 0.8f) - x) * b0[i + 1]) * 2.5f;
    }
#pragma unroll
    for (int i = 0; i < 9; ++i) {
        float gi = -2.2f + 0.4f * (float)i;
        b2[i] = ((x - gi) * b1[i] + ((gi + 1.2f) - x) * b1[i + 1]) * 1.25f;
    }
#pragma unroll
    for (int i = 0; i < 8; ++i) {
        float gi = -2.2f + 0.4f * (float)i;
        bas[i] = ((x - gi) * b2[i] + ((gi + 1.6f) - x) * b2[i + 1]) * (1.0f / 1.2f);
    }
}

__device__ __forceinline__ float sigmoidf(float x) { return 1.0f / (1.0f + expf(-x)); }

// ---------------------------------------------------------------------------
// K1: weighted = time_kernel[s] * inputs   (float4)
// ---------------------------------------------------------------------------
__global__ void k_weighted(const float* __restrict__ inp, const float* __restrict__ tk,
                           float* __restrict__ wout) {
    int i = blockIdx.x * 256 + threadIdx.x;          // over B*S*F/4
    int n4 = BB * SS * FF / 4;
    if (i >= n4) return;
    float4 v = ((const float4*)inp)[i];
    int s = (i / (FF / 4)) % SS;
    float t = tk[s];
    v.x *= t; v.y *= t; v.z *= t; v.w *= t;
    ((float4*)wout)[i] = v;
}

// ---------------------------------------------------------------------------
// K1b: transpose spline_w (U,F*NB) -> (F*NB, U)
// ---------------------------------------------------------------------------
__global__ void k_transpose_w(const float* __restrict__ sw, float* __restrict__ swT) {
    int idx = blockIdx.x * 256 + threadIdx.x;        // over U*F*NB
    if (idx >= UU * FF * NBB) return;
    int u = idx / (FF * NBB);
    int c = idx % (FF * NBB);
    swT[(size_t)c * UU + u] = sw[idx];
}

// ---------------------------------------------------------------------------
// K2a: signature level-2 partials.  a_t = 0.5*(w[t]+w[t+1]) - w[0], d_t = w[t+1]-w[t]
// s2[i][j] = sum_t a_t[i] * d_t[j].  Split t into 4 chunks of 128.
// grid (4 chunks, 64 batches), 256 thr, thread tile 8x8 over (i,j) in 128x128
// ---------------------------------------------------------------------------
__global__ void k_sig_part(const float* __restrict__ weighted, float* __restrict__ s2part) {
    int chunk = blockIdx.x, b = blockIdx.y;
    int tid = threadIdx.x;
    __shared__ float aT[16][128];
    __shared__ float dT[16][128];
    __shared__ float w0s[128];
    const float* wb = weighted + (size_t)b * SS * FF;
    if (tid < 128) w0s[tid] = wb[tid];
    float acc[8][8] = {};
    int i0 = (tid >> 4) * 8, j0 = (tid & 15) * 8;
    for (int t0 = chunk * 128; t0 < chunk * 128 + 128; t0 += 16) {
        __syncthreads();
        for (int e = tid; e < 16 * 128; e += 256) {
            int tt = e >> 7, f = e & 127;
            int t = t0 + tt;
            float av = 0.f, dv = 0.f;
            if (t < SS - 1) {
                float wa = wb[t * FF + f], wc = wb[(t + 1) * FF + f];
                av = 0.5f * (wa + wc) - w0s[f];
                dv = wc - wa;
            }
            aT[tt][f] = av; dT[tt][f] = dv;
        }
        __syncthreads();
#pragma unroll
        for (int kk = 0; kk < 16; ++kk) {
            float a8[8], d8[8];
#pragma unroll
            for (int i = 0; i < 8; ++i) a8[i] = aT[kk][i0 + i];
#pragma unroll
            for (int j = 0; j < 8; ++j) d8[j] = dT[kk][j0 + j];
#pragma unroll
            for (int i = 0; i < 8; ++i)
#pragma unroll
                for (int j = 0; j < 8; ++j) acc[i][j] += a8[i] * d8[j];
        }
    }
    float* outp = s2part + ((size_t)chunk * BB + b) * (FF * FF);
#pragma unroll
    for (int i = 0; i < 8; ++i)
#pragma unroll
        for (int j = 0; j < 8; ++j)
            outp[(i0 + i) * FF + (j0 + j)] = acc[i][j];
}

// ---------------------------------------------------------------------------
// K2b: sig[b, 0:F] = w[S-1]-w[0];  sig[b, F + ij] = sum_c s2part[c][b][ij]
// ---------------------------------------------------------------------------
__global__ void k_sig_reduce(const float* __restrict__ weighted, const float* __restrict__ s2part,
                             float* __restrict__ sig) {
    int idx = blockIdx.x * 256 + threadIdx.x;
    if (idx >= BB * SIGDIM) return;
    int b = idx / SIGDIM, r = idx % SIGDIM;
    if (r < FF) {
        const float* wb = weighted + (size_t)b * SS * FF;
        sig[idx] = wb[(SS - 1) * FF + r] - wb[r];
    } else {
        int ij = r - FF;
        float s = 0.f;
#pragma unroll
        for (int c = 0; c < 4; ++c) s += s2part[((size_t)c * BB + b) * (FF * FF) + ij];
        sig[idx] = s;
    }
}

// ---------------------------------------------------------------------------
// K3: h1_partial / skip_partial = sig (64 x 16512) @ {w1, skip_w} (16512 x 512)
// split-K: grid (43 kchunks, 8 utiles); tile 64b x 64u, thread 4x4
// ---------------------------------------------------------------------------
__global__ void k_gemm_h1skip(const float* __restrict__ sig, const float* __restrict__ w1,
                              const float* __restrict__ skw,
                              float* __restrict__ part1, float* __restrict__ part2) {
    int kc = blockIdx.x;
    int u0 = blockIdx.y * 64;
    int tid = threadIdx.x;
    __shared__ float As[16][64];
    __shared__ float W1s[16][64];
    __shared__ float W2s[16][64];
    float acc1[4][4] = {}, acc2[4][4] = {};
    int tx = tid & 15, ty = tid >> 4;
    int b0 = ty * 4, uu0 = tx * 4;
    for (int t = 0; t < KCH / 16; ++t) {
        int k0 = kc * KCH + t * 16;
        __syncthreads();
        for (int e = tid; e < 1024; e += 256) {
            int b_ = e >> 4, kk = e & 15;
            As[kk][b_] = sig[(size_t)b_ * SIGDIM + k0 + kk];
        }
        for (int e = tid; e < 1024; e += 256) {
            int kk = e >> 6, uu = e & 63;
            W1s[kk][uu] = w1[(size_t)(k0 + kk) * UU + u0 + uu];
            W2s[kk][uu] = skw[(size_t)(k0 + kk) * UU + u0 + uu];
        }
        __syncthreads();
#pragma unroll
        for (int kk = 0; kk < 16; ++kk) {
            float av[4], w1v[4], w2v[4];
#pragma unroll
            for (int i = 0; i < 4; ++i) av[i] = As[kk][b0 + i];
#pragma unroll
            for (int j = 0; j < 4; ++j) { w1v[j] = W1s[kk][uu0 + j]; w2v[j] = W2s[kk][uu0 + j]; }
#pragma unroll
            for (int i = 0; i < 4; ++i)
#pragma unroll
                for (int j = 0; j < 4; ++j) {
                    acc1[i][j] += av[i] * w1v[j];
                    acc2[i][j] += av[i] * w2v[j];
                }
        }
    }
#pragma unroll
    for (int i = 0; i < 4; ++i)
#pragma unroll
        for (int j = 0; j < 4; ++j) {
            size_t o = ((size_t)kc * BB + (b0 + i)) * UU + u0 + uu0 + j;
            part1[o] = acc1[i][j];
            part2[o] = acc2[i][j];
        }
}

// ---------------------------------------------------------------------------
// K3b: reduce split-K, apply bias+elu for h1, pass through skip_pre
// ---------------------------------------------------------------------------
__global__ void k_red3(const float* __restrict__ part1, const float* __restrict__ part2,
                       const float* __restrict__ b1, float* __restrict__ h1,
                       float* __restrict__ skippre) {
    int idx = blockIdx.x * 256 + threadIdx.x;     // B*U
    if (idx >= BB * UU) return;
    int u = idx & (UU - 1);
    float s1 = 0.f, s2 = 0.f;
    for (int kc = 0; kc < KSPLIT; ++kc) {
        s1 += part1[(size_t)kc * BB * UU + idx];
        s2 += part2[(size_t)kc * BB * UU + idx];
    }
    float v = s1 + b1[u];
    h1[idx] = v > 0.f ? v : expf(v) - 1.0f;
    skippre[idx] = s2;
}

// ---------------------------------------------------------------------------
// K4: h2 = h1 @ w2 + b2    (grid 64, 512 thr)
// ---------------------------------------------------------------------------
__global__ void k_h2(const float* __restrict__ h1, const float* __restrict__ w2,
                     const float* __restrict__ b2, float* __restrict__ h2) {
    int b = blockIdx.x, u = threadIdx.x;
    __shared__ float hr[UU];
    hr[u] = h1[(size_t)b * UU + u];
    __syncthreads();
    float s = 0.f;
    for (int k = 0; k < UU; ++k) s += hr[k] * w2[(size_t)k * UU + u];
    h2[(size_t)b * UU + u] = s + b2[u];
}

// ---------------------------------------------------------------------------
// K5: y = skip_pre + skip_b + sigmoid(h2@w3+b3) * (h2@w4+b4)
// ---------------------------------------------------------------------------
__global__ void k_glu_y(const float* __restrict__ h2, const float* __restrict__ w3,
                        const float* __restrict__ b3, const float* __restrict__ w4,
                        const float* __restrict__ b4, const float* __restrict__ skippre,
                        const float* __restrict__ skb, float* __restrict__ yv) {
    int b = blockIdx.x, u = threadIdx.x;
    __shared__ float hr[UU];
    hr[u] = h2[(size_t)b * UU + u];
    __syncthreads();
    float s3 = 0.f, s4 = 0.f;
    for (int k = 0; k < UU; ++k) {
        float h = hr[k];
        s3 += h * w3[(size_t)k * UU + u];
        s4 += h * w4[(size_t)k * UU + u];
    }
    float g = sigmoidf(s3 + b3[u]);
    yv[(size_t)b * UU + u] = skippre[(size_t)b * UU + u] + skb[u] + g * (s4 + b4[u]);
}

// ---------------------------------------------------------------------------
// K6: layernorm (eps 1e-3) + softmax over U -> attn   (grid 64, 512 thr)
// ---------------------------------------------------------------------------
__device__ __forceinline__ float block_sum(float v, float* red) {
    int tid = threadIdx.x;
#pragma unroll
    for (int off = 32; off > 0; off >>= 1) v += __shfl_down(v, off);
    __syncthreads();
    if ((tid & 63) == 0) red[tid >> 6] = v;
    __syncthreads();
    float r = red[0];
#pragma unroll
    for (int i = 1; i < 8; ++i) r += red[i];
    return r;
}
__device__ __forceinline__ float block_max(float v, float* red) {
    int tid = threadIdx.x;
#pragma unroll
    for (int off = 32; off > 0; off >>= 1) v = fmaxf(v, __shfl_down(v, off));
    __syncthreads();
    if ((tid & 63) == 0) red[tid >> 6] = v;
    __syncthreads();
    float r = red[0];
#pragma unroll
    for (int i = 1; i < 8; ++i) r = fmaxf(r, red[i]);
    return r;
}

__global__ void k_lnsm(const float* __restrict__ yv, const float* __restrict__ gamma,
                       const float* __restrict__ beta, float* __restrict__ attn) {
    int b = blockIdx.x, u = threadIdx.x;
    __shared__ float red[8];
    float v = yv[(size_t)b * UU + u];
    float mu = block_sum(v, red) * (1.0f / UU);
    float d = v - mu;
    float var = block_sum(d * d, red) * (1.0f / UU);
    float z = d * rsqrtf(var + 1e-3f) * gamma[u] + beta[u];
    float m = block_max(z, red);
    float e = expf(z - m);
    float Z = block_sum(e, red);
    attn[(size_t)b * UU + u] = e / Z;
}

// ---------------------------------------------------------------------------
// K7: fused KAN linear + attn weighting + partial mean over s.
// kan[n,u] = silu(x[n,:]) @ base_w + bases(x[n,:]) @ wspT
// per block: 64 rows (one batch, 64 consecutive s) x 256 u cols, thread 8x8.
// epilogue: part7[(s_tile)*B+b][u] = sum_rows attn[b,s]*kan[s,u]
// grid (2 utiles, 512 rowtiles), 256 thr
// ---------------------------------------------------------------------------
#define UT 256
__global__ __launch_bounds__(256) void k_kan(const float* __restrict__ weighted,
                                             const float* __restrict__ wspT,
                                             const float* __restrict__ base_w,
                                             const float* __restrict__ attn,
                                             float* __restrict__ part7) {
    int u0 = blockIdx.x * UT;
    int rt = blockIdx.y;
    int b = rt >> 3, s0 = (rt & 7) * 64;
    int tid = threadIdx.x;
    __shared__ float xs[64 * FF];        // raw x tile
    __shared__ float stg[16 * 64];       // bases / silu chunk, [kk][row]
    __shared__ float Wsh[16 * UT];       // weight chunk, [kk][uu]; reused as red[8][UT]

    const float4* wg = (const float4*)(weighted + ((size_t)b * SS + s0) * FF);
    float4* xs4 = (float4*)xs;
    for (int e = tid; e < 64 * FF / 4; e += 256) xs4[e] = wg[e];
    __syncthreads();

    float acc[8][8] = {};
    int tx = tid & 31, ty = tid >> 5;
    int r0 = ty * 8, c0 = tx * 8;

    // phase A: spline branch, K = 1024 in 64 chunks of 16 (2 features each)
    for (int c = 0; c < 64; ++c) {
        if (tid < 128) {
            int row = tid & 63, fl = tid >> 6;
            float bas[8];
            bspline8(xs[row * FF + c * 2 + fl], bas);
#pragma unroll
            for (int k = 0; k < 8; ++k) stg[(fl * 8 + k) * 64 + row] = bas[k];
        }
        for (int e = tid; e < 16 * UT; e += 256) {
            int kk = e >> 8, uu = e & (UT - 1);
            Wsh[kk * UT + uu] = wspT[(size_t)(c * 16 + kk) * UU + u0 + uu];
        }
        __syncthreads();
#pragma unroll
        for (int kk = 0; kk < 16; ++kk) {
            float a8[8], w8[8];
#pragma unroll
            for (int i = 0; i < 8; ++i) a8[i] = stg[kk * 64 + r0 + i];
#pragma unroll
            for (int j = 0; j < 8; ++j) w8[j] = Wsh[kk * UT + c0 + j];
#pragma unroll
            for (int i = 0; i < 8; ++i)
#pragma unroll
                for (int j = 0; j < 8; ++j) acc[i][j] += a8[i] * w8[j];
        }
        __syncthreads();
    }

    // phase B: silu base branch, K = 128 in 8 chunks of 16
    for (int cb = 0; cb < 8; ++cb) {
        for (int e = tid; e < 1024; e += 256) {
            int kk = e >> 6, row = e & 63;
            float x = xs[row * FF + cb * 16 + kk];
            stg[kk * 64 + row] = x * sigmoidf(x);
        }
        for (int e = tid; e < 16 * UT; e += 256) {
            int kk = e >> 8, uu = e & (UT - 1);
            Wsh[kk * UT + uu] = base_w[(size_t)(cb * 16 + kk) * UU + u0 + uu];
        }
        __syncthreads();
#pragma unroll
        for (int kk = 0; kk < 16; ++kk) {
            float a8[8], w8[8];
#pragma unroll
            for (int i = 0; i < 8; ++i) a8[i] = stg[kk * 64 + r0 + i];
#pragma unroll
            for (int j = 0; j < 8; ++j) w8[j] = Wsh[kk * UT + c0 + j];
#pragma unroll
            for (int i = 0; i < 8; ++i)
#pragma unroll
                for (int j = 0; j < 8; ++j) acc[i][j] += a8[i] * w8[j];
        }
        __syncthreads();
    }

    // epilogue: attn-weighted partial sum over this block's 64 rows
    float at[8], part[8];
#pragma unroll
    for (int i = 0; i < 8; ++i) at[i] = attn[(size_t)b * UU + s0 + r0 + i];
#pragma unroll
    for (int j = 0; j < 8; ++j) {
        float s = 0.f;
#pragma unroll
        for (int i = 0; i < 8; ++i) s += at[i] * acc[i][j];
        part[j] = s;
    }
    float* red = Wsh;   // 8 * UT floats
#pragma unroll
    for (int j = 0; j < 8; ++j) red[ty * UT + c0 + j] = part[j];
    __syncthreads();
    float v = 0.f;
#pragma unroll
    for (int t = 0; t < 8; ++t) v += red[t * UT + tid];
    part7[((size_t)(rt & 7) * BB + b) * UU + u0 + tid] = v;
}

// ---------------------------------------------------------------------------
// K8: current = mean partials; LSTM gates; write h_new, c_new
// ---------------------------------------------------------------------------
__global__ void k_lstm(const float* __restrict__ part7, const float* __restrict__ h_prev,
                       const float* __restrict__ c_prev,
                       const float* __restrict__ wf, const float* __restrict__ bf_,
                       const float* __restrict__ wi, const float* __restrict__ bi_,
                       const float* __restrict__ wc, const float* __restrict__ bc_,
                       const float* __restrict__ wo, const float* __restrict__ bo_,
                       float* __restrict__ out) {
    int b = blockIdx.x, u = threadIdx.x;
    __shared__ float comb[2 * UU];
    float cur = 0.f;
#pragma unroll
    for (int r = 0; r < 8; ++r) cur += part7[((size_t)r * BB + b) * UU + u];
    comb[u] = cur * (1.0f / SS);
    comb[u + UU] = h_prev[(size_t)b * UU + u];
    __syncthreads();
    float sf = 0.f, si = 0.f, sc = 0.f, so = 0.f;
    for (int k = 0; k < 2 * UU; ++k) {
        float c = comb[k];
        sf += c * wf[(size_t)k * UU + u];
        si += c * wi[(size_t)k * UU + u];
        sc += c * wc[(size_t)k * UU + u];
        so += c * wo[(size_t)k * UU + u];
    }
    float f = sigmoidf(sf + bf_[u]);
    float ii = sigmoidf(si + bi_[u]);
    float g = tanhf(sc + bc_[u]);
    float o = sigmoidf(so + bo_[u]);
    float cn = f * c_prev[(size_t)b * UU + u] + ii * g;
    out[(size_t)b * UU + u] = o * tanhf(cn);
    out[(size_t)BB * UU + (size_t)b * UU + u] = cn;
}

// ---------------------------------------------------------------------------
extern "C" void kernel_launch(void* const* d_in, const int* in_sizes, int n_in,
                              void* d_out, int out_size, void* d_ws, size_t ws_size,
                              hipStream_t stream) {
    const float* inp   = (const float*)d_in[0];
    const float* hprev = (const float*)d_in[1];
    const float* cprev = (const float*)d_in[2];
    const float* tk    = (const float*)d_in[3];
    const float* basew = (const float*)d_in[4];
    const float* splw  = (const float*)d_in[5];
    const float* gw1   = (const float*)d_in[6];
    const float* gb1   = (const float*)d_in[7];
    const float* gw2   = (const float*)d_in[8];
    const float* gb2   = (const float*)d_in[9];
    const float* gw3   = (const float*)d_in[10];
    const float* gb3   = (const float*)d_in[11];
    const float* gw4   = (const float*)d_in[12];
    const float* gb4   = (const float*)d_in[13];
    const float* gsw   = (const float*)d_in[14];
    const float* gsb   = (const float*)d_in[15];
    const float* lng   = (const float*)d_in[16];
    const float* lnb   = (const float*)d_in[17];
    const float* wf    = (const float*)d_in[18];
    const float* bf_   = (const float*)d_in[19];
    const float* wi    = (const float*)d_in[20];
    const float* bi_   = (const float*)d_in[21];
    const float* wc    = (const float*)d_in[22];
    const float* bc_   = (const float*)d_in[23];
    const float* wo    = (const float*)d_in[24];
    const float* bo_   = (const float*)d_in[25];
    float* out = (float*)d_out;

    float* ws = (float*)d_ws;
    size_t o = 0;
    float* weighted = ws + o; o += (size_t)BB * SS * FF;        // 4,194,304
    float* wspT     = ws + o; o += (size_t)FF * NBB * UU;       //   524,288
    float* s2part   = ws + o; o += (size_t)4 * BB * FF * FF;    // 4,194,304
    float* sig      = ws + o; o += (size_t)BB * SIGDIM;         // 1,056,768
    float* part1    = ws + o; o += (size_t)KSPLIT * BB * UU;    // 1,409,024
    float* part2    = ws + o; o += (size_t)KSPLIT * BB * UU;    // 1,409,024
    float* skippre  = ws + o; o += (size_t)BB * UU;
    float* h1       = ws + o; o += (size_t)BB * UU;
    float* h2      = ws + o; o += (size_t)BB * UU;
    float* yv       = ws + o; o += (size_t)BB * UU;
    float* attn     = ws + o; o += (size_t)BB * UU;
    float* part7    = ws + o; o += (size_t)8 * BB * UU;         //   262,144
    (void)ws_size; (void)in_sizes; (void)n_in; (void)out_size;

    k_weighted<<<(BB * SS * FF / 4 + 255) / 256, 256, 0, stream>>>(inp, tk, weighted);
    k_transpose_w<<<(UU * FF * NBB + 255) / 256, 256, 0, stream>>>(splw, wspT);
    k_sig_part<<<dim3(4, BB), 256, 0, stream>>>(weighted, s2part);
    k_sig_reduce<<<(BB * SIGDIM + 255) / 256, 256, 0, stream>>>(weighted, s2part, sig);
    k_gemm_h1skip<<<dim3(KSPLIT, 8), 256, 0, stream>>>(sig, gw1, gsw, part1, part2);
    k_red3<<<(BB * UU + 255) / 256, 256, 0, stream>>>(part1, part2, gb1, h1, skippre);
    k_h2<<<BB, UU, 0, stream>>>(h1, gw2, gb2, h2);
    k_glu_y<<<BB, UU, 0, stream>>>(h2, gw3, gb3, gw4, gb4, skippre, gsb, yv);
    k_lnsm<<<BB, UU, 0, stream>>>(yv, lng, lnb, attn);
    k_kan<<<dim3(2, (BB * SS) / 64), 256, 0, stream>>>(weighted, wspT, basew, attn, part7);
    k_lstm<<<BB, UU, 0, stream>>>(part7, hprev, cprev, wf, bf_, wi, bi_, wc, bc_, wo, bo_, out);
}

// Round 2
// 815.540 us; speedup vs baseline: 2.4455x; 2.4455x over previous
//
#include <hip/hip_runtime.h>
#include <math.h>

#define BB 64
#define SS 512
#define FF 128
#define UU 512
#define NBB 8
#define SIGDIM (FF + FF*FF)   // 16512
#define KSPLIT 43             // 43 * 384 = 16512
#define KCH 384
#define KK 1152               // 1024 spline + 128 base

typedef __attribute__((ext_vector_type(8))) __bf16 bf16x8;
typedef __attribute__((ext_vector_type(4))) float f32x4;

__device__ __forceinline__ unsigned short f2bf(float x) {
    unsigned int u = __float_as_uint(x);
    unsigned int r = u + 0x7FFFu + ((u >> 16) & 1u);   // RNE
    return (unsigned short)(r >> 16);
}

__device__ __forceinline__ void gload16(const void* g, void* l) {
    __builtin_amdgcn_global_load_lds(
        (const __attribute__((address_space(1))) unsigned int*)g,
        (__attribute__((address_space(3))) unsigned int*)l, 16, 0, 0);
}

// ---------------------------------------------------------------------------
// B-spline bases (grid: -1 + 0.4*(i-3), i=0..11; order 3 -> 8 bases)
// ---------------------------------------------------------------------------
__device__ __forceinline__ void bspline8(float x, float* __restrict__ bas) {
    float b0[11], b1[10], b2[9];
#pragma unroll
    for (int i = 0; i < 11; ++i) {
        float g0 = -2.2f + 0.4f * (float)i;
        b0[i] = (x >= g0 && x < g0 + 0.4f) ? 1.0f : 0.0f;
    }
#pragma unroll
    for (int i = 0; i < 10; ++i) {
        float gi = -2.2f + 0.4f * (float)i;
        b1[i] = ((x - gi) * b0[i] + ((gi + 0.8f) - x) * b0[i + 1]) * 2.5f;
    }
#pragma unroll
    for (int i = 0; i < 9; ++i) {
        float gi = -2.2f + 0.4f * (float)i;
        b2[i] = ((x - gi) * b1[i] + ((gi + 1.2f) - x) * b1[i + 1]) * 1.25f;
    }
#pragma unroll
    for (int i = 0; i < 8; ++i) {
        float gi = -2.2f + 0.4f * (float)i;
        bas[i] = ((x - gi) * b2[i] + ((gi + 1.6f) - x) * b2[i + 1]) * (1.0f / 1.2f);
    }
}

__device__ __forceinline__ float sigmoidf(float x) { return 1.0f / (1.0f + expf(-x)); }

// ---------------------------------------------------------------------------
// K1: weighted (fp32) + Abig (bf16 [32768][1152] = bases | silu)
// 2 rows per block; thread = (n, f)
// ---------------------------------------------------------------------------
__global__ __launch_bounds__(256) void k_gen(const float* __restrict__ inp,
                                             const float* __restrict__ tk,
                                             float* __restrict__ weighted,
                                             unsigned short* __restrict__ Abig) {
    int tid = threadIdx.x;
    int n = blockIdx.x * 2 + (tid >> 7);
    int f = tid & 127;
    int s = n & (SS - 1);
    float w = tk[s] * inp[(size_t)n * FF + f];
    weighted[(size_t)n * FF + f] = w;
    float bas[8];
    bspline8(w, bas);
    unsigned short pk[8];
#pragma unroll
    for (int j = 0; j < 8; ++j) pk[j] = f2bf(bas[j]);
    *(ulonglong2*)(Abig + (size_t)n * KK + f * 8) = *(ulonglong2*)pk;
    Abig[(size_t)n * KK + 1024 + f] = f2bf(w * sigmoidf(w));
}

// ---------------------------------------------------------------------------
// K1b: Wt bf16 [512 u][1152 k] = [splw(u,:,:) flat | base_w^T]
// ---------------------------------------------------------------------------
__global__ void k_wprep(const float* __restrict__ splw, const float* __restrict__ basew,
                        unsigned short* __restrict__ Wt) {
    int idx = blockIdx.x * 256 + threadIdx.x;
    if (idx >= UU * KK) return;
    int u = idx / KK, c = idx % KK;
    float v = (c < 1024) ? splw[(size_t)u * 1024 + c] : basew[(size_t)(c - 1024) * UU + u];
    Wt[idx] = f2bf(v);
}

// ---------------------------------------------------------------------------
// K2a: signature level-2 partials (unchanged)
// ---------------------------------------------------------------------------
__global__ void k_sig_part(const float* __restrict__ weighted, float* __restrict__ s2part) {
    int chunk = blockIdx.x, b = blockIdx.y;
    int tid = threadIdx.x;
    __shared__ float aT[16][128];
    __shared__ float dT[16][128];
    __shared__ float w0s[128];
    const float* wb = weighted + (size_t)b * SS * FF;
    if (tid < 128) w0s[tid] = wb[tid];
    float acc[8][8] = {};
    int i0 = (tid >> 4) * 8, j0 = (tid & 15) * 8;
    for (int t0 = chunk * 128; t0 < chunk * 128 + 128; t0 += 16) {
        __syncthreads();
        for (int e = tid; e < 16 * 128; e += 256) {
            int tt = e >> 7, f = e & 127;
            int t = t0 + tt;
            float av = 0.f, dv = 0.f;
            if (t < SS - 1) {
                float wa = wb[t * FF + f], wc = wb[(t + 1) * FF + f];
                av = 0.5f * (wa + wc) - w0s[f];
                dv = wc - wa;
            }
            aT[tt][f] = av; dT[tt][f] = dv;
        }
        __syncthreads();
#pragma unroll
        for (int kk = 0; kk < 16; ++kk) {
            float a8[8], d8[8];
#pragma unroll
            for (int i = 0; i < 8; ++i) a8[i] = aT[kk][i0 + i];
#pragma unroll
            for (int j = 0; j < 8; ++j) d8[j] = dT[kk][j0 + j];
#pragma unroll
            for (int i = 0; i < 8; ++i)
#pragma unroll
                for (int j = 0; j < 8; ++j) acc[i][j] += a8[i] * d8[j];
        }
    }
    float* outp = s2part + ((size_t)chunk * BB + b) * (FF * FF);
#pragma unroll
    for (int i = 0; i < 8; ++i)
#pragma unroll
        for (int j = 0; j < 8; ++j)
            outp[(i0 + i) * FF + (j0 + j)] = acc[i][j];
}

// ---------------------------------------------------------------------------
// K2b: assemble sig (unchanged)
// ---------------------------------------------------------------------------
__global__ void k_sig_reduce(const float* __restrict__ weighted, const float* __restrict__ s2part,
                             float* __restrict__ sig) {
    int idx = blockIdx.x * 256 + threadIdx.x;
    if (idx >= BB * SIGDIM) return;
    int b = idx / SIGDIM, r = idx % SIGDIM;
    if (r < FF) {
        const float* wb = weighted + (size_t)b * SS * FF;
        sig[idx] = wb[(SS - 1) * FF + r] - wb[r];
    } else {
        int ij = r - FF;
        float s = 0.f;
#pragma unroll
        for (int c = 0; c < 4; ++c) s += s2part[((size_t)c * BB + b) * (FF * FF) + ij];
        sig[idx] = s;
    }
}

// ---------------------------------------------------------------------------
// K3: split-K GEMM for h1/skip (unchanged)
// ---------------------------------------------------------------------------
__global__ void k_gemm_h1skip(const float* __restrict__ sig, const float* __restrict__ w1,
                              const float* __restrict__ skw,
                              float* __restrict__ part1, float* __restrict__ part2) {
    int kc = blockIdx.x;
    int u0 = blockIdx.y * 64;
    int tid = threadIdx.x;
    __shared__ float As[16][64];
    __shared__ float W1s[16][64];
    __shared__ float W2s[16][64];
    float acc1[4][4] = {}, acc2[4][4] = {};
    int tx = tid & 15, ty = tid >> 4;
    int b0 = ty * 4, uu0 = tx * 4;
    for (int t = 0; t < KCH / 16; ++t) {
        int k0 = kc * KCH + t * 16;
        __syncthreads();
        for (int e = tid; e < 1024; e += 256) {
            int b_ = e >> 4, kk = e & 15;
            As[kk][b_] = sig[(size_t)b_ * SIGDIM + k0 + kk];
        }
        for (int e = tid; e < 1024; e += 256) {
            int kk = e >> 6, uu = e & 63;
            W1s[kk][uu] = w1[(size_t)(k0 + kk) * UU + u0 + uu];
            W2s[kk][uu] = skw[(size_t)(k0 + kk) * UU + u0 + uu];
        }
        __syncthreads();
#pragma unroll
        for (int kk = 0; kk < 16; ++kk) {
            float av[4], w1v[4], w2v[4];
#pragma unroll
            for (int i = 0; i < 4; ++i) av[i] = As[kk][b0 + i];
#pragma unroll
            for (int j = 0; j < 4; ++j) { w1v[j] = W1s[kk][uu0 + j]; w2v[j] = W2s[kk][uu0 + j]; }
#pragma unroll
            for (int i = 0; i < 4; ++i)
#pragma unroll
                for (int j = 0; j < 4; ++j) {
                    acc1[i][j] += av[i] * w1v[j];
                    acc2[i][j] += av[i] * w2v[j];
                }
        }
    }
#pragma unroll
    for (int i = 0; i < 4; ++i)
#pragma unroll
        for (int j = 0; j < 4; ++j) {
            size_t o = ((size_t)kc * BB + (b0 + i)) * UU + u0 + uu0 + j;
            part1[o] = acc1[i][j];
            part2[o] = acc2[i][j];
        }
}

__global__ void k_red3(const float* __restrict__ part1, const float* __restrict__ part2,
                       const float* __restrict__ b1, float* __restrict__ h1,
                       float* __restrict__ skippre) {
    int idx = blockIdx.x * 256 + threadIdx.x;
    if (idx >= BB * UU) return;
    int u = idx & (UU - 1);
    float s1 = 0.f, s2 = 0.f;
    for (int kc = 0; kc < KSPLIT; ++kc) {
        s1 += part1[(size_t)kc * BB * UU + idx];
        s2 += part2[(size_t)kc * BB * UU + idx];
    }
    float v = s1 + b1[u];
    h1[idx] = v > 0.f ? v : expf(v) - 1.0f;
    skippre[idx] = s2;
}

__global__ void k_h2(const float* __restrict__ h1, const float* __restrict__ w2,
                     const float* __restrict__ b2, float* __restrict__ h2) {
    int b = blockIdx.x, u = threadIdx.x;
    __shared__ float hr[UU];
    hr[u] = h1[(size_t)b * UU + u];
    __syncthreads();
    float s = 0.f;
    for (int k = 0; k < UU; ++k) s += hr[k] * w2[(size_t)k * UU + u];
    h2[(size_t)b * UU + u] = s + b2[u];
}

__global__ void k_glu_y(const float* __restrict__ h2, const float* __restrict__ w3,
                        const float* __restrict__ b3, const float* __restrict__ w4,
                        const float* __restrict__ b4, const float* __restrict__ skippre,
                        const float* __restrict__ skb, float* __restrict__ yv) {
    int b = blockIdx.x, u = threadIdx.x;
    __shared__ float hr[UU];
    hr[u] = h2[(size_t)b * UU + u];
    __syncthreads();
    float s3 = 0.f, s4 = 0.f;
    for (int k = 0; k < UU; ++k) {
        float h = hr[k];
        s3 += h * w3[(size_t)k * UU + u];
        s4 += h * w4[(size_t)k * UU + u];
    }
    float g = sigmoidf(s3 + b3[u]);
    yv[(size_t)b * UU + u] = skippre[(size_t)b * UU + u] + skb[u] + g * (s4 + b4[u]);
}

__device__ __forceinline__ float block_sum(float v, float* red) {
    int tid = threadIdx.x;
#pragma unroll
    for (int off = 32; off > 0; off >>= 1) v += __shfl_down(v, off);
    __syncthreads();
    if ((tid & 63) == 0) red[tid >> 6] = v;
    __syncthreads();
    float r = red[0];
#pragma unroll
    for (int i = 1; i < 8; ++i) r += red[i];
    return r;
}
__device__ __forceinline__ float block_max(float v, float* red) {
    int tid = threadIdx.x;
#pragma unroll
    for (int off = 32; off > 0; off >>= 1) v = fmaxf(v, __shfl_down(v, off));
    __syncthreads();
    if ((tid & 63) == 0) red[tid >> 6] = v;
    __syncthreads();
    float r = red[0];
#pragma unroll
    for (int i = 1; i < 8; ++i) r = fmaxf(r, red[i]);
    return r;
}

__global__ void k_lnsm(const float* __restrict__ yv, const float* __restrict__ gamma,
                       const float* __restrict__ beta, float* __restrict__ attn) {
    int b = blockIdx.x, u = threadIdx.x;
    __shared__ float red[8];
    float v = yv[(size_t)b * UU + u];
    float mu = block_sum(v, red) * (1.0f / UU);
    float d = v - mu;
    float var = block_sum(d * d, red) * (1.0f / UU);
    float z = d * rsqrtf(var + 1e-3f) * gamma[u] + beta[u];
    float m = block_max(z, red);
    float e = expf(z - m);
    float Z = block_sum(e, red);
    attn[(size_t)b * UU + u] = e / Z;
}

// ---------------------------------------------------------------------------
// K7: bf16 MFMA GEMM: Abig[32768][1152] @ Wt[512][1152]^T, fused attn-weighted
// row reduction.  m97 pattern: 128x128 tile, 16x16x32 MFMA, 4x4 acc/wave,
// global_load_lds width 16, B^T frags via ds_read_b128.
// grid (4 utiles, 256 ntiles), 256 thr.
// ---------------------------------------------------------------------------
__global__ __launch_bounds__(256) void k_kan_mfma(const unsigned short* __restrict__ Abig,
                                                  const unsigned short* __restrict__ Wt,
                                                  const float* __restrict__ attn,
                                                  float* __restrict__ part7) {
    __shared__ short Asm[128 * 32];       // [row][k] 8KB
    __shared__ short Bsm[128 * 32];       // [u][k]   8KB
    __shared__ float attnS[128];
    __shared__ float redS[2][128];
    int tid = threadIdx.x;
    int lane = tid & 63;
    int wv = __builtin_amdgcn_readfirstlane(tid >> 6);
    int u0 = blockIdx.x * 128, n0 = blockIdx.y * 128;
    int b = n0 >> 9, s0 = n0 & (SS - 1);
    if (tid < 128) attnS[tid] = attn[(size_t)b * UU + s0 + tid];

    f32x4 acc[4][4];
#pragma unroll
    for (int i = 0; i < 4; ++i)
#pragma unroll
        for (int j = 0; j < 4; ++j) acc[i][j] = (f32x4)(0.f);

    int wrow = (wv & 1) * 64, wcol = (wv >> 1) * 64;
    const unsigned short* gA = Abig + (size_t)(n0 + wv * 16 + (lane >> 2)) * KK + (lane & 3) * 8;
    const unsigned short* gB = Wt + (size_t)(u0 + wv * 16 + (lane >> 2)) * KK + (lane & 3) * 8;
    char* lA0 = (char*)Asm + wv * 1024;
    char* lB0 = (char*)Bsm + wv * 1024;

    for (int kc = 0; kc < KK / 32; ++kc) {
        int k0 = kc * 32;
        __syncthreads();
        gload16(gA + k0, lA0);
        gload16(gA + (size_t)64 * KK + k0, lA0 + 4096);
        gload16(gB + k0, lB0);
        gload16(gB + (size_t)64 * KK + k0, lB0 + 4096);
        __syncthreads();
        bf16x8 af[4], bf8[4];
#pragma unroll
        for (int rt = 0; rt < 4; ++rt)
            af[rt] = *(const bf16x8*)(Asm + (wrow + rt * 16 + (lane & 15)) * 32 + (lane >> 4) * 8);
#pragma unroll
        for (int ct = 0; ct < 4; ++ct)
            bf8[ct] = *(const bf16x8*)(Bsm + (wcol + ct * 16 + (lane & 15)) * 32 + (lane >> 4) * 8);
#pragma unroll
        for (int rt = 0; rt < 4; ++rt)
#pragma unroll
            for (int ct = 0; ct < 4; ++ct)
                acc[rt][ct] = __builtin_amdgcn_mfma_f32_16x16x32_bf16(af[rt], bf8[ct], acc[rt][ct], 0, 0, 0);
    }

    // epilogue: out[col] = sum_row attnS[row] * C[row][col]; C row = quad*4+reg
    int quad = lane >> 4, col = lane & 15;
#pragma unroll
    for (int ct = 0; ct < 4; ++ct) {
        float p = 0.f;
#pragma unroll
        for (int rt = 0; rt < 4; ++rt)
#pragma unroll
            for (int reg = 0; reg < 4; ++reg)
                p += attnS[wrow + rt * 16 + quad * 4 + reg] * acc[rt][ct][reg];
        p += __shfl_down(p, 32);
        p += __shfl_down(p, 16);
        if (lane < 16) redS[wv & 1][wcol + ct * 16 + col] = p;
    }
    __syncthreads();
    if (tid < 128) {
        int stile = s0 >> 7;
        part7[((size_t)stile * BB + b) * UU + u0 + tid] = redS[0][tid] + redS[1][tid];
    }
}

// ---------------------------------------------------------------------------
// K8: reduce 4 partials; LSTM gates (4-partial version)
// ---------------------------------------------------------------------------
__global__ void k_lstm(const float* __restrict__ part7, const float* __restrict__ h_prev,
                       const float* __restrict__ c_prev,
                       const float* __restrict__ wf, const float* __restrict__ bf_,
                       const float* __restrict__ wi, const float* __restrict__ bi_,
                       const float* __restrict__ wc, const float* __restrict__ bc_,
                       const float* __restrict__ wo, const float* __restrict__ bo_,
                       float* __restrict__ out) {
    int b = blockIdx.x, u = threadIdx.x;
    __shared__ float comb[2 * UU];
    float cur = 0.f;
#pragma unroll
    for (int r = 0; r < 4; ++r) cur += part7[((size_t)r * BB + b) * UU + u];
    comb[u] = cur * (1.0f / SS);
    comb[u + UU] = h_prev[(size_t)b * UU + u];
    __syncthreads();
    float sf = 0.f, si = 0.f, sc = 0.f, so = 0.f;
    for (int k = 0; k < 2 * UU; ++k) {
        float c = comb[k];
        sf += c * wf[(size_t)k * UU + u];
        si += c * wi[(size_t)k * UU + u];
        sc += c * wc[(size_t)k * UU + u];
        so += c * wo[(size_t)k * UU + u];
    }
    float f = sigmoidf(sf + bf_[u]);
    float ii = sigmoidf(si + bi_[u]);
    float g = tanhf(sc + bc_[u]);
    float o = sigmoidf(so + bo_[u]);
    float cn = f * c_prev[(size_t)b * UU + u] + ii * g;
    out[(size_t)b * UU + u] = o * tanhf(cn);
    out[(size_t)BB * UU + (size_t)b * UU + u] = cn;
}

// ---------------------------------------------------------------------------
extern "C" void kernel_launch(void* const* d_in, const int* in_sizes, int n_in,
                              void* d_out, int out_size, void* d_ws, size_t ws_size,
                              hipStream_t stream) {
    const float* inp   = (const float*)d_in[0];
    const float* hprev = (const float*)d_in[1];
    const float* cprev = (const float*)d_in[2];
    const float* tk    = (const float*)d_in[3];
    const float* basew = (const float*)d_in[4];
    const float* splw  = (const float*)d_in[5];
    const float* gw1   = (const float*)d_in[6];
    const float* gb1   = (const float*)d_in[7];
    const float* gw2   = (const float*)d_in[8];
    const float* gb2   = (const float*)d_in[9];
    const float* gw3   = (const float*)d_in[10];
    const float* gb3   = (const float*)d_in[11];
    const float* gw4   = (const float*)d_in[12];
    const float* gb4   = (const float*)d_in[13];
    const float* gsw   = (const float*)d_in[14];
    const float* gsb   = (const float*)d_in[15];
    const float* lng   = (const float*)d_in[16];
    const float* lnb   = (const float*)d_in[17];
    const float* wf    = (const float*)d_in[18];
    const float* bf_   = (const float*)d_in[19];
    const float* wi    = (const float*)d_in[20];
    const float* bi_   = (const float*)d_in[21];
    const float* wc    = (const float*)d_in[22];
    const float* bc_   = (const float*)d_in[23];
    const float* wo    = (const float*)d_in[24];
    const float* bo_   = (const float*)d_in[25];
    float* out = (float*)d_out;

    float* ws = (float*)d_ws;
    size_t o = 0;
    float* weighted      = ws + o; o += (size_t)BB * SS * FF;            // 16.78 MB
    unsigned short* Abig = (unsigned short*)(ws + o); o += (size_t)BB * SS * KK / 2;  // 75.5 MB
    unsigned short* Wt   = (unsigned short*)(ws + o); o += (size_t)UU * KK / 2;       // 1.18 MB
    float* s2part   = ws + o; o += (size_t)4 * BB * FF * FF;
    float* sig      = ws + o; o += (size_t)BB * SIGDIM;
    float* part1    = ws + o; o += (size_t)KSPLIT * BB * UU;
    float* part2    = ws + o; o += (size_t)KSPLIT * BB * UU;
    float* skippre  = ws + o; o += (size_t)BB * UU;
    float* h1       = ws + o; o += (size_t)BB * UU;
    float* h2       = ws + o; o += (size_t)BB * UU;
    float* yv       = ws + o; o += (size_t)BB * UU;
    float* attn     = ws + o; o += (size_t)BB * UU;
    float* part7    = ws + o; o += (size_t)4 * BB * UU;
    (void)ws_size; (void)in_sizes; (void)n_in; (void)out_size;

    k_gen<<<BB * SS / 2, 256, 0, stream>>>(inp, tk, weighted, Abig);
    k_wprep<<<(UU * KK + 255) / 256, 256, 0, stream>>>(splw, basew, Wt);
    k_sig_part<<<dim3(4, BB), 256, 0, stream>>>(weighted, s2part);
    k_sig_reduce<<<(BB * SIGDIM + 255) / 256, 256, 0, stream>>>(weighted, s2part, sig);
    k_gemm_h1skip<<<dim3(KSPLIT, 8), 256, 0, stream>>>(sig, gw1, gsw, part1, part2);
    k_red3<<<(BB * UU + 255) / 256, 256, 0, stream>>>(part1, part2, gb1, h1, skippre);
    k_h2<<<BB, UU, 0, stream>>>(h1, gw2, gb2, h2);
    k_glu_y<<<BB, UU, 0, stream>>>(h2, gw3, gb3, gw4, gb4, skippre, gsb, yv);
    k_lnsm<<<BB, UU, 0, stream>>>(yv, lng, lnb, attn);
    k_kan_mfma<<<dim3(4, 256), 256, 0, stream>>>(Abig, Wt, attn, part7);
    k_lstm<<<BB, UU, 0, stream>>>(part7, hprev, cprev, wf, bf_, wi, bi_, wc, bc_, wo, bo_, out);
}

// Round 3
// 494.065 us; speedup vs baseline: 4.0366x; 1.6507x over previous
//
#include <hip/hip_runtime.h>
#include <math.h>

#define BB 64
#define SS 512
#define FF 128
#define UU 512
#define NBB 8
#define SIGDIM (FF + FF*FF)   // 16512
#define K3 16512              // sig GEMM K
#define KSPLIT 43             // 43 * 384 = 16512
#define KCH 384
#define KK 1152               // KAN GEMM K: 1024 spline + 128 base

typedef __attribute__((ext_vector_type(8))) __bf16 bf16x8;
typedef __attribute__((ext_vector_type(4))) float f32x4;

__device__ __forceinline__ unsigned short f2bf(float x) {
    unsigned int u = __float_as_uint(x);
    unsigned int r = u + 0x7FFFu + ((u >> 16) & 1u);   // RNE
    return (unsigned short)(r >> 16);
}

__device__ __forceinline__ void gload16(const void* g, void* l) {
    __builtin_amdgcn_global_load_lds(
        (const __attribute__((address_space(1))) unsigned int*)g,
        (__attribute__((address_space(3))) unsigned int*)l, 16, 0, 0);
}

// ---------------------------------------------------------------------------
// B-spline bases (grid: -1 + 0.4*(i-3), i=0..11; order 3 -> 8 bases)
// ---------------------------------------------------------------------------
__device__ __forceinline__ void bspline8(float x, float* __restrict__ bas) {
    float b0[11], b1[10], b2[9];
#pragma unroll
    for (int i = 0; i < 11; ++i) {
        float g0 = -2.2f + 0.4f * (float)i;
        b0[i] = (x >= g0 && x < g0 + 0.4f) ? 1.0f : 0.0f;
    }
#pragma unroll
    for (int i = 0; i < 10; ++i) {
        float gi = -2.2f + 0.4f * (float)i;
        b1[i] = ((x - gi) * b0[i] + ((gi + 0.8f) - x) * b0[i + 1]) * 2.5f;
    }
#pragma unroll
    for (int i = 0; i < 9; ++i) {
        float gi = -2.2f + 0.4f * (float)i;
        b2[i] = ((x - gi) * b1[i] + ((gi + 1.2f) - x) * b1[i + 1]) * 1.25f;
    }
#pragma unroll
    for (int i = 0; i < 8; ++i) {
        float gi = -2.2f + 0.4f * (float)i;
        bas[i] = ((x - gi) * b2[i] + ((gi + 1.6f) - x) * b2[i + 1]) * (1.0f / 1.2f);
    }
}

__device__ __forceinline__ float sigmoidf(float x) { return 1.0f / (1.0f + expf(-x)); }

// ---------------------------------------------------------------------------
// K1: weighted (fp32) + Abig (bf16 [32768][1152] = bases | silu)
// ---------------------------------------------------------------------------
__global__ __launch_bounds__(256) void k_gen(const float* __restrict__ inp,
                                             const float* __restrict__ tk,
                                             float* __restrict__ weighted,
                                             unsigned short* __restrict__ Abig) {
    int tid = threadIdx.x;
    int n = blockIdx.x * 2 + (tid >> 7);
    int f = tid & 127;
    int s = n & (SS - 1);
    float w = tk[s] * inp[(size_t)n * FF + f];
    weighted[(size_t)n * FF + f] = w;
    float bas[8];
    bspline8(w, bas);
    unsigned short pk[8];
#pragma unroll
    for (int j = 0; j < 8; ++j) pk[j] = f2bf(bas[j]);
    *(ulonglong2*)(Abig + (size_t)n * KK + f * 8) = *(ulonglong2*)pk;
    Abig[(size_t)n * KK + 1024 + f] = f2bf(w * sigmoidf(w));
}

// ---------------------------------------------------------------------------
// K1b: Wt bf16 [512 u][1152 k] = [splw(u,:,:) flat | base_w^T]
// ---------------------------------------------------------------------------
__global__ void k_wprep(const float* __restrict__ splw, const float* __restrict__ basew,
                        unsigned short* __restrict__ Wt) {
    int idx = blockIdx.x * 256 + threadIdx.x;
    if (idx >= UU * KK) return;
    int u = idx / KK, c = idx % KK;
    float v = (c < 1024) ? splw[(size_t)u * 1024 + c] : basew[(size_t)(c - 1024) * UU + u];
    Wt[idx] = f2bf(v);
}

// ---------------------------------------------------------------------------
// K2a: signature level-2 partials
// ---------------------------------------------------------------------------
__global__ void k_sig_part(const float* __restrict__ weighted, float* __restrict__ s2part) {
    int chunk = blockIdx.x, b = blockIdx.y;
    int tid = threadIdx.x;
    __shared__ float aT[16][128];
    __shared__ float dT[16][128];
    __shared__ float w0s[128];
    const float* wb = weighted + (size_t)b * SS * FF;
    if (tid < 128) w0s[tid] = wb[tid];
    float acc[8][8] = {};
    int i0 = (tid >> 4) * 8, j0 = (tid & 15) * 8;
    for (int t0 = chunk * 128; t0 < chunk * 128 + 128; t0 += 16) {
        __syncthreads();
        for (int e = tid; e < 16 * 128; e += 256) {
            int tt = e >> 7, f = e & 127;
            int t = t0 + tt;
            float av = 0.f, dv = 0.f;
            if (t < SS - 1) {
                float wa = wb[t * FF + f], wc = wb[(t + 1) * FF + f];
                av = 0.5f * (wa + wc) - w0s[f];
                dv = wc - wa;
            }
            aT[tt][f] = av; dT[tt][f] = dv;
        }
        __syncthreads();
#pragma unroll
        for (int kk = 0; kk < 16; ++kk) {
            float a8[8], d8[8];
#pragma unroll
            for (int i = 0; i < 8; ++i) a8[i] = aT[kk][i0 + i];
#pragma unroll
            for (int j = 0; j < 8; ++j) d8[j] = dT[kk][j0 + j];
#pragma unroll
            for (int i = 0; i < 8; ++i)
#pragma unroll
                for (int j = 0; j < 8; ++j) acc[i][j] += a8[i] * d8[j];
        }
    }
    float* outp = s2part + ((size_t)chunk * BB + b) * (FF * FF);
#pragma unroll
    for (int i = 0; i < 8; ++i)
#pragma unroll
        for (int j = 0; j < 8; ++j)
            outp[(i0 + i) * FF + (j0 + j)] = acc[i][j];
}

// ---------------------------------------------------------------------------
// K2b: assemble sig
// ---------------------------------------------------------------------------
__global__ void k_sig_reduce(const float* __restrict__ weighted, const float* __restrict__ s2part,
                             float* __restrict__ sig) {
    int idx = blockIdx.x * 256 + threadIdx.x;
    if (idx >= BB * SIGDIM) return;
    int b = idx / SIGDIM, r = idx % SIGDIM;
    if (r < FF) {
        const float* wb = weighted + (size_t)b * SS * FF;
        sig[idx] = wb[(SS - 1) * FF + r] - wb[r];
    } else {
        int ij = r - FF;
        float s = 0.f;
#pragma unroll
        for (int c = 0; c < 4; ++c) s += s2part[((size_t)c * BB + b) * (FF * FF) + ij];
        sig[idx] = s;
    }
}

// ---------------------------------------------------------------------------
// K2c: sig -> bf16
// ---------------------------------------------------------------------------
__global__ void k_sig2bf(const float* __restrict__ sig, unsigned short* __restrict__ sigb) {
    int i = blockIdx.x * 256 + threadIdx.x;
    if (i >= BB * K3) return;
    sigb[i] = f2bf(sig[i]);
}

// ---------------------------------------------------------------------------
// K2d: transpose w1 / skip_w (16512 x 512 fp32) -> bf16 [512][16512]
// 64x64 tiles via LDS (+1 pad: 2-way bank alias = free)
// ---------------------------------------------------------------------------
__global__ __launch_bounds__(256) void k_wt2(const float* __restrict__ w1,
                                             const float* __restrict__ gsw,
                                             unsigned short* __restrict__ W1t,
                                             unsigned short* __restrict__ Wst) {
    int kt = blockIdx.x, ut = blockIdx.y, mat = blockIdx.z;
    const float* src = mat ? gsw : w1;
    unsigned short* dst = mat ? Wst : W1t;
    __shared__ float tile[64][65];
    int tid = threadIdx.x;
    int k0 = kt * 64, u0 = ut * 64;
#pragma unroll
    for (int p = 0; p < 16; ++p) {
        int e = p * 256 + tid;
        int kk = e >> 6, uu = e & 63;
        tile[kk][uu] = src[(size_t)(k0 + kk) * UU + u0 + uu];
    }
    __syncthreads();
#pragma unroll
    for (int p = 0; p < 16; ++p) {
        int e = p * 256 + tid;
        int uu = e >> 6, kk = e & 63;
        dst[(size_t)(u0 + uu) * K3 + k0 + kk] = f2bf(tile[kk][uu]);
    }
}

// ---------------------------------------------------------------------------
// K3: MFMA split-K GEMM: sigb[64][16512] @ {W1t,Wst}^T -> part1/part2
// grid (43 kchunks, 4 utiles, 2 mats), 256 thr.  64x128 tile, K=384/block.
// ---------------------------------------------------------------------------
__global__ __launch_bounds__(256) void k_gemm_sig_mfma(const unsigned short* __restrict__ sigb,
                                                       const unsigned short* __restrict__ W1t,
                                                       const unsigned short* __restrict__ Wst,
                                                       float* __restrict__ part1,
                                                       float* __restrict__ part2) {
    int kc = blockIdx.x;
    int u0 = blockIdx.y * 128;
    int mat = blockIdx.z;
    const unsigned short* Wt = mat ? Wst : W1t;
    float* dst = mat ? part2 : part1;
    __shared__ short Asm[64 * 32];    // 4 KB
    __shared__ short Bsm[128 * 32];   // 8 KB
    int tid = threadIdx.x, lane = tid & 63;
    int wv = __builtin_amdgcn_readfirstlane(tid >> 6);
    const unsigned short* gA = sigb + (size_t)(wv * 16 + (lane >> 2)) * K3 + (lane & 3) * 8;
    const unsigned short* gB = Wt + (size_t)(u0 + wv * 32 + (lane >> 2)) * K3 + (lane & 3) * 8;
    char* lA = (char*)Asm + wv * 1024;
    char* lB = (char*)Bsm + wv * 2048;
    f32x4 acc[4][2];
#pragma unroll
    for (int i = 0; i < 4; ++i)
#pragma unroll
        for (int j = 0; j < 2; ++j) acc[i][j] = (f32x4)(0.f);
    int wcol = wv * 32;
    for (int t = 0; t < KCH / 32; ++t) {
        int k0 = kc * KCH + t * 32;
        __syncthreads();
        gload16(gA + k0, lA);
        gload16(gB + k0, lB);
        gload16(gB + (size_t)16 * K3 + k0, lB + 1024);
        __syncthreads();
        bf16x8 af[4], bfr[2];
#pragma unroll
        for (int rt = 0; rt < 4; ++rt)
            af[rt] = *(const bf16x8*)(Asm + (rt * 16 + (lane & 15)) * 32 + (lane >> 4) * 8);
#pragma unroll
        for (int ct = 0; ct < 2; ++ct)
            bfr[ct] = *(const bf16x8*)(Bsm + (wcol + ct * 16 + (lane & 15)) * 32 + (lane >> 4) * 8);
#pragma unroll
        for (int rt = 0; rt < 4; ++rt)
#pragma unroll
            for (int ct = 0; ct < 2; ++ct)
                acc[rt][ct] = __builtin_amdgcn_mfma_f32_16x16x32_bf16(af[rt], bfr[ct], acc[rt][ct], 0, 0, 0);
    }
    int quad = lane >> 4, col = lane & 15;
#pragma unroll
    for (int rt = 0; rt < 4; ++rt)
#pragma unroll
        for (int ct = 0; ct < 2; ++ct)
#pragma unroll
            for (int reg = 0; reg < 4; ++reg) {
                int row = rt * 16 + quad * 4 + reg;
                dst[((size_t)kc * BB + row) * UU + u0 + wcol + ct * 16 + col] = acc[rt][ct][reg];
            }
}

// ---------------------------------------------------------------------------
// K3b: reduce split-K, bias+elu for h1, pass skip_pre
// ---------------------------------------------------------------------------
__global__ void k_red3(const float* __restrict__ part1, const float* __restrict__ part2,
                       const float* __restrict__ b1, float* __restrict__ h1,
                       float* __restrict__ skippre) {
    int idx = blockIdx.x * 256 + threadIdx.x;
    if (idx >= BB * UU) return;
    int u = idx & (UU - 1);
    float s1 = 0.f, s2 = 0.f;
    for (int kc = 0; kc < KSPLIT; ++kc) {
        s1 += part1[(size_t)kc * BB * UU + idx];
        s2 += part2[(size_t)kc * BB * UU + idx];
    }
    float v = s1 + b1[u];
    h1[idx] = v > 0.f ? v : expf(v) - 1.0f;
    skippre[idx] = s2;
}

__global__ void k_h2(const float* __restrict__ h1, const float* __restrict__ w2,
                     const float* __restrict__ b2, float* __restrict__ h2) {
    int b = blockIdx.x, u = threadIdx.x;
    __shared__ float hr[UU];
    hr[u] = h1[(size_t)b * UU + u];
    __syncthreads();
    float s = 0.f;
    for (int k = 0; k < UU; ++k) s += hr[k] * w2[(size_t)k * UU + u];
    h2[(size_t)b * UU + u] = s + b2[u];
}

__global__ void k_glu_y(const float* __restrict__ h2, const float* __restrict__ w3,
                        const float* __restrict__ b3, const float* __restrict__ w4,
                        const float* __restrict__ b4, const float* __restrict__ skippre,
                        const float* __restrict__ skb, float* __restrict__ yv) {
    int b = blockIdx.x, u = threadIdx.x;
    __shared__ float hr[UU];
    hr[u] = h2[(size_t)b * UU + u];
    __syncthreads();
    float s3 = 0.f, s4 = 0.f;
    for (int k = 0; k < UU; ++k) {
        float h = hr[k];
        s3 += h * w3[(size_t)k * UU + u];
        s4 += h * w4[(size_t)k * UU + u];
    }
    float g = sigmoidf(s3 + b3[u]);
    yv[(size_t)b * UU + u] = skippre[(size_t)b * UU + u] + skb[u] + g * (s4 + b4[u]);
}

__device__ __forceinline__ float block_sum(float v, float* red) {
    int tid = threadIdx.x;
#pragma unroll
    for (int off = 32; off > 0; off >>= 1) v += __shfl_down(v, off);
    __syncthreads();
    if ((tid & 63) == 0) red[tid >> 6] = v;
    __syncthreads();
    float r = red[0];
#pragma unroll
    for (int i = 1; i < 8; ++i) r += red[i];
    return r;
}
__device__ __forceinline__ float block_max(float v, float* red) {
    int tid = threadIdx.x;
#pragma unroll
    for (int off = 32; off > 0; off >>= 1) v = fmaxf(v, __shfl_down(v, off));
    __syncthreads();
    if ((tid & 63) == 0) red[tid >> 6] = v;
    __syncthreads();
    float r = red[0];
#pragma unroll
    for (int i = 1; i < 8; ++i) r = fmaxf(r, red[i]);
    return r;
}

__global__ void k_lnsm(const float* __restrict__ yv, const float* __restrict__ gamma,
                       const float* __restrict__ beta, float* __restrict__ attn) {
    int b = blockIdx.x, u = threadIdx.x;
    __shared__ float red[8];
    float v = yv[(size_t)b * UU + u];
    float mu = block_sum(v, red) * (1.0f / UU);
    float d = v - mu;
    float var = block_sum(d * d, red) * (1.0f / UU);
    float z = d * rsqrtf(var + 1e-3f) * gamma[u] + beta[u];
    float m = block_max(z, red);
    float e = expf(z - m);
    float Z = block_sum(e, red);
    attn[(size_t)b * UU + u] = e / Z;
}

// ---------------------------------------------------------------------------
// K7: KAN bf16 MFMA GEMM + fused attn-weighted row reduction
// ---------------------------------------------------------------------------
__global__ __launch_bounds__(256) void k_kan_mfma(const unsigned short* __restrict__ Abig,
                                                  const unsigned short* __restrict__ Wt,
                                                  const float* __restrict__ attn,
                                                  float* __restrict__ part7) {
    __shared__ short Asm[128 * 32];
    __shared__ short Bsm[128 * 32];
    __shared__ float attnS[128];
    __shared__ float redS[2][128];
    int tid = threadIdx.x;
    int lane = tid & 63;
    int wv = __builtin_amdgcn_readfirstlane(tid >> 6);
    int u0 = blockIdx.x * 128, n0 = blockIdx.y * 128;
    int b = n0 >> 9, s0 = n0 & (SS - 1);
    if (tid < 128) attnS[tid] = attn[(size_t)b * UU + s0 + tid];

    f32x4 acc[4][4];
#pragma unroll
    for (int i = 0; i < 4; ++i)
#pragma unroll
        for (int j = 0; j < 4; ++j) acc[i][j] = (f32x4)(0.f);

    int wrow = (wv & 1) * 64, wcol = (wv >> 1) * 64;
    const unsigned short* gA = Abig + (size_t)(n0 + wv * 16 + (lane >> 2)) * KK + (lane & 3) * 8;
    const unsigned short* gB = Wt + (size_t)(u0 + wv * 16 + (lane >> 2)) * KK + (lane & 3) * 8;
    char* lA0 = (char*)Asm + wv * 1024;
    char* lB0 = (char*)Bsm + wv * 1024;

    for (int kc = 0; kc < KK / 32; ++kc) {
        int k0 = kc * 32;
        __syncthreads();
        gload16(gA + k0, lA0);
        gload16(gA + (size_t)64 * KK + k0, lA0 + 4096);
        gload16(gB + k0, lB0);
        gload16(gB + (size_t)64 * KK + k0, lB0 + 4096);
        __syncthreads();
        bf16x8 af[4], bf8[4];
#pragma unroll
        for (int rt = 0; rt < 4; ++rt)
            af[rt] = *(const bf16x8*)(Asm + (wrow + rt * 16 + (lane & 15)) * 32 + (lane >> 4) * 8);
#pragma unroll
        for (int ct = 0; ct < 4; ++ct)
            bf8[ct] = *(const bf16x8*)(Bsm + (wcol + ct * 16 + (lane & 15)) * 32 + (lane >> 4) * 8);
#pragma unroll
        for (int rt = 0; rt < 4; ++rt)
#pragma unroll
            for (int ct = 0; ct < 4; ++ct)
                acc[rt][ct] = __builtin_amdgcn_mfma_f32_16x16x32_bf16(af[rt], bf8[ct], acc[rt][ct], 0, 0, 0);
    }

    int quad = lane >> 4, col = lane & 15;
#pragma unroll
    for (int ct = 0; ct < 4; ++ct) {
        float p = 0.f;
#pragma unroll
        for (int rt = 0; rt < 4; ++rt)
#pragma unroll
            for (int reg = 0; reg < 4; ++reg)
                p += attnS[wrow + rt * 16 + quad * 4 + reg] * acc[rt][ct][reg];
        p += __shfl_down(p, 32);
        p += __shfl_down(p, 16);
        if (lane < 16) redS[wv & 1][wcol + ct * 16 + col] = p;
    }
    __syncthreads();
    if (tid < 128) {
        int stile = s0 >> 7;
        part7[((size_t)stile * BB + b) * UU + u0 + tid] = redS[0][tid] + redS[1][tid];
    }
}

// ---------------------------------------------------------------------------
// K8: reduce 4 partials; LSTM gates
// ---------------------------------------------------------------------------
__global__ void k_lstm(const float* __restrict__ part7, const float* __restrict__ h_prev,
                       const float* __restrict__ c_prev,
                       const float* __restrict__ wf, const float* __restrict__ bf_,
                       const float* __restrict__ wi, const float* __restrict__ bi_,
                       const float* __restrict__ wc, const float* __restrict__ bc_,
                       const float* __restrict__ wo, const float* __restrict__ bo_,
                       float* __restrict__ out) {
    int b = blockIdx.x, u = threadIdx.x;
    __shared__ float comb[2 * UU];
    float cur = 0.f;
#pragma unroll
    for (int r = 0; r < 4; ++r) cur += part7[((size_t)r * BB + b) * UU + u];
    comb[u] = cur * (1.0f / SS);
    comb[u + UU] = h_prev[(size_t)b * UU + u];
    __syncthreads();
    float sf = 0.f, si = 0.f, sc = 0.f, so = 0.f;
    for (int k = 0; k < 2 * UU; ++k) {
        float c = comb[k];
        sf += c * wf[(size_t)k * UU + u];
        si += c * wi[(size_t)k * UU + u];
        sc += c * wc[(size_t)k * UU + u];
        so += c * wo[(size_t)k * UU + u];
    }
    float f = sigmoidf(sf + bf_[u]);
    float ii = sigmoidf(si + bi_[u]);
    float g = tanhf(sc + bc_[u]);
    float o = sigmoidf(so + bo_[u]);
    float cn = f * c_prev[(size_t)b * UU + u] + ii * g;
    out[(size_t)b * UU + u] = o * tanhf(cn);
    out[(size_t)BB * UU + (size_t)b * UU + u] = cn;
}

// ---------------------------------------------------------------------------
extern "C" void kernel_launch(void* const* d_in, const int* in_sizes, int n_in,
                              void* d_out, int out_size, void* d_ws, size_t ws_size,
                              hipStream_t stream) {
    const float* inp   = (const float*)d_in[0];
    const float* hprev = (const float*)d_in[1];
    const float* cprev = (const float*)d_in[2];
    const float* tk    = (const float*)d_in[3];
    const float* basew = (const float*)d_in[4];
    const float* splw  = (const float*)d_in[5];
    const float* gw1   = (const float*)d_in[6];
    const float* gb1   = (const float*)d_in[7];
    const float* gw2   = (const float*)d_in[8];
    const float* gb2   = (const float*)d_in[9];
    const float* gw3   = (const float*)d_in[10];
    const float* gb3   = (const float*)d_in[11];
    const float* gw4   = (const float*)d_in[12];
    const float* gb4   = (const float*)d_in[13];
    const float* gsw   = (const float*)d_in[14];
    const float* gsb   = (const float*)d_in[15];
    const float* lng   = (const float*)d_in[16];
    const float* lnb   = (const float*)d_in[17];
    const float* wf    = (const float*)d_in[18];
    const float* bf_   = (const float*)d_in[19];
    const float* wi    = (const float*)d_in[20];
    const float* bi_   = (const float*)d_in[21];
    const float* wc    = (const float*)d_in[22];
    const float* bc_   = (const float*)d_in[23];
    const float* wo    = (const float*)d_in[24];
    const float* bo_   = (const float*)d_in[25];
    float* out = (float*)d_out;

    float* ws = (float*)d_ws;
    size_t o = 0;
    // region A: weighted + s2part + pad; W1t/Wst overlay it after k_sig_reduce
    float* weighted = ws + o;
    unsigned short* W1t = (unsigned short*)weighted;                  // overlays
    o += (size_t)BB * SS * FF;                                        // 16.78 MB
    float* s2part = ws + o; o += (size_t)4 * BB * FF * FF;            // 16.78 MB
    o += 131072;  // 0.5 MB pad so W1t+Wst (33.82 MB) fit in region A
    unsigned short* Wst = W1t + (size_t)UU * K3;
    unsigned short* Abig = (unsigned short*)(ws + o); o += (size_t)BB * SS * KK / 2;
    unsigned short* Wt   = (unsigned short*)(ws + o); o += (size_t)UU * KK / 2;
    float* sig      = ws + o; o += (size_t)BB * SIGDIM;
    unsigned short* sigb = (unsigned short*)(ws + o); o += (size_t)BB * K3 / 2;
    float* part1    = ws + o; o += (size_t)KSPLIT * BB * UU;
    float* part2    = ws + o; o += (size_t)KSPLIT * BB * UU;
    float* skippre  = ws + o; o += (size_t)BB * UU;
    float* h1       = ws + o; o += (size_t)BB * UU;
    float* h2       = ws + o; o += (size_t)BB * UU;
    float* yv       = ws + o; o += (size_t)BB * UU;
    float* attn     = ws + o; o += (size_t)BB * UU;
    float* part7    = ws + o; o += (size_t)4 * BB * UU;
    (void)ws_size; (void)in_sizes; (void)n_in; (void)out_size;

    k_gen<<<BB * SS / 2, 256, 0, stream>>>(inp, tk, weighted, Abig);
    k_wprep<<<(UU * KK + 255) / 256, 256, 0, stream>>>(splw, basew, Wt);
    k_sig_part<<<dim3(4, BB), 256, 0, stream>>>(weighted, s2part);
    k_sig_reduce<<<(BB * SIGDIM + 255) / 256, 256, 0, stream>>>(weighted, s2part, sig);
    k_sig2bf<<<(BB * K3 + 255) / 256, 256, 0, stream>>>(sig, sigb);
    // weighted/s2part dead now; transpose weights into the overlay
    k_wt2<<<dim3(K3 / 64, UU / 64, 2), 256, 0, stream>>>(gw1, gsw, W1t, Wst);
    k_gemm_sig_mfma<<<dim3(KSPLIT, 4, 2), 256, 0, stream>>>(sigb, W1t, Wst, part1, part2);
    k_red3<<<(BB * UU + 255) / 256, 256, 0, stream>>>(part1, part2, gb1, h1, skippre);
    k_h2<<<BB, UU, 0, stream>>>(h1, gw2, gb2, h2);
    k_glu_y<<<BB, UU, 0, stream>>>(h2, gw3, gb3, gw4, gb4, skippre, gsb, yv);
    k_lnsm<<<BB, UU, 0, stream>>>(yv, lng, lnb, attn);
    k_kan_mfma<<<dim3(4, 256), 256, 0, stream>>>(Abig, Wt, attn, part7);
    k_lstm<<<BB, UU, 0, stream>>>(part7, hprev, cprev, wf, bf_, wi, bi_, wc, bc_, wo, bo_, out);
}

// Round 4
// 370.673 us; speedup vs baseline: 5.3804x; 1.3329x over previous
//
#include <hip/hip_runtime.h>
#include <math.h>

#define BB 64
#define SS 512
#define FF 128
#define UU 512
#define NBB 8
#define SIGDIM (FF + FF*FF)   // 16512
#define K3 16512              // sig GEMM K
#define KSPLIT 43             // 43 * 384 = 16512
#define KCH 384
#define KK 1152               // KAN GEMM K: 1024 spline + 128 base

typedef __attribute__((ext_vector_type(8))) __bf16 bf16x8;
typedef __attribute__((ext_vector_type(4))) float f32x4;

__device__ __forceinline__ unsigned short f2bf(float x) {
    unsigned int u = __float_as_uint(x);
    unsigned int r = u + 0x7FFFu + ((u >> 16) & 1u);   // RNE
    return (unsigned short)(r >> 16);
}

__device__ __forceinline__ void gload16(const void* g, void* l) {
    __builtin_amdgcn_global_load_lds(
        (const __attribute__((address_space(1))) unsigned int*)g,
        (__attribute__((address_space(3))) unsigned int*)l, 16, 0, 0);
}

// ---------------------------------------------------------------------------
// B-spline bases (grid: -1 + 0.4*(i-3), i=0..11; order 3 -> 8 bases)
// ---------------------------------------------------------------------------
__device__ __forceinline__ void bspline8(float x, float* __restrict__ bas) {
    float b0[11], b1[10], b2[9];
#pragma unroll
    for (int i = 0; i < 11; ++i) {
        float g0 = -2.2f + 0.4f * (float)i;
        b0[i] = (x >= g0 && x < g0 + 0.4f) ? 1.0f : 0.0f;
    }
#pragma unroll
    for (int i = 0; i < 10; ++i) {
        float gi = -2.2f + 0.4f * (float)i;
        b1[i] = ((x - gi) * b0[i] + ((gi + 0.8f) - x) * b0[i + 1]) * 2.5f;
    }
#pragma unroll
    for (int i = 0; i < 9; ++i) {
        float gi = -2.2f + 0.4f * (float)i;
        b2[i] = ((x - gi) * b1[i] + ((gi + 1.2f) - x) * b1[i + 1]) * 1.25f;
    }
#pragma unroll
    for (int i = 0; i < 8; ++i) {
        float gi = -2.2f + 0.4f * (float)i;
        bas[i] = ((x - gi) * b2[i] + ((gi + 1.6f) - x) * b2[i + 1]) * (1.0f / 1.2f);
    }
}

__device__ __forceinline__ float sigmoidf(float x) { return 1.0f / (1.0f + expf(-x)); }

// ---------------------------------------------------------------------------
// K1: weighted (fp32) + Abig (bf16 [32768][1152] = bases | silu)
// ---------------------------------------------------------------------------
__global__ __launch_bounds__(256) void k_gen(const float* __restrict__ inp,
                                             const float* __restrict__ tk,
                                             float* __restrict__ weighted,
                                             unsigned short* __restrict__ Abig) {
    int tid = threadIdx.x;
    int n = blockIdx.x * 2 + (tid >> 7);
    int f = tid & 127;
    int s = n & (SS - 1);
    float w = tk[s] * inp[(size_t)n * FF + f];
    weighted[(size_t)n * FF + f] = w;
    float bas[8];
    bspline8(w, bas);
    unsigned short pk[8];
#pragma unroll
    for (int j = 0; j < 8; ++j) pk[j] = f2bf(bas[j]);
    *(ulonglong2*)(Abig + (size_t)n * KK + f * 8) = *(ulonglong2*)pk;
    Abig[(size_t)n * KK + 1024 + f] = f2bf(w * sigmoidf(w));
}

// ---------------------------------------------------------------------------
// K1b: Wt bf16 [512 u][1152 k] = [splw(u,:,:) flat | base_w^T]
// ---------------------------------------------------------------------------
__global__ void k_wprep(const float* __restrict__ splw, const float* __restrict__ basew,
                        unsigned short* __restrict__ Wt) {
    int idx = blockIdx.x * 256 + threadIdx.x;
    if (idx >= UU * KK) return;
    int u = idx / KK, c = idx % KK;
    float v = (c < 1024) ? splw[(size_t)u * 1024 + c] : basew[(size_t)(c - 1024) * UU + u];
    Wt[idx] = f2bf(v);
}

// ---------------------------------------------------------------------------
// K2a: signature level-2 partials
// ---------------------------------------------------------------------------
__global__ void k_sig_part(const float* __restrict__ weighted, float* __restrict__ s2part) {
    int chunk = blockIdx.x, b = blockIdx.y;
    int tid = threadIdx.x;
    __shared__ float aT[16][128];
    __shared__ float dT[16][128];
    __shared__ float w0s[128];
    const float* wb = weighted + (size_t)b * SS * FF;
    if (tid < 128) w0s[tid] = wb[tid];
    float acc[8][8] = {};
    int i0 = (tid >> 4) * 8, j0 = (tid & 15) * 8;
    for (int t0 = chunk * 128; t0 < chunk * 128 + 128; t0 += 16) {
        __syncthreads();
        for (int e = tid; e < 16 * 128; e += 256) {
            int tt = e >> 7, f = e & 127;
            int t = t0 + tt;
            float av = 0.f, dv = 0.f;
            if (t < SS - 1) {
                float wa = wb[t * FF + f], wc = wb[(t + 1) * FF + f];
                av = 0.5f * (wa + wc) - w0s[f];
                dv = wc - wa;
            }
            aT[tt][f] = av; dT[tt][f] = dv;
        }
        __syncthreads();
#pragma unroll
        for (int kk = 0; kk < 16; ++kk) {
            float a8[8], d8[8];
#pragma unroll
            for (int i = 0; i < 8; ++i) a8[i] = aT[kk][i0 + i];
#pragma unroll
            for (int j = 0; j < 8; ++j) d8[j] = dT[kk][j0 + j];
#pragma unroll
            for (int i = 0; i < 8; ++i)
#pragma unroll
                for (int j = 0; j < 8; ++j) acc[i][j] += a8[i] * d8[j];
        }
    }
    float* outp = s2part + ((size_t)chunk * BB + b) * (FF * FF);
#pragma unroll
    for (int i = 0; i < 8; ++i)
#pragma unroll
        for (int j = 0; j < 8; ++j)
            outp[(i0 + i) * FF + (j0 + j)] = acc[i][j];
}

// ---------------------------------------------------------------------------
// K2b: assemble sig
// ---------------------------------------------------------------------------
__global__ void k_sig_reduce(const float* __restrict__ weighted, const float* __restrict__ s2part,
                             float* __restrict__ sig) {
    int idx = blockIdx.x * 256 + threadIdx.x;
    if (idx >= BB * SIGDIM) return;
    int b = idx / SIGDIM, r = idx % SIGDIM;
    if (r < FF) {
        const float* wb = weighted + (size_t)b * SS * FF;
        sig[idx] = wb[(SS - 1) * FF + r] - wb[r];
    } else {
        int ij = r - FF;
        float s = 0.f;
#pragma unroll
        for (int c = 0; c < 4; ++c) s += s2part[((size_t)c * BB + b) * (FF * FF) + ij];
        sig[idx] = s;
    }
}

// ---------------------------------------------------------------------------
// K2c: sig -> bf16
// ---------------------------------------------------------------------------
__global__ void k_sig2bf(const float* __restrict__ sig, unsigned short* __restrict__ sigb) {
    int i = blockIdx.x * 256 + threadIdx.x;
    if (i >= BB * K3) return;
    sigb[i] = f2bf(sig[i]);
}

// ---------------------------------------------------------------------------
// K2d: transpose w1 / skip_w (16512 x 512 fp32) -> bf16 [512][16512]
// ---------------------------------------------------------------------------
__global__ __launch_bounds__(256) void k_wt2(const float* __restrict__ w1,
                                             const float* __restrict__ gsw,
                                             unsigned short* __restrict__ W1t,
                                             unsigned short* __restrict__ Wst) {
    int kt = blockIdx.x, ut = blockIdx.y, mat = blockIdx.z;
    const float* src = mat ? gsw : w1;
    unsigned short* dst = mat ? Wst : W1t;
    __shared__ float tile[64][65];
    int tid = threadIdx.x;
    int k0 = kt * 64, u0 = ut * 64;
#pragma unroll
    for (int p = 0; p < 16; ++p) {
        int e = p * 256 + tid;
        int kk = e >> 6, uu = e & 63;
        tile[kk][uu] = src[(size_t)(k0 + kk) * UU + u0 + uu];
    }
    __syncthreads();
#pragma unroll
    for (int p = 0; p < 16; ++p) {
        int e = p * 256 + tid;
        int uu = e >> 6, kk = e & 63;
        dst[(size_t)(u0 + uu) * K3 + k0 + kk] = f2bf(tile[kk][uu]);
    }
}

// ---------------------------------------------------------------------------
// K2e: transpose small weights -> bf16 B^T.
// z=0..2: w2/w3/w4 [512][512] -> W2t/W3t/W4t [512][512]
// z=3..6: wf/wi/wc/wo [1024][512] -> Wgt[(g*512+u)][1024]
// ---------------------------------------------------------------------------
__global__ __launch_bounds__(256) void k_wt3(const float* __restrict__ w2, const float* __restrict__ w3,
                                             const float* __restrict__ w4, const float* __restrict__ wf,
                                             const float* __restrict__ wi, const float* __restrict__ wc,
                                             const float* __restrict__ wo,
                                             unsigned short* __restrict__ W2t,
                                             unsigned short* __restrict__ W3t,
                                             unsigned short* __restrict__ W4t,
                                             unsigned short* __restrict__ Wgt) {
    int kt = blockIdx.x, ut = blockIdx.y, z = blockIdx.z;
    int Kdim = (z < 3) ? 512 : 1024;
    if (kt * 64 >= Kdim) return;
    const float* src;
    unsigned short* dst;
    switch (z) {
        case 0: src = w2; dst = W2t; break;
        case 1: src = w3; dst = W3t; break;
        case 2: src = w4; dst = W4t; break;
        case 3: src = wf; dst = Wgt; break;
        case 4: src = wi; dst = Wgt + (size_t)512 * 1024; break;
        case 5: src = wc; dst = Wgt + (size_t)1024 * 1024; break;
        default: src = wo; dst = Wgt + (size_t)1536 * 1024; break;
    }
    __shared__ float tile[64][65];
    int tid = threadIdx.x;
    int k0 = kt * 64, u0 = ut * 64;
#pragma unroll
    for (int p = 0; p < 16; ++p) {
        int e = p * 256 + tid;
        int kk = e >> 6, uu = e & 63;
        tile[kk][uu] = src[(size_t)(k0 + kk) * UU + u0 + uu];
    }
    __syncthreads();
#pragma unroll
    for (int p = 0; p < 16; ++p) {
        int e = p * 256 + tid;
        int uu = e >> 6, kk = e & 63;
        dst[(size_t)(u0 + uu) * Kdim + k0 + kk] = f2bf(tile[kk][uu]);
    }
}

// ---------------------------------------------------------------------------
// K3: MFMA split-K GEMM: sigb[64][16512] @ {W1t,Wst}^T -> part1/part2
// ---------------------------------------------------------------------------
__global__ __launch_bounds__(256) void k_gemm_sig_mfma(const unsigned short* __restrict__ sigb,
                                                       const unsigned short* __restrict__ W1t,
                                                       const unsigned short* __restrict__ Wst,
                                                       float* __restrict__ part1,
                                                       float* __restrict__ part2) {
    int kc = blockIdx.x;
    int u0 = blockIdx.y * 128;
    int mat = blockIdx.z;
    const unsigned short* Wt = mat ? Wst : W1t;
    float* dst = mat ? part2 : part1;
    __shared__ short Asm[64 * 32];
    __shared__ short Bsm[128 * 32];
    int tid = threadIdx.x, lane = tid & 63;
    int wv = __builtin_amdgcn_readfirstlane(tid >> 6);
    const unsigned short* gA = sigb + (size_t)(wv * 16 + (lane >> 2)) * K3 + (lane & 3) * 8;
    const unsigned short* gB = Wt + (size_t)(u0 + wv * 32 + (lane >> 2)) * K3 + (lane & 3) * 8;
    char* lA = (char*)Asm + wv * 1024;
    char* lB = (char*)Bsm + wv * 2048;
    f32x4 acc[4][2];
#pragma unroll
    for (int i = 0; i < 4; ++i)
#pragma unroll
        for (int j = 0; j < 2; ++j) acc[i][j] = (f32x4)(0.f);
    int wcol = wv * 32;
    for (int t = 0; t < KCH / 32; ++t) {
        int k0 = kc * KCH + t * 32;
        __syncthreads();
        gload16(gA + k0, lA);
        gload16(gB + k0, lB);
        gload16(gB + (size_t)16 * K3 + k0, lB + 1024);
        __syncthreads();
        bf16x8 af[4], bfr[2];
#pragma unroll
        for (int rt = 0; rt < 4; ++rt)
            af[rt] = *(const bf16x8*)(Asm + (rt * 16 + (lane & 15)) * 32 + (lane >> 4) * 8);
#pragma unroll
        for (int ct = 0; ct < 2; ++ct)
            bfr[ct] = *(const bf16x8*)(Bsm + (wcol + ct * 16 + (lane & 15)) * 32 + (lane >> 4) * 8);
#pragma unroll
        for (int rt = 0; rt < 4; ++rt)
#pragma unroll
            for (int ct = 0; ct < 2; ++ct)
                acc[rt][ct] = __builtin_amdgcn_mfma_f32_16x16x32_bf16(af[rt], bfr[ct], acc[rt][ct], 0, 0, 0);
    }
    int quad = lane >> 4, col = lane & 15;
#pragma unroll
    for (int rt = 0; rt < 4; ++rt)
#pragma unroll
        for (int ct = 0; ct < 2; ++ct)
#pragma unroll
            for (int reg = 0; reg < 4; ++reg) {
                int row = rt * 16 + quad * 4 + reg;
                dst[((size_t)kc * BB + row) * UU + u0 + wcol + ct * 16 + col] = acc[rt][ct][reg];
            }
}

// ---------------------------------------------------------------------------
// K3b: reduce split-K, bias+elu -> h1 (bf16), pass skip_pre (fp32)
// ---------------------------------------------------------------------------
__global__ void k_red3(const float* __restrict__ part1, const float* __restrict__ part2,
                       const float* __restrict__ b1, unsigned short* __restrict__ h1b,
                       float* __restrict__ skippre) {
    int idx = blockIdx.x * 256 + threadIdx.x;
    if (idx >= BB * UU) return;
    int u = idx & (UU - 1);
    float s1 = 0.f, s2 = 0.f;
    for (int kc = 0; kc < KSPLIT; ++kc) {
        s1 += part1[(size_t)kc * BB * UU + idx];
        s2 += part2[(size_t)kc * BB * UU + idx];
    }
    float v = s1 + b1[u];
    h1b[idx] = f2bf(v > 0.f ? v : expf(v) - 1.0f);
    skippre[idx] = s2;
}

// ---------------------------------------------------------------------------
// K4: h2 = h1b @ W2t^T + b2 -> bf16.  M=64,N=512,K=512. grid 8, 64x64 tile.
// ---------------------------------------------------------------------------
__global__ __launch_bounds__(256) void k_h2_mfma(const unsigned short* __restrict__ h1b,
                                                 const unsigned short* __restrict__ W2t,
                                                 const float* __restrict__ b2,
                                                 unsigned short* __restrict__ h2b) {
    __shared__ short Asm[64 * 32];
    __shared__ short Bsm[64 * 32];
    int tid = threadIdx.x, lane = tid & 63;
    int wv = __builtin_amdgcn_readfirstlane(tid >> 6);
    int u0 = blockIdx.x * 64;
    const unsigned short* gA = h1b + (size_t)(wv * 16 + (lane >> 2)) * 512 + (lane & 3) * 8;
    const unsigned short* gB = W2t + (size_t)(u0 + wv * 16 + (lane >> 2)) * 512 + (lane & 3) * 8;
    char* lA = (char*)Asm + wv * 1024;
    char* lB = (char*)Bsm + wv * 1024;
    f32x4 acc[4];
#pragma unroll
    for (int i = 0; i < 4; ++i) acc[i] = (f32x4)(0.f);
    int wcol = wv * 16;
    for (int t = 0; t < 16; ++t) {
        int k0 = t * 32;
        __syncthreads();
        gload16(gA + k0, lA);
        gload16(gB + k0, lB);
        __syncthreads();
        bf16x8 bfr = *(const bf16x8*)(Bsm + (wcol + (lane & 15)) * 32 + (lane >> 4) * 8);
#pragma unroll
        for (int rt = 0; rt < 4; ++rt) {
            bf16x8 af = *(const bf16x8*)(Asm + (rt * 16 + (lane & 15)) * 32 + (lane >> 4) * 8);
            acc[rt] = __builtin_amdgcn_mfma_f32_16x16x32_bf16(af, bfr, acc[rt], 0, 0, 0);
        }
    }
    int quad = lane >> 4, col = lane & 15;
    int j = u0 + wcol + col;
#pragma unroll
    for (int rt = 0; rt < 4; ++rt)
#pragma unroll
        for (int reg = 0; reg < 4; ++reg) {
            int row = rt * 16 + quad * 4 + reg;
            h2b[(size_t)row * UU + j] = f2bf(acc[rt][reg] + b2[j]);
        }
}

// ---------------------------------------------------------------------------
// K5: y = skippre + skb + sigmoid(h2@w3+b3)*(h2@w4+b4).  Two B streams.
// ---------------------------------------------------------------------------
__global__ __launch_bounds__(256) void k_glu_mfma(const unsigned short* __restrict__ h2b,
                                                  const unsigned short* __restrict__ W3t,
                                                  const unsigned short* __restrict__ W4t,
                                                  const float* __restrict__ b3,
                                                  const float* __restrict__ b4,
                                                  const float* __restrict__ skippre,
                                                  const float* __restrict__ skb,
                                                  float* __restrict__ yv) {
    __shared__ short Asm[64 * 32];
    __shared__ short B3s[64 * 32];
    __shared__ short B4s[64 * 32];
    int tid = threadIdx.x, lane = tid & 63;
    int wv = __builtin_amdgcn_readfirstlane(tid >> 6);
    int u0 = blockIdx.x * 64;
    const unsigned short* gA = h2b + (size_t)(wv * 16 + (lane >> 2)) * 512 + (lane & 3) * 8;
    const unsigned short* gB3 = W3t + (size_t)(u0 + wv * 16 + (lane >> 2)) * 512 + (lane & 3) * 8;
    const unsigned short* gB4 = W4t + (size_t)(u0 + wv * 16 + (lane >> 2)) * 512 + (lane & 3) * 8;
    char* lA = (char*)Asm + wv * 1024;
    char* lB3 = (char*)B3s + wv * 1024;
    char* lB4 = (char*)B4s + wv * 1024;
    f32x4 acc3[4], acc4[4];
#pragma unroll
    for (int i = 0; i < 4; ++i) { acc3[i] = (f32x4)(0.f); acc4[i] = (f32x4)(0.f); }
    int wcol = wv * 16;
    for (int t = 0; t < 16; ++t) {
        int k0 = t * 32;
        __syncthreads();
        gload16(gA + k0, lA);
        gload16(gB3 + k0, lB3);
        gload16(gB4 + k0, lB4);
        __syncthreads();
        bf16x8 b3f = *(const bf16x8*)(B3s + (wcol + (lane & 15)) * 32 + (lane >> 4) * 8);
        bf16x8 b4f = *(const bf16x8*)(B4s + (wcol + (lane & 15)) * 32 + (lane >> 4) * 8);
#pragma unroll
        for (int rt = 0; rt < 4; ++rt) {
            bf16x8 af = *(const bf16x8*)(Asm + (rt * 16 + (lane & 15)) * 32 + (lane >> 4) * 8);
            acc3[rt] = __builtin_amdgcn_mfma_f32_16x16x32_bf16(af, b3f, acc3[rt], 0, 0, 0);
            acc4[rt] = __builtin_amdgcn_mfma_f32_16x16x32_bf16(af, b4f, acc4[rt], 0, 0, 0);
        }
    }
    int quad = lane >> 4, col = lane & 15;
    int j = u0 + wcol + col;
    float bb3 = b3[j], bb4 = b4[j], sb = skb[j];
#pragma unroll
    for (int rt = 0; rt < 4; ++rt)
#pragma unroll
        for (int reg = 0; reg < 4; ++reg) {
            int row = rt * 16 + quad * 4 + reg;
            float g = sigmoidf(acc3[rt][reg] + bb3);
            yv[(size_t)row * UU + j] = skippre[(size_t)row * UU + j] + sb + g * (acc4[rt][reg] + bb4);
        }
}

__device__ __forceinline__ float block_sum(float v, float* red) {
    int tid = threadIdx.x;
#pragma unroll
    for (int off = 32; off > 0; off >>= 1) v += __shfl_down(v, off);
    __syncthreads();
    if ((tid & 63) == 0) red[tid >> 6] = v;
    __syncthreads();
    float r = red[0];
#pragma unroll
    for (int i = 1; i < 8; ++i) r += red[i];
    return r;
}
__device__ __forceinline__ float block_max(float v, float* red) {
    int tid = threadIdx.x;
#pragma unroll
    for (int off = 32; off > 0; off >>= 1) v = fmaxf(v, __shfl_down(v, off));
    __syncthreads();
    if ((tid & 63) == 0) red[tid >> 6] = v;
    __syncthreads();
    float r = red[0];
#pragma unroll
    for (int i = 1; i < 8; ++i) r = fmaxf(r, red[i]);
    return r;
}

__global__ void k_lnsm(const float* __restrict__ yv, const float* __restrict__ gamma,
                       const float* __restrict__ beta, float* __restrict__ attn) {
    int b = blockIdx.x, u = threadIdx.x;
    __shared__ float red[8];
    float v = yv[(size_t)b * UU + u];
    float mu = block_sum(v, red) * (1.0f / UU);
    float d = v - mu;
    float var = block_sum(d * d, red) * (1.0f / UU);
    float z = d * rsqrtf(var + 1e-3f) * gamma[u] + beta[u];
    float m = block_max(z, red);
    float e = expf(z - m);
    float Z = block_sum(e, red);
    attn[(size_t)b * UU + u] = e / Z;
}

// ---------------------------------------------------------------------------
// K7: KAN bf16 MFMA GEMM + fused attn-weighted row reduction
// ---------------------------------------------------------------------------
__global__ __launch_bounds__(256) void k_kan_mfma(const unsigned short* __restrict__ Abig,
                                                  const unsigned short* __restrict__ Wt,
                                                  const float* __restrict__ attn,
                                                  float* __restrict__ part7) {
    __shared__ short Asm[128 * 32];
    __shared__ short Bsm[128 * 32];
    __shared__ float attnS[128];
    __shared__ float redS[2][128];
    int tid = threadIdx.x;
    int lane = tid & 63;
    int wv = __builtin_amdgcn_readfirstlane(tid >> 6);
    int u0 = blockIdx.x * 128, n0 = blockIdx.y * 128;
    int b = n0 >> 9, s0 = n0 & (SS - 1);
    if (tid < 128) attnS[tid] = attn[(size_t)b * UU + s0 + tid];

    f32x4 acc[4][4];
#pragma unroll
    for (int i = 0; i < 4; ++i)
#pragma unroll
        for (int j = 0; j < 4; ++j) acc[i][j] = (f32x4)(0.f);

    int wrow = (wv & 1) * 64, wcol = (wv >> 1) * 64;
    const unsigned short* gA = Abig + (size_t)(n0 + wv * 16 + (lane >> 2)) * KK + (lane & 3) * 8;
    const unsigned short* gB = Wt + (size_t)(u0 + wv * 16 + (lane >> 2)) * KK + (lane & 3) * 8;
    char* lA0 = (char*)Asm + wv * 1024;
    char* lB0 = (char*)Bsm + wv * 1024;

    for (int kc = 0; kc < KK / 32; ++kc) {
        int k0 = kc * 32;
        __syncthreads();
        gload16(gA + k0, lA0);
        gload16(gA + (size_t)64 * KK + k0, lA0 + 4096);
        gload16(gB + k0, lB0);
        gload16(gB + (size_t)64 * KK + k0, lB0 + 4096);
        __syncthreads();
        bf16x8 af[4], bf8[4];
#pragma unroll
        for (int rt = 0; rt < 4; ++rt)
            af[rt] = *(const bf16x8*)(Asm + (wrow + rt * 16 + (lane & 15)) * 32 + (lane >> 4) * 8);
#pragma unroll
        for (int ct = 0; ct < 4; ++ct)
            bf8[ct] = *(const bf16x8*)(Bsm + (wcol + ct * 16 + (lane & 15)) * 32 + (lane >> 4) * 8);
#pragma unroll
        for (int rt = 0; rt < 4; ++rt)
#pragma unroll
            for (int ct = 0; ct < 4; ++ct)
                acc[rt][ct] = __builtin_amdgcn_mfma_f32_16x16x32_bf16(af[rt], bf8[ct], acc[rt][ct], 0, 0, 0);
    }

    int quad = lane >> 4, col = lane & 15;
#pragma unroll
    for (int ct = 0; ct < 4; ++ct) {
        float p = 0.f;
#pragma unroll
        for (int rt = 0; rt < 4; ++rt)
#pragma unroll
            for (int reg = 0; reg < 4; ++reg)
                p += attnS[wrow + rt * 16 + quad * 4 + reg] * acc[rt][ct][reg];
        p += __shfl_down(p, 32);
        p += __shfl_down(p, 16);
        if (lane < 16) redS[wv & 1][wcol + ct * 16 + col] = p;
    }
    __syncthreads();
    if (tid < 128) {
        int stile = s0 >> 7;
        part7[((size_t)stile * BB + b) * UU + u0 + tid] = redS[0][tid] + redS[1][tid];
    }
}

// ---------------------------------------------------------------------------
// K8a: comb_b[64][1024] bf16 = [mean(part7)/S | h_prev]
// ---------------------------------------------------------------------------
__global__ void k_comb(const float* __restrict__ part7, const float* __restrict__ h_prev,
                       unsigned short* __restrict__ comb_b) {
    int idx = blockIdx.x * 256 + threadIdx.x;
    if (idx >= BB * 1024) return;
    int b = idx >> 10, c = idx & 1023;
    float v;
    if (c < 512) {
        float cur = 0.f;
#pragma unroll
        for (int r = 0; r < 4; ++r) cur += part7[((size_t)r * BB + b) * UU + c];
        v = cur * (1.0f / SS);
    } else {
        v = h_prev[(size_t)b * UU + (c - 512)];
    }
    comb_b[idx] = f2bf(v);
}

// ---------------------------------------------------------------------------
// K8b: gates[64][2048] = comb_b @ Wgt^T.  M=64,N=2048,K=1024. grid 16.
// ---------------------------------------------------------------------------
__global__ __launch_bounds__(256) void k_gates_mfma(const unsigned short* __restrict__ comb_b,
                                                    const unsigned short* __restrict__ Wgt,
                                                    float* __restrict__ gates) {
    __shared__ short Asm[64 * 32];
    __shared__ short Bsm[128 * 32];
    int tid = threadIdx.x, lane = tid & 63;
    int wv = __builtin_amdgcn_readfirstlane(tid >> 6);
    int u0 = blockIdx.x * 128;
    const unsigned short* gA = comb_b + (size_t)(wv * 16 + (lane >> 2)) * 1024 + (lane & 3) * 8;
    const unsigned short* gB = Wgt + (size_t)(u0 + wv * 32 + (lane >> 2)) * 1024 + (lane & 3) * 8;
    char* lA = (char*)Asm + wv * 1024;
    char* lB = (char*)Bsm + wv * 2048;
    f32x4 acc[4][2];
#pragma unroll
    for (int i = 0; i < 4; ++i)
#pragma unroll
        for (int j = 0; j < 2; ++j) acc[i][j] = (f32x4)(0.f);
    int wcol = wv * 32;
    for (int t = 0; t < 32; ++t) {
        int k0 = t * 32;
        __syncthreads();
        gload16(gA + k0, lA);
        gload16(gB + k0, lB);
        gload16(gB + (size_t)16 * 1024 + k0, lB + 1024);
        __syncthreads();
        bf16x8 af[4], bfr[2];
#pragma unroll
        for (int rt = 0; rt < 4; ++rt)
            af[rt] = *(const bf16x8*)(Asm + (rt * 16 + (lane & 15)) * 32 + (lane >> 4) * 8);
#pragma unroll
        for (int ct = 0; ct < 2; ++ct)
            bfr[ct] = *(const bf16x8*)(Bsm + (wcol + ct * 16 + (lane & 15)) * 32 + (lane >> 4) * 8);
#pragma unroll
        for (int rt = 0; rt < 4; ++rt)
#pragma unroll
            for (int ct = 0; ct < 2; ++ct)
                acc[rt][ct] = __builtin_amdgcn_mfma_f32_16x16x32_bf16(af[rt], bfr[ct], acc[rt][ct], 0, 0, 0);
    }
    int quad = lane >> 4, col = lane & 15;
#pragma unroll
    for (int rt = 0; rt < 4; ++rt)
#pragma unroll
        for (int ct = 0; ct < 2; ++ct)
#pragma unroll
            for (int reg = 0; reg < 4; ++reg) {
                int row = rt * 16 + quad * 4 + reg;
                gates[(size_t)row * 2048 + u0 + wcol + ct * 16 + col] = acc[rt][ct][reg];
            }
}

// ---------------------------------------------------------------------------
// K8c: elementwise cell update
// ---------------------------------------------------------------------------
__global__ void k_cell(const float* __restrict__ gates,
                       const float* __restrict__ bf_, const float* __restrict__ bi_,
                       const float* __restrict__ bc_, const float* __restrict__ bo_,
                       const float* __restrict__ c_prev, float* __restrict__ out) {
    int idx = blockIdx.x * 256 + threadIdx.x;
    if (idx >= BB * UU) return;
    int b = idx >> 9, u = idx & 511;
    const float* g = gates + (size_t)b * 2048;
    float f = sigmoidf(g[u] + bf_[u]);
    float ii = sigmoidf(g[512 + u] + bi_[u]);
    float cd = tanhf(g[1024 + u] + bc_[u]);
    float o = sigmoidf(g[1536 + u] + bo_[u]);
    float cn = f * c_prev[idx] + ii * cd;
    out[idx] = o * tanhf(cn);
    out[(size_t)BB * UU + idx] = cn;
}

// ---------------------------------------------------------------------------
extern "C" void kernel_launch(void* const* d_in, const int* in_sizes, int n_in,
                              void* d_out, int out_size, void* d_ws, size_t ws_size,
                              hipStream_t stream) {
    const float* inp   = (const float*)d_in[0];
    const float* hprev = (const float*)d_in[1];
    const float* cprev = (const float*)d_in[2];
    const float* tk    = (const float*)d_in[3];
    const float* basew = (const float*)d_in[4];
    const float* splw  = (const float*)d_in[5];
    const float* gw1   = (const float*)d_in[6];
    const float* gb1   = (const float*)d_in[7];
    const float* gw2   = (const float*)d_in[8];
    const float* gb2   = (const float*)d_in[9];
    const float* gw3   = (const float*)d_in[10];
    const float* gb3   = (const float*)d_in[11];
    const float* gw4   = (const float*)d_in[12];
    const float* gb4   = (const float*)d_in[13];
    const float* gsw   = (const float*)d_in[14];
    const float* gsb   = (const float*)d_in[15];
    const float* lng   = (const float*)d_in[16];
    const float* lnb   = (const float*)d_in[17];
    const float* wf    = (const float*)d_in[18];
    const float* bf_   = (const float*)d_in[19];
    const float* wi    = (const float*)d_in[20];
    const float* bi_   = (const float*)d_in[21];
    const float* wc    = (const float*)d_in[22];
    const float* bc_   = (const float*)d_in[23];
    const float* wo    = (const float*)d_in[24];
    const float* bo_   = (const float*)d_in[25];
    float* out = (float*)d_out;

    float* ws = (float*)d_ws;
    size_t o = 0;
    // region A: weighted + s2part + pad; W1t/Wst overlay it after k_sig_reduce
    float* weighted = ws + o;
    unsigned short* W1t = (unsigned short*)weighted;                  // overlays
    o += (size_t)BB * SS * FF;                                        // 16.78 MB
    float* s2part = ws + o; o += (size_t)4 * BB * FF * FF;            // 16.78 MB
    o += 131072;  // pad so W1t+Wst (33.82 MB) fit in region A
    unsigned short* Wst = W1t + (size_t)UU * K3;
    unsigned short* Abig = (unsigned short*)(ws + o); o += (size_t)BB * SS * KK / 2;
    unsigned short* Wt   = (unsigned short*)(ws + o); o += (size_t)UU * KK / 2;
    float* sig      = ws + o; o += (size_t)BB * SIGDIM;
    unsigned short* sigb = (unsigned short*)(ws + o); o += (size_t)BB * K3 / 2;
    float* part1    = ws + o; o += (size_t)KSPLIT * BB * UU;
    float* part2    = ws + o; o += (size_t)KSPLIT * BB * UU;
    float* skippre  = ws + o; o += (size_t)BB * UU;
    unsigned short* h1b = (unsigned short*)(ws + o); o += (size_t)BB * UU / 2;
    unsigned short* h2b = (unsigned short*)(ws + o); o += (size_t)BB * UU / 2;
    float* yv       = ws + o; o += (size_t)BB * UU;
    float* attn     = ws + o; o += (size_t)BB * UU;
    float* part7    = ws + o; o += (size_t)4 * BB * UU;
    unsigned short* W2t = (unsigned short*)(ws + o); o += (size_t)UU * 512 / 2;
    unsigned short* W3t = (unsigned short*)(ws + o); o += (size_t)UU * 512 / 2;
    unsigned short* W4t = (unsigned short*)(ws + o); o += (size_t)UU * 512 / 2;
    unsigned short* Wgt = (unsigned short*)(ws + o); o += (size_t)2048 * 1024 / 2;
    unsigned short* comb_b = (unsigned short*)(ws + o); o += (size_t)BB * 1024 / 2;
    float* gates    = ws + o; o += (size_t)BB * 2048;
    (void)ws_size; (void)in_sizes; (void)n_in; (void)out_size;

    k_gen<<<BB * SS / 2, 256, 0, stream>>>(inp, tk, weighted, Abig);
    k_wprep<<<(UU * KK + 255) / 256, 256, 0, stream>>>(splw, basew, Wt);
    k_wt3<<<dim3(16, 8, 7), 256, 0, stream>>>(gw2, gw3, gw4, wf, wi, wc, wo, W2t, W3t, W4t, Wgt);
    k_sig_part<<<dim3(4, BB), 256, 0, stream>>>(weighted, s2part);
    k_sig_reduce<<<(BB * SIGDIM + 255) / 256, 256, 0, stream>>>(weighted, s2part, sig);
    k_sig2bf<<<(BB * K3 + 255) / 256, 256, 0, stream>>>(sig, sigb);
    k_wt2<<<dim3(K3 / 64, UU / 64, 2), 256, 0, stream>>>(gw1, gsw, W1t, Wst);
    k_gemm_sig_mfma<<<dim3(KSPLIT, 4, 2), 256, 0, stream>>>(sigb, W1t, Wst, part1, part2);
    k_red3<<<(BB * UU + 255) / 256, 256, 0, stream>>>(part1, part2, gb1, h1b, skippre);
    k_h2_mfma<<<8, 256, 0, stream>>>(h1b, W2t, gb2, h2b);
    k_glu_mfma<<<8, 256, 0, stream>>>(h2b, W3t, W4t, gb3, gb4, skippre, gsb, yv);
    k_lnsm<<<BB, UU, 0, stream>>>(yv, lng, lnb, attn);
    k_kan_mfma<<<dim3(4, 256), 256, 0, stream>>>(Abig, Wt, attn, part7);
    k_comb<<<(BB * 1024 + 255) / 256, 256, 0, stream>>>(part7, hprev, comb_b);
    k_gates_mfma<<<16, 256, 0, stream>>>(comb_b, Wgt, gates);
    k_cell<<<(BB * UU + 255) / 256, 256, 0, stream>>>(gates, bf_, bi_, bc_, bo_, cprev, out);
}

// Round 5
// 360.320 us; speedup vs baseline: 5.5350x; 1.0287x over previous
//
#include <hip/hip_runtime.h>
#include <math.h>

#define BB 64
#define SS 512
#define FF 128
#define UU 512
#define NBB 8
#define SIGDIM (FF + FF*FF)   // 16512
#define K3 16512              // sig GEMM K
#define KSPLIT 43             // 43 * 384 = 16512
#define KCH 384
#define KK 1152               // KAN GEMM K: 1024 spline + 128 base

typedef __attribute__((ext_vector_type(8))) __bf16 bf16x8;
typedef __attribute__((ext_vector_type(4))) float f32x4;

__device__ __forceinline__ unsigned short f2bf(float x) {
    unsigned int u = __float_as_uint(x);
    unsigned int r = u + 0x7FFFu + ((u >> 16) & 1u);   // RNE
    return (unsigned short)(r >> 16);
}

__device__ __forceinline__ void gload16(const void* g, void* l) {
    __builtin_amdgcn_global_load_lds(
        (const __attribute__((address_space(1))) unsigned int*)g,
        (__attribute__((address_space(3))) unsigned int*)l, 16, 0, 0);
}

// ---------------------------------------------------------------------------
// B-spline bases (grid: -1 + 0.4*(i-3), i=0..11; order 3 -> 8 bases)
// ---------------------------------------------------------------------------
__device__ __forceinline__ void bspline8(float x, float* __restrict__ bas) {
    float b0[11], b1[10], b2[9];
#pragma unroll
    for (int i = 0; i < 11; ++i) {
        float g0 = -2.2f + 0.4f * (float)i;
        b0[i] = (x >= g0 && x < g0 + 0.4f) ? 1.0f : 0.0f;
    }
#pragma unroll
    for (int i = 0; i < 10; ++i) {
        float gi = -2.2f + 0.4f * (float)i;
        b1[i] = ((x - gi) * b0[i] + ((gi + 0.8f) - x) * b0[i + 1]) * 2.5f;
    }
#pragma unroll
    for (int i = 0; i < 9; ++i) {
        float gi = -2.2f + 0.4f * (float)i;
        b2[i] = ((x - gi) * b1[i] + ((gi + 1.2f) - x) * b1[i + 1]) * 1.25f;
    }
#pragma unroll
    for (int i = 0; i < 8; ++i) {
        float gi = -2.2f + 0.4f * (float)i;
        bas[i] = ((x - gi) * b2[i] + ((gi + 1.6f) - x) * b2[i + 1]) * (1.0f / 1.2f);
    }
}

__device__ __forceinline__ float sigmoidf(float x) { return 1.0f / (1.0f + expf(-x)); }

// ---------------------------------------------------------------------------
// K1: weighted = time_kernel[s] * inputs   (float4)
// ---------------------------------------------------------------------------
__global__ void k_weighted(const float* __restrict__ inp, const float* __restrict__ tk,
                           float* __restrict__ wout) {
    int i = blockIdx.x * 256 + threadIdx.x;
    int n4 = BB * SS * FF / 4;
    if (i >= n4) return;
    float4 v = ((const float4*)inp)[i];
    int s = (i / (FF / 4)) % SS;
    float t = tk[s];
    v.x *= t; v.y *= t; v.z *= t; v.w *= t;
    ((float4*)wout)[i] = v;
}

// ---------------------------------------------------------------------------
// K1b: Wt bf16 [512 u][1152 k] = [splw(u,:,:) flat | base_w^T]
// ---------------------------------------------------------------------------
__global__ void k_wprep(const float* __restrict__ splw, const float* __restrict__ basew,
                        unsigned short* __restrict__ Wt) {
    int idx = blockIdx.x * 256 + threadIdx.x;
    if (idx >= UU * KK) return;
    int u = idx / KK, c = idx % KK;
    float v = (c < 1024) ? splw[(size_t)u * 1024 + c] : basew[(size_t)(c - 1024) * UU + u];
    Wt[idx] = f2bf(v);
}

// ---------------------------------------------------------------------------
// K2a: signature level-2 partials
// ---------------------------------------------------------------------------
__global__ void k_sig_part(const float* __restrict__ weighted, float* __restrict__ s2part) {
    int chunk = blockIdx.x, b = blockIdx.y;
    int tid = threadIdx.x;
    __shared__ float aT[16][128];
    __shared__ float dT[16][128];
    __shared__ float w0s[128];
    const float* wb = weighted + (size_t)b * SS * FF;
    if (tid < 128) w0s[tid] = wb[tid];
    float acc[8][8] = {};
    int i0 = (tid >> 4) * 8, j0 = (tid & 15) * 8;
    for (int t0 = chunk * 128; t0 < chunk * 128 + 128; t0 += 16) {
        __syncthreads();
        for (int e = tid; e < 16 * 128; e += 256) {
            int tt = e >> 7, f = e & 127;
            int t = t0 + tt;
            float av = 0.f, dv = 0.f;
            if (t < SS - 1) {
                float wa = wb[t * FF + f], wc = wb[(t + 1) * FF + f];
                av = 0.5f * (wa + wc) - w0s[f];
                dv = wc - wa;
            }
            aT[tt][f] = av; dT[tt][f] = dv;
        }
        __syncthreads();
#pragma unroll
        for (int kk = 0; kk < 16; ++kk) {
            float a8[8], d8[8];
#pragma unroll
            for (int i = 0; i < 8; ++i) a8[i] = aT[kk][i0 + i];
#pragma unroll
            for (int j = 0; j < 8; ++j) d8[j] = dT[kk][j0 + j];
#pragma unroll
            for (int i = 0; i < 8; ++i)
#pragma unroll
                for (int j = 0; j < 8; ++j) acc[i][j] += a8[i] * d8[j];
        }
    }
    float* outp = s2part + ((size_t)chunk * BB + b) * (FF * FF);
#pragma unroll
    for (int i = 0; i < 8; ++i)
#pragma unroll
        for (int j = 0; j < 8; ++j)
            outp[(i0 + i) * FF + (j0 + j)] = acc[i][j];
}

// ---------------------------------------------------------------------------
// K2b: assemble sig
// ---------------------------------------------------------------------------
__global__ void k_sig_reduce(const float* __restrict__ weighted, const float* __restrict__ s2part,
                             float* __restrict__ sig) {
    int idx = blockIdx.x * 256 + threadIdx.x;
    if (idx >= BB * SIGDIM) return;
    int b = idx / SIGDIM, r = idx % SIGDIM;
    if (r < FF) {
        const float* wb = weighted + (size_t)b * SS * FF;
        sig[idx] = wb[(SS - 1) * FF + r] - wb[r];
    } else {
        int ij = r - FF;
        float s = 0.f;
#pragma unroll
        for (int c = 0; c < 4; ++c) s += s2part[((size_t)c * BB + b) * (FF * FF) + ij];
        sig[idx] = s;
    }
}

// ---------------------------------------------------------------------------
// K2c: sig -> bf16
// ---------------------------------------------------------------------------
__global__ void k_sig2bf(const float* __restrict__ sig, unsigned short* __restrict__ sigb) {
    int i = blockIdx.x * 256 + threadIdx.x;
    if (i >= BB * K3) return;
    sigb[i] = f2bf(sig[i]);
}

// ---------------------------------------------------------------------------
// K2d: transpose w1 / skip_w (16512 x 512 fp32) -> bf16 [512][16512]
// ---------------------------------------------------------------------------
__global__ __launch_bounds__(256) void k_wt2(const float* __restrict__ w1,
                                             const float* __restrict__ gsw,
                                             unsigned short* __restrict__ W1t,
                                             unsigned short* __restrict__ Wst) {
    int kt = blockIdx.x, ut = blockIdx.y, mat = blockIdx.z;
    const float* src = mat ? gsw : w1;
    unsigned short* dst = mat ? Wst : W1t;
    __shared__ float tile[64][65];
    int tid = threadIdx.x;
    int k0 = kt * 64, u0 = ut * 64;
#pragma unroll
    for (int p = 0; p < 16; ++p) {
        int e = p * 256 + tid;
        int kk = e >> 6, uu = e & 63;
        tile[kk][uu] = src[(size_t)(k0 + kk) * UU + u0 + uu];
    }
    __syncthreads();
#pragma unroll
    for (int p = 0; p < 16; ++p) {
        int e = p * 256 + tid;
        int uu = e >> 6, kk = e & 63;
        dst[(size_t)(u0 + uu) * K3 + k0 + kk] = f2bf(tile[kk][uu]);
    }
}

// ---------------------------------------------------------------------------
// K2e: transpose small weights -> bf16 B^T.
// ---------------------------------------------------------------------------
__global__ __launch_bounds__(256) void k_wt3(const float* __restrict__ w2, const float* __restrict__ w3,
                                             const float* __restrict__ w4, const float* __restrict__ wf,
                                             const float* __restrict__ wi, const float* __restrict__ wc,
                                             const float* __restrict__ wo,
                                             unsigned short* __restrict__ W2t,
                                             unsigned short* __restrict__ W3t,
                                             unsigned short* __restrict__ W4t,
                                             unsigned short* __restrict__ Wgt) {
    int kt = blockIdx.x, ut = blockIdx.y, z = blockIdx.z;
    int Kdim = (z < 3) ? 512 : 1024;
    if (kt * 64 >= Kdim) return;
    const float* src;
    unsigned short* dst;
    switch (z) {
        case 0: src = w2; dst = W2t; break;
        case 1: src = w3; dst = W3t; break;
        case 2: src = w4; dst = W4t; break;
        case 3: src = wf; dst = Wgt; break;
        case 4: src = wi; dst = Wgt + (size_t)512 * 1024; break;
        case 5: src = wc; dst = Wgt + (size_t)1024 * 1024; break;
        default: src = wo; dst = Wgt + (size_t)1536 * 1024; break;
    }
    __shared__ float tile[64][65];
    int tid = threadIdx.x;
    int k0 = kt * 64, u0 = ut * 64;
#pragma unroll
    for (int p = 0; p < 16; ++p) {
        int e = p * 256 + tid;
        int kk = e >> 6, uu = e & 63;
        tile[kk][uu] = src[(size_t)(k0 + kk) * UU + u0 + uu];
    }
    __syncthreads();
#pragma unroll
    for (int p = 0; p < 16; ++p) {
        int e = p * 256 + tid;
        int uu = e >> 6, kk = e & 63;
        dst[(size_t)(u0 + uu) * Kdim + k0 + kk] = f2bf(tile[kk][uu]);
    }
}

// ---------------------------------------------------------------------------
// K3: MFMA split-K GEMM: sigb[64][16512] @ {W1t,Wst}^T -> part1/part2
// ---------------------------------------------------------------------------
__global__ __launch_bounds__(256) void k_gemm_sig_mfma(const unsigned short* __restrict__ sigb,
                                                       const unsigned short* __restrict__ W1t,
                                                       const unsigned short* __restrict__ Wst,
                                                       float* __restrict__ part1,
                                                       float* __restrict__ part2) {
    int kc = blockIdx.x;
    int u0 = blockIdx.y * 128;
    int mat = blockIdx.z;
    const unsigned short* Wt = mat ? Wst : W1t;
    float* dst = mat ? part2 : part1;
    __shared__ short Asm[64 * 32];
    __shared__ short Bsm[128 * 32];
    int tid = threadIdx.x, lane = tid & 63;
    int wv = __builtin_amdgcn_readfirstlane(tid >> 6);
    const unsigned short* gA = sigb + (size_t)(wv * 16 + (lane >> 2)) * K3 + (lane & 3) * 8;
    const unsigned short* gB = Wt + (size_t)(u0 + wv * 32 + (lane >> 2)) * K3 + (lane & 3) * 8;
    char* lA = (char*)Asm + wv * 1024;
    char* lB = (char*)Bsm + wv * 2048;
    f32x4 acc[4][2];
#pragma unroll
    for (int i = 0; i < 4; ++i)
#pragma unroll
        for (int j = 0; j < 2; ++j) acc[i][j] = (f32x4)(0.f);
    int wcol = wv * 32;
    for (int t = 0; t < KCH / 32; ++t) {
        int k0 = kc * KCH + t * 32;
        __syncthreads();
        gload16(gA + k0, lA);
        gload16(gB + k0, lB);
        gload16(gB + (size_t)16 * K3 + k0, lB + 1024);
        __syncthreads();
        bf16x8 af[4], bfr[2];
#pragma unroll
        for (int rt = 0; rt < 4; ++rt)
            af[rt] = *(const bf16x8*)(Asm + (rt * 16 + (lane & 15)) * 32 + (lane >> 4) * 8);
#pragma unroll
        for (int ct = 0; ct < 2; ++ct)
            bfr[ct] = *(const bf16x8*)(Bsm + (wcol + ct * 16 + (lane & 15)) * 32 + (lane >> 4) * 8);
#pragma unroll
        for (int rt = 0; rt < 4; ++rt)
#pragma unroll
            for (int ct = 0; ct < 2; ++ct)
                acc[rt][ct] = __builtin_amdgcn_mfma_f32_16x16x32_bf16(af[rt], bfr[ct], acc[rt][ct], 0, 0, 0);
    }
    int quad = lane >> 4, col = lane & 15;
#pragma unroll
    for (int rt = 0; rt < 4; ++rt)
#pragma unroll
        for (int ct = 0; ct < 2; ++ct)
#pragma unroll
            for (int reg = 0; reg < 4; ++reg) {
                int row = rt * 16 + quad * 4 + reg;
                dst[((size_t)kc * BB + row) * UU + u0 + wcol + ct * 16 + col] = acc[rt][ct][reg];
            }
}

// ---------------------------------------------------------------------------
// K3b: reduce split-K, bias+elu -> h1 (bf16), pass skip_pre (fp32)
// ---------------------------------------------------------------------------
__global__ void k_red3(const float* __restrict__ part1, const float* __restrict__ part2,
                       const float* __restrict__ b1, unsigned short* __restrict__ h1b,
                       float* __restrict__ skippre) {
    int idx = blockIdx.x * 256 + threadIdx.x;
    if (idx >= BB * UU) return;
    int u = idx & (UU - 1);
    float s1 = 0.f, s2 = 0.f;
    for (int kc = 0; kc < KSPLIT; ++kc) {
        s1 += part1[(size_t)kc * BB * UU + idx];
        s2 += part2[(size_t)kc * BB * UU + idx];
    }
    float v = s1 + b1[u];
    h1b[idx] = f2bf(v > 0.f ? v : expf(v) - 1.0f);
    skippre[idx] = s2;
}

// ---------------------------------------------------------------------------
// K4: h2 = h1b @ W2t^T + b2 -> bf16
// ---------------------------------------------------------------------------
__global__ __launch_bounds__(256) void k_h2_mfma(const unsigned short* __restrict__ h1b,
                                                 const unsigned short* __restrict__ W2t,
                                                 const float* __restrict__ b2,
                                                 unsigned short* __restrict__ h2b) {
    __shared__ short Asm[64 * 32];
    __shared__ short Bsm[64 * 32];
    int tid = threadIdx.x, lane = tid & 63;
    int wv = __builtin_amdgcn_readfirstlane(tid >> 6);
    int u0 = blockIdx.x * 64;
    const unsigned short* gA = h1b + (size_t)(wv * 16 + (lane >> 2)) * 512 + (lane & 3) * 8;
    const unsigned short* gB = W2t + (size_t)(u0 + wv * 16 + (lane >> 2)) * 512 + (lane & 3) * 8;
    char* lA = (char*)Asm + wv * 1024;
    char* lB = (char*)Bsm + wv * 1024;
    f32x4 acc[4];
#pragma unroll
    for (int i = 0; i < 4; ++i) acc[i] = (f32x4)(0.f);
    int wcol = wv * 16;
    for (int t = 0; t < 16; ++t) {
        int k0 = t * 32;
        __syncthreads();
        gload16(gA + k0, lA);
        gload16(gB + k0, lB);
        __syncthreads();
        bf16x8 bfr = *(const bf16x8*)(Bsm + (wcol + (lane & 15)) * 32 + (lane >> 4) * 8);
#pragma unroll
        for (int rt = 0; rt < 4; ++rt) {
            bf16x8 af = *(const bf16x8*)(Asm + (rt * 16 + (lane & 15)) * 32 + (lane >> 4) * 8);
            acc[rt] = __builtin_amdgcn_mfma_f32_16x16x32_bf16(af, bfr, acc[rt], 0, 0, 0);
        }
    }
    int quad = lane >> 4, col = lane & 15;
    int j = u0 + wcol + col;
#pragma unroll
    for (int rt = 0; rt < 4; ++rt)
#pragma unroll
        for (int reg = 0; reg < 4; ++reg) {
            int row = rt * 16 + quad * 4 + reg;
            h2b[(size_t)row * UU + j] = f2bf(acc[rt][reg] + b2[j]);
        }
}

// ---------------------------------------------------------------------------
// K5: y = skippre + skb + sigmoid(h2@w3+b3)*(h2@w4+b4)
// ---------------------------------------------------------------------------
__global__ __launch_bounds__(256) void k_glu_mfma(const unsigned short* __restrict__ h2b,
                                                  const unsigned short* __restrict__ W3t,
                                                  const unsigned short* __restrict__ W4t,
                                                  const float* __restrict__ b3,
                                                  const float* __restrict__ b4,
                                                  const float* __restrict__ skippre,
                                                  const float* __restrict__ skb,
                                                  float* __restrict__ yv) {
    __shared__ short Asm[64 * 32];
    __shared__ short B3s[64 * 32];
    __shared__ short B4s[64 * 32];
    int tid = threadIdx.x, lane = tid & 63;
    int wv = __builtin_amdgcn_readfirstlane(tid >> 6);
    int u0 = blockIdx.x * 64;
    const unsigned short* gA = h2b + (size_t)(wv * 16 + (lane >> 2)) * 512 + (lane & 3) * 8;
    const unsigned short* gB3 = W3t + (size_t)(u0 + wv * 16 + (lane >> 2)) * 512 + (lane & 3) * 8;
    const unsigned short* gB4 = W4t + (size_t)(u0 + wv * 16 + (lane >> 2)) * 512 + (lane & 3) * 8;
    char* lA = (char*)Asm + wv * 1024;
    char* lB3 = (char*)B3s + wv * 1024;
    char* lB4 = (char*)B4s + wv * 1024;
    f32x4 acc3[4], acc4[4];
#pragma unroll
    for (int i = 0; i < 4; ++i) { acc3[i] = (f32x4)(0.f); acc4[i] = (f32x4)(0.f); }
    int wcol = wv * 16;
    for (int t = 0; t < 16; ++t) {
        int k0 = t * 32;
        __syncthreads();
        gload16(gA + k0, lA);
        gload16(gB3 + k0, lB3);
        gload16(gB4 + k0, lB4);
        __syncthreads();
        bf16x8 b3f = *(const bf16x8*)(B3s + (wcol + (lane & 15)) * 32 + (lane >> 4) * 8);
        bf16x8 b4f = *(const bf16x8*)(B4s + (wcol + (lane & 15)) * 32 + (lane >> 4) * 8);
#pragma unroll
        for (int rt = 0; rt < 4; ++rt) {
            bf16x8 af = *(const bf16x8*)(Asm + (rt * 16 + (lane & 15)) * 32 + (lane >> 4) * 8);
            acc3[rt] = __builtin_amdgcn_mfma_f32_16x16x32_bf16(af, b3f, acc3[rt], 0, 0, 0);
            acc4[rt] = __builtin_amdgcn_mfma_f32_16x16x32_bf16(af, b4f, acc4[rt], 0, 0, 0);
        }
    }
    int quad = lane >> 4, col = lane & 15;
    int j = u0 + wcol + col;
    float bb3 = b3[j], bb4 = b4[j], sb = skb[j];
#pragma unroll
    for (int rt = 0; rt < 4; ++rt)
#pragma unroll
        for (int reg = 0; reg < 4; ++reg) {
            int row = rt * 16 + quad * 4 + reg;
            float g = sigmoidf(acc3[rt][reg] + bb3);
            yv[(size_t)row * UU + j] = skippre[(size_t)row * UU + j] + sb + g * (acc4[rt][reg] + bb4);
        }
}

__device__ __forceinline__ float block_sum(float v, float* red) {
    int tid = threadIdx.x;
#pragma unroll
    for (int off = 32; off > 0; off >>= 1) v += __shfl_down(v, off);
    __syncthreads();
    if ((tid & 63) == 0) red[tid >> 6] = v;
    __syncthreads();
    float r = red[0];
#pragma unroll
    for (int i = 1; i < 8; ++i) r += red[i];
    return r;
}
__device__ __forceinline__ float block_max(float v, float* red) {
    int tid = threadIdx.x;
#pragma unroll
    for (int off = 32; off > 0; off >>= 1) v = fmaxf(v, __shfl_down(v, off));
    __syncthreads();
    if ((tid & 63) == 0) red[tid >> 6] = v;
    __syncthreads();
    float r = red[0];
#pragma unroll
    for (int i = 1; i < 8; ++i) r = fmaxf(r, red[i]);
    return r;
}

__global__ void k_lnsm(const float* __restrict__ yv, const float* __restrict__ gamma,
                       const float* __restrict__ beta, float* __restrict__ attn) {
    int b = blockIdx.x, u = threadIdx.x;
    __shared__ float red[8];
    float v = yv[(size_t)b * UU + u];
    float mu = block_sum(v, red) * (1.0f / UU);
    float d = v - mu;
    float var = block_sum(d * d, red) * (1.0f / UU);
    float z = d * rsqrtf(var + 1e-3f) * gamma[u] + beta[u];
    float m = block_max(z, red);
    float e = expf(z - m);
    float Z = block_sum(e, red);
    attn[(size_t)b * UU + u] = e / Z;
}

// ---------------------------------------------------------------------------
// K7a: attn-weighted reduction of KAN features over s (on-the-fly bases).
// Apart[ch][b][f*8+k] = sum_{s in chunk} attn[b,s]*bas_k(w[b,s,f])
// Apart[ch][b][1024+f] = sum attn[b,s]*silu(w[b,s,f])
// grid (64 b, 8 schunks), 128 thr (f)
// ---------------------------------------------------------------------------
__global__ __launch_bounds__(128) void k_attn_red(const float* __restrict__ weighted,
                                                  const float* __restrict__ attn,
                                                  float* __restrict__ Apart) {
    int b = blockIdx.x, ch = blockIdx.y;
    int f = threadIdx.x;
    __shared__ float attnS[64];
    if (f < 64) attnS[f] = attn[(size_t)b * UU + ch * 64 + f];
    __syncthreads();
    const float* wb = weighted + ((size_t)b * SS + ch * 64) * FF + f;
    float acc[9] = {};
    for (int s = 0; s < 64; ++s) {
        float w = wb[(size_t)s * FF];
        float a = attnS[s];
        float bas[8];
        bspline8(w, bas);
#pragma unroll
        for (int k2 = 0; k2 < 8; ++k2) acc[k2] += a * bas[k2];
        acc[8] += a * (w * sigmoidf(w));
    }
    float* op = Apart + ((size_t)ch * BB + b) * KK;
#pragma unroll
    for (int k2 = 0; k2 < 8; ++k2) op[f * 8 + k2] = acc[k2];
    op[1024 + f] = acc[8];
}

// ---------------------------------------------------------------------------
// K7b: reduce 8 chunks, apply 1/S, -> bf16 Aredb[64][1152]
// ---------------------------------------------------------------------------
__global__ void k_ared_red(const float* __restrict__ Apart, unsigned short* __restrict__ Aredb) {
    int idx = blockIdx.x * 256 + threadIdx.x;
    if (idx >= BB * KK) return;
    int b = idx / KK, c = idx % KK;
    float s = 0.f;
#pragma unroll
    for (int ch = 0; ch < 8; ++ch) s += Apart[((size_t)ch * BB + b) * KK + c];
    Aredb[idx] = f2bf(s * (1.0f / SS));
}

// ---------------------------------------------------------------------------
// K7c: current[64][512] = Aredb[64][1152] @ Wt[512][1152]^T.  grid 4.
// ---------------------------------------------------------------------------
__global__ __launch_bounds__(256) void k_cur_mfma(const unsigned short* __restrict__ Aredb,
                                                  const unsigned short* __restrict__ Wt,
                                                  float* __restrict__ current) {
    int u0 = blockIdx.x * 128;
    __shared__ short Asm[64 * 32];
    __shared__ short Bsm[128 * 32];
    int tid = threadIdx.x, lane = tid & 63;
    int wv = __builtin_amdgcn_readfirstlane(tid >> 6);
    const unsigned short* gA = Aredb + (size_t)(wv * 16 + (lane >> 2)) * KK + (lane & 3) * 8;
    const unsigned short* gB = Wt + (size_t)(u0 + wv * 32 + (lane >> 2)) * KK + (lane & 3) * 8;
    char* lA = (char*)Asm + wv * 1024;
    char* lB = (char*)Bsm + wv * 2048;
    f32x4 acc[4][2];
#pragma unroll
    for (int i = 0; i < 4; ++i)
#pragma unroll
        for (int j = 0; j < 2; ++j) acc[i][j] = (f32x4)(0.f);
    int wcol = wv * 32;
    for (int t = 0; t < KK / 32; ++t) {
        int k0 = t * 32;
        __syncthreads();
        gload16(gA + k0, lA);
        gload16(gB + k0, lB);
        gload16(gB + (size_t)16 * KK + k0, lB + 1024);
        __syncthreads();
        bf16x8 af[4], bfr[2];
#pragma unroll
        for (int rt = 0; rt < 4; ++rt)
            af[rt] = *(const bf16x8*)(Asm + (rt * 16 + (lane & 15)) * 32 + (lane >> 4) * 8);
#pragma unroll
        for (int ct = 0; ct < 2; ++ct)
            bfr[ct] = *(const bf16x8*)(Bsm + (wcol + ct * 16 + (lane & 15)) * 32 + (lane >> 4) * 8);
#pragma unroll
        for (int rt = 0; rt < 4; ++rt)
#pragma unroll
            for (int ct = 0; ct < 2; ++ct)
                acc[rt][ct] = __builtin_amdgcn_mfma_f32_16x16x32_bf16(af[rt], bfr[ct], acc[rt][ct], 0, 0, 0);
    }
    int quad = lane >> 4, col = lane & 15;
#pragma unroll
    for (int rt = 0; rt < 4; ++rt)
#pragma unroll
        for (int ct = 0; ct < 2; ++ct)
#pragma unroll
            for (int reg = 0; reg < 4; ++reg) {
                int row = rt * 16 + quad * 4 + reg;
                current[(size_t)row * UU + u0 + wcol + ct * 16 + col] = acc[rt][ct][reg];
            }
}

// ---------------------------------------------------------------------------
// K8a: comb_b[64][1024] bf16 = [current | h_prev]
// ---------------------------------------------------------------------------
__global__ void k_comb(const float* __restrict__ current, const float* __restrict__ h_prev,
                       unsigned short* __restrict__ comb_b) {
    int idx = blockIdx.x * 256 + threadIdx.x;
    if (idx >= BB * 1024) return;
    int b = idx >> 10, c = idx & 1023;
    float v = (c < 512) ? current[(size_t)b * UU + c] : h_prev[(size_t)b * UU + (c - 512)];
    comb_b[idx] = f2bf(v);
}

// ---------------------------------------------------------------------------
// K8b: gates[64][2048] = comb_b @ Wgt^T
// ---------------------------------------------------------------------------
__global__ __launch_bounds__(256) void k_gates_mfma(const unsigned short* __restrict__ comb_b,
                                                    const unsigned short* __restrict__ Wgt,
                                                    float* __restrict__ gates) {
    __shared__ short Asm[64 * 32];
    __shared__ short Bsm[128 * 32];
    int tid = threadIdx.x, lane = tid & 63;
    int wv = __builtin_amdgcn_readfirstlane(tid >> 6);
    int u0 = blockIdx.x * 128;
    const unsigned short* gA = comb_b + (size_t)(wv * 16 + (lane >> 2)) * 1024 + (lane & 3) * 8;
    const unsigned short* gB = Wgt + (size_t)(u0 + wv * 32 + (lane >> 2)) * 1024 + (lane & 3) * 8;
    char* lA = (char*)Asm + wv * 1024;
    char* lB = (char*)Bsm + wv * 2048;
    f32x4 acc[4][2];
#pragma unroll
    for (int i = 0; i < 4; ++i)
#pragma unroll
        for (int j = 0; j < 2; ++j) acc[i][j] = (f32x4)(0.f);
    int wcol = wv * 32;
    for (int t = 0; t < 32; ++t) {
        int k0 = t * 32;
        __syncthreads();
        gload16(gA + k0, lA);
        gload16(gB + k0, lB);
        gload16(gB + (size_t)16 * 1024 + k0, lB + 1024);
        __syncthreads();
        bf16x8 af[4], bfr[2];
#pragma unroll
        for (int rt = 0; rt < 4; ++rt)
            af[rt] = *(const bf16x8*)(Asm + (rt * 16 + (lane & 15)) * 32 + (lane >> 4) * 8);
#pragma unroll
        for (int ct = 0; ct < 2; ++ct)
            bfr[ct] = *(const bf16x8*)(Bsm + (wcol + ct * 16 + (lane & 15)) * 32 + (lane >> 4) * 8);
#pragma unroll
        for (int rt = 0; rt < 4; ++rt)
#pragma unroll
            for (int ct = 0; ct < 2; ++ct)
                acc[rt][ct] = __builtin_amdgcn_mfma_f32_16x16x32_bf16(af[rt], bfr[ct], acc[rt][ct], 0, 0, 0);
    }
    int quad = lane >> 4, col = lane & 15;
#pragma unroll
    for (int rt = 0; rt < 4; ++rt)
#pragma unroll
        for (int ct = 0; ct < 2; ++ct)
#pragma unroll
            for (int reg = 0; reg < 4; ++reg) {
                int row = rt * 16 + quad * 4 + reg;
                gates[(size_t)row * 2048 + u0 + wcol + ct * 16 + col] = acc[rt][ct][reg];
            }
}

// ---------------------------------------------------------------------------
// K8c: elementwise cell update
// ---------------------------------------------------------------------------
__global__ void k_cell(const float* __restrict__ gates,
                       const float* __restrict__ bf_, const float* __restrict__ bi_,
                       const float* __restrict__ bc_, const float* __restrict__ bo_,
                       const float* __restrict__ c_prev, float* __restrict__ out) {
    int idx = blockIdx.x * 256 + threadIdx.x;
    if (idx >= BB * UU) return;
    int b = idx >> 9, u = idx & 511;
    const float* g = gates + (size_t)b * 2048;
    float f = sigmoidf(g[u] + bf_[u]);
    float ii = sigmoidf(g[512 + u] + bi_[u]);
    float cd = tanhf(g[1024 + u] + bc_[u]);
    float o = sigmoidf(g[1536 + u] + bo_[u]);
    float cn = f * c_prev[idx] + ii * cd;
    out[idx] = o * tanhf(cn);
    out[(size_t)BB * UU + idx] = cn;
}

// ---------------------------------------------------------------------------
extern "C" void kernel_launch(void* const* d_in, const int* in_sizes, int n_in,
                              void* d_out, int out_size, void* d_ws, size_t ws_size,
                              hipStream_t stream) {
    const float* inp   = (const float*)d_in[0];
    const float* hprev = (const float*)d_in[1];
    const float* cprev = (const float*)d_in[2];
    const float* tk    = (const float*)d_in[3];
    const float* basew = (const float*)d_in[4];
    const float* splw  = (const float*)d_in[5];
    const float* gw1   = (const float*)d_in[6];
    const float* gb1   = (const float*)d_in[7];
    const float* gw2   = (const float*)d_in[8];
    const float* gb2   = (const float*)d_in[9];
    const float* gw3   = (const float*)d_in[10];
    const float* gb3   = (const float*)d_in[11];
    const float* gw4   = (const float*)d_in[12];
    const float* gb4   = (const float*)d_in[13];
    const float* gsw   = (const float*)d_in[14];
    const float* gsb   = (const float*)d_in[15];
    const float* lng   = (const float*)d_in[16];
    const float* lnb   = (const float*)d_in[17];
    const float* wf    = (const float*)d_in[18];
    const float* bf_   = (const float*)d_in[19];
    const float* wi    = (const float*)d_in[20];
    const float* bi_   = (const float*)d_in[21];
    const float* wc    = (const float*)d_in[22];
    const float* bc_   = (const float*)d_in[23];
    const float* wo    = (const float*)d_in[24];
    const float* bo_   = (const float*)d_in[25];
    float* out = (float*)d_out;

    float* ws = (float*)d_ws;
    size_t o = 0;
    float* weighted = ws + o; o += (size_t)BB * SS * FF;              // 16.78 MB (live to end)
    float* s2part   = ws + o; o += (size_t)4 * BB * FF * FF;          // 16.78 MB
    unsigned short* W1t = (unsigned short*)(ws + o); o += (size_t)UU * K3 / 2;  // 16.9 MB
    unsigned short* Wst = (unsigned short*)(ws + o); o += (size_t)UU * K3 / 2;  // 16.9 MB
    unsigned short* Wt  = (unsigned short*)(ws + o); o += (size_t)UU * KK / 2;  // 1.18 MB
    float* sig      = ws + o; o += (size_t)BB * SIGDIM;
    unsigned short* sigb = (unsigned short*)(ws + o); o += (size_t)BB * K3 / 2;
    float* part1    = ws + o; o += (size_t)KSPLIT * BB * UU;
    float* part2    = ws + o; o += (size_t)KSPLIT * BB * UU;
    float* skippre  = ws + o; o += (size_t)BB * UU;
    unsigned short* h1b = (unsigned short*)(ws + o); o += (size_t)BB * UU / 2;
    unsigned short* h2b = (unsigned short*)(ws + o); o += (size_t)BB * UU / 2;
    float* yv       = ws + o; o += (size_t)BB * UU;
    float* attn     = ws + o; o += (size_t)BB * UU;
    float* Apart    = ws + o; o += (size_t)8 * BB * KK;               // 2.36 MB
    unsigned short* Aredb = (unsigned short*)(ws + o); o += (size_t)BB * KK / 2;
    float* current  = ws + o; o += (size_t)BB * UU;
    unsigned short* W2t = (unsigned short*)(ws + o); o += (size_t)UU * 512 / 2;
    unsigned short* W3t = (unsigned short*)(ws + o); o += (size_t)UU * 512 / 2;
    unsigned short* W4t = (unsigned short*)(ws + o); o += (size_t)UU * 512 / 2;
    unsigned short* Wgt = (unsigned short*)(ws + o); o += (size_t)2048 * 1024 / 2;
    unsigned short* comb_b = (unsigned short*)(ws + o); o += (size_t)BB * 1024 / 2;
    float* gates    = ws + o; o += (size_t)BB * 2048;
    (void)ws_size; (void)in_sizes; (void)n_in; (void)out_size;

    k_weighted<<<(BB * SS * FF / 4 + 255) / 256, 256, 0, stream>>>(inp, tk, weighted);
    k_wprep<<<(UU * KK + 255) / 256, 256, 0, stream>>>(splw, basew, Wt);
    k_wt3<<<dim3(16, 8, 7), 256, 0, stream>>>(gw2, gw3, gw4, wf, wi, wc, wo, W2t, W3t, W4t, Wgt);
    k_wt2<<<dim3(K3 / 64, UU / 64, 2), 256, 0, stream>>>(gw1, gsw, W1t, Wst);
    k_sig_part<<<dim3(4, BB), 256, 0, stream>>>(weighted, s2part);
    k_sig_reduce<<<(BB * SIGDIM + 255) / 256, 256, 0, stream>>>(weighted, s2part, sig);
    k_sig2bf<<<(BB * K3 + 255) / 256, 256, 0, stream>>>(sig, sigb);
    k_gemm_sig_mfma<<<dim3(KSPLIT, 4, 2), 256, 0, stream>>>(sigb, W1t, Wst, part1, part2);
    k_red3<<<(BB * UU + 255) / 256, 256, 0, stream>>>(part1, part2, gb1, h1b, skippre);
    k_h2_mfma<<<8, 256, 0, stream>>>(h1b, W2t, gb2, h2b);
    k_glu_mfma<<<8, 256, 0, stream>>>(h2b, W3t, W4t, gb3, gb4, skippre, gsb, yv);
    k_lnsm<<<BB, UU, 0, stream>>>(yv, lng, lnb, attn);
    k_attn_red<<<dim3(BB, 8), 128, 0, stream>>>(weighted, attn, Apart);
    k_ared_red<<<(BB * KK + 255) / 256, 256, 0, stream>>>(Apart, Aredb);
    k_cur_mfma<<<4, 256, 0, stream>>>(Aredb, Wt, current);
    k_comb<<<(BB * 1024 + 255) / 256, 256, 0, stream>>>(current, hprev, comb_b);
    k_gates_mfma<<<16, 256, 0, stream>>>(comb_b, Wgt, gates);
    k_cell<<<(BB * UU + 255) / 256, 256, 0, stream>>>(gates, bf_, bi_, bc_, bo_, cprev, out);
}

// Round 6
// 333.374 us; speedup vs baseline: 5.9824x; 1.0808x over previous
//
#include <hip/hip_runtime.h>
#include <math.h>

#define BB 64
#define SS 512
#define FF 128
#define UU 512
#define NBB 8
#define SIGDIM (FF + FF*FF)   // 16512
#define K3 16512              // sig GEMM K
#define KK 1152               // KAN GEMM K: 1024 spline + 128 base
#define NCH 32                // attn-reduction s-chunks

typedef __attribute__((ext_vector_type(8))) __bf16 bf16x8;
typedef __attribute__((ext_vector_type(4))) float f32x4;

__device__ __forceinline__ unsigned short f2bf(float x) {
    unsigned int u = __float_as_uint(x);
    unsigned int r = u + 0x7FFFu + ((u >> 16) & 1u);   // RNE
    return (unsigned short)(r >> 16);
}

__device__ __forceinline__ float sigmoidf(float x) { return 1.0f / (1.0f + expf(-x)); }

// ---------------------------------------------------------------------------
// K1: Wt bf16 [512 u][1152 k] = [splw(u,:,:) flat | base_w^T]
//     + copy h_prev into right half of comb_b
// ---------------------------------------------------------------------------
__global__ void k_wprep(const float* __restrict__ splw, const float* __restrict__ basew,
                        const float* __restrict__ h_prev,
                        unsigned short* __restrict__ Wt, unsigned short* __restrict__ comb_b) {
    int idx = blockIdx.x * 256 + threadIdx.x;
    if (idx >= UU * KK) return;
    int u = idx / KK, c = idx % KK;
    float v = (c < 1024) ? splw[(size_t)u * 1024 + c] : basew[(size_t)(c - 1024) * UU + u];
    Wt[idx] = f2bf(v);
    if (idx < BB * UU) {
        int b = idx >> 9, uu = idx & 511;
        comb_b[(size_t)b * 1024 + 512 + uu] = f2bf(h_prev[idx]);
    }
}

// ---------------------------------------------------------------------------
// K2: transpose small weights -> bf16 B^T.
// z=0..2: w2/w3/w4 [512][512] -> W2t/W3t/W4t; z=3..6: gate mats -> Wgt[2048][1024]
// ---------------------------------------------------------------------------
__global__ __launch_bounds__(256) void k_wt3(const float* __restrict__ w2, const float* __restrict__ w3,
                                             const float* __restrict__ w4, const float* __restrict__ wf,
                                             const float* __restrict__ wi, const float* __restrict__ wc,
                                             const float* __restrict__ wo,
                                             unsigned short* __restrict__ W2t,
                                             unsigned short* __restrict__ W3t,
                                             unsigned short* __restrict__ W4t,
                                             unsigned short* __restrict__ Wgt) {
    int kt = blockIdx.x, ut = blockIdx.y, z = blockIdx.z;
    int Kdim = (z < 3) ? 512 : 1024;
    if (kt * 64 >= Kdim) return;
    const float* src;
    unsigned short* dst;
    switch (z) {
        case 0: src = w2; dst = W2t; break;
        case 1: src = w3; dst = W3t; break;
        case 2: src = w4; dst = W4t; break;
        case 3: src = wf; dst = Wgt; break;
        case 4: src = wi; dst = Wgt + (size_t)512 * 1024; break;
        case 5: src = wc; dst = Wgt + (size_t)1024 * 1024; break;
        default: src = wo; dst = Wgt + (size_t)1536 * 1024; break;
    }
    __shared__ float tile[64][65];
    int tid = threadIdx.x;
    int k0 = kt * 64, u0 = ut * 64;
#pragma unroll
    for (int p = 0; p < 16; ++p) {
        int e = p * 256 + tid;
        int kk = e >> 6, uu = e & 63;
        tile[kk][uu] = src[(size_t)(k0 + kk) * UU + u0 + uu];
    }
    __syncthreads();
#pragma unroll
    for (int p = 0; p < 16; ++p) {
        int e = p * 256 + tid;
        int uu = e >> 6, kk = e & 63;
        dst[(size_t)(u0 + uu) * Kdim + k0 + kk] = f2bf(tile[kk][uu]);
    }
}

// ---------------------------------------------------------------------------
// K3: transpose w1 / skip_w (16512 x 512 fp32) -> bf16 [512][16512]
// ---------------------------------------------------------------------------
__global__ __launch_bounds__(256) void k_wt2(const float* __restrict__ w1,
                                             const float* __restrict__ gsw,
                                             unsigned short* __restrict__ W1t,
                                             unsigned short* __restrict__ Wst) {
    int kt = blockIdx.x, ut = blockIdx.y, mat = blockIdx.z;
    const float* src = mat ? gsw : w1;
    unsigned short* dst = mat ? Wst : W1t;
    __shared__ float tile[64][65];
    int tid = threadIdx.x;
    int k0 = kt * 64, u0 = ut * 64;
#pragma unroll
    for (int p = 0; p < 16; ++p) {
        int e = p * 256 + tid;
        int kk = e >> 6, uu = e & 63;
        tile[kk][uu] = src[(size_t)(k0 + kk) * UU + u0 + uu];
    }
    __syncthreads();
#pragma unroll
    for (int p = 0; p < 16; ++p) {
        int e = p * 256 + tid;
        int uu = e >> 6, kk = e & 63;
        dst[(size_t)(u0 + uu) * K3 + k0 + kk] = f2bf(tile[kk][uu]);
    }
}

// ---------------------------------------------------------------------------
// K4: signature level-2 partials (reads inp, applies tk on the fly)
// ---------------------------------------------------------------------------
__global__ void k_sig_part(const float* __restrict__ inp, const float* __restrict__ tk,
                           float* __restrict__ s2part) {
    int chunk = blockIdx.x, b = blockIdx.y;
    int tid = threadIdx.x;
    __shared__ float aT[16][128];
    __shared__ float dT[16][128];
    __shared__ float w0s[128];
    __shared__ float tkS[130];
    const float* ib = inp + (size_t)b * SS * FF;
    if (tid < 130) { int t = chunk * 128 + tid; tkS[tid] = (t < SS) ? tk[t] : 0.f; }
    if (tid < 128) w0s[tid] = tk[0] * ib[tid];
    float acc[8][8] = {};
    int i0 = (tid >> 4) * 8, j0 = (tid & 15) * 8;
    for (int t0 = chunk * 128; t0 < chunk * 128 + 128; t0 += 16) {
        __syncthreads();
        for (int e = tid; e < 16 * 128; e += 256) {
            int tt = e >> 7, f = e & 127;
            int t = t0 + tt;
            float av = 0.f, dv = 0.f;
            if (t < SS - 1) {
                int tl = t - chunk * 128;
                float wa = tkS[tl] * ib[t * FF + f], wc = tkS[tl + 1] * ib[(t + 1) * FF + f];
                av = 0.5f * (wa + wc) - w0s[f];
                dv = wc - wa;
            }
            aT[tt][f] = av; dT[tt][f] = dv;
        }
        __syncthreads();
#pragma unroll
        for (int kk = 0; kk < 16; ++kk) {
            float a8[8], d8[8];
#pragma unroll
            for (int i = 0; i < 8; ++i) a8[i] = aT[kk][i0 + i];
#pragma unroll
            for (int j = 0; j < 8; ++j) d8[j] = dT[kk][j0 + j];
#pragma unroll
            for (int i = 0; i < 8; ++i)
#pragma unroll
                for (int j = 0; j < 8; ++j) acc[i][j] += a8[i] * d8[j];
        }
    }
    float* outp = s2part + ((size_t)chunk * BB + b) * (FF * FF);
#pragma unroll
    for (int i = 0; i < 8; ++i)
#pragma unroll
        for (int j = 0; j < 8; ++j)
            outp[(i0 + i) * FF + (j0 + j)] = acc[i][j];
}

// ---------------------------------------------------------------------------
// K5: assemble sig directly as bf16 (merged sig2bf)
// ---------------------------------------------------------------------------
__global__ void k_sig_reduce(const float* __restrict__ inp, const float* __restrict__ tk,
                             const float* __restrict__ s2part, unsigned short* __restrict__ sigb) {
    int idx = blockIdx.x * 256 + threadIdx.x;
    if (idx >= BB * SIGDIM) return;
    int b = idx / SIGDIM, r = idx % SIGDIM;
    float v;
    if (r < FF) {
        v = tk[SS - 1] * inp[((size_t)b * SS + SS - 1) * FF + r] - tk[0] * inp[(size_t)b * SS * FF + r];
    } else {
        int ij = r - FF;
        v = 0.f;
#pragma unroll
        for (int c = 0; c < 4; ++c) v += s2part[((size_t)c * BB + b) * (FF * FF) + ij];
    }
    sigb[idx] = f2bf(v);
}

// ---------------------------------------------------------------------------
// K6: direct single-wave MFMA: {h1,skip} = sigb[64][16512] @ {W1t,Wst}^T
// grid (4 mt, 32 nt, 2 mat) x 64 thr.  No LDS, no barriers: loads pipeline.
// ---------------------------------------------------------------------------
__global__ __launch_bounds__(64) void k_sig_direct(const unsigned short* __restrict__ sigb,
                                                   const unsigned short* __restrict__ W1t,
                                                   const unsigned short* __restrict__ Wst,
                                                   const float* __restrict__ b1,
                                                   unsigned short* __restrict__ h1b,
                                                   float* __restrict__ skippre) {
    int lane = threadIdx.x;
    int mt = blockIdx.x, nt = blockIdx.y, mat = blockIdx.z;
    const unsigned short* Bp = mat ? Wst : W1t;
    const unsigned short* pa = sigb + (size_t)(mt * 16 + (lane & 15)) * K3 + (lane >> 4) * 8;
    const unsigned short* pb = Bp + (size_t)(nt * 16 + (lane & 15)) * K3 + (lane >> 4) * 8;
    f32x4 acc0 = (f32x4)(0.f), acc1 = (f32x4)(0.f);
#pragma unroll 8
    for (int t = 0; t < K3 / 32; t += 2) {
        bf16x8 a0 = *(const bf16x8*)(pa + t * 32);
        bf16x8 b0 = *(const bf16x8*)(pb + t * 32);
        bf16x8 a1 = *(const bf16x8*)(pa + t * 32 + 32);
        bf16x8 b1v = *(const bf16x8*)(pb + t * 32 + 32);
        acc0 = __builtin_amdgcn_mfma_f32_16x16x32_bf16(a0, b0, acc0, 0, 0, 0);
        acc1 = __builtin_amdgcn_mfma_f32_16x16x32_bf16(a1, b1v, acc1, 0, 0, 0);
    }
    int col = lane & 15, quad = lane >> 4;
    int j = nt * 16 + col;
    if (mat == 0) {
        float bb = b1[j];
#pragma unroll
        for (int reg = 0; reg < 4; ++reg) {
            int row = mt * 16 + quad * 4 + reg;
            float v = acc0[reg] + acc1[reg] + bb;
            h1b[(size_t)row * UU + j] = f2bf(v > 0.f ? v : expf(v) - 1.0f);
        }
    } else {
#pragma unroll
        for (int reg = 0; reg < 4; ++reg) {
            int row = mt * 16 + quad * 4 + reg;
            skippre[(size_t)row * UU + j] = acc0[reg] + acc1[reg];
        }
    }
}

// ---------------------------------------------------------------------------
// K7: direct h2 = h1b @ W2t^T + b2 -> bf16.  grid (4,32) x 64.
// ---------------------------------------------------------------------------
__global__ __launch_bounds__(64) void k_h2_direct(const unsigned short* __restrict__ h1b,
                                                  const unsigned short* __restrict__ W2t,
                                                  const float* __restrict__ b2,
                                                  unsigned short* __restrict__ h2b) {
    int lane = threadIdx.x;
    int mt = blockIdx.x, nt = blockIdx.y;
    const unsigned short* pa = h1b + (size_t)(mt * 16 + (lane & 15)) * 512 + (lane >> 4) * 8;
    const unsigned short* pb = W2t + (size_t)(nt * 16 + (lane & 15)) * 512 + (lane >> 4) * 8;
    f32x4 acc0 = (f32x4)(0.f), acc1 = (f32x4)(0.f);
#pragma unroll
    for (int t = 0; t < 16; t += 2) {
        bf16x8 a0 = *(const bf16x8*)(pa + t * 32);
        bf16x8 b0 = *(const bf16x8*)(pb + t * 32);
        bf16x8 a1 = *(const bf16x8*)(pa + t * 32 + 32);
        bf16x8 b1v = *(const bf16x8*)(pb + t * 32 + 32);
        acc0 = __builtin_amdgcn_mfma_f32_16x16x32_bf16(a0, b0, acc0, 0, 0, 0);
        acc1 = __builtin_amdgcn_mfma_f32_16x16x32_bf16(a1, b1v, acc1, 0, 0, 0);
    }
    int col = lane & 15, quad = lane >> 4;
    int j = nt * 16 + col;
    float bb = b2[j];
#pragma unroll
    for (int reg = 0; reg < 4; ++reg) {
        int row = mt * 16 + quad * 4 + reg;
        h2b[(size_t)row * UU + j] = f2bf(acc0[reg] + acc1[reg] + bb);
    }
}

// ---------------------------------------------------------------------------
// K8: direct GLU: y = skippre + skb + sigmoid(h2@w3+b3)*(h2@w4+b4). grid (4,32) x 64.
// ---------------------------------------------------------------------------
__global__ __launch_bounds__(64) void k_glu_direct(const unsigned short* __restrict__ h2b,
                                                   const unsigned short* __restrict__ W3t,
                                                   const unsigned short* __restrict__ W4t,
                                                   const float* __restrict__ b3,
                                                   const float* __restrict__ b4,
                                                   const float* __restrict__ skippre,
                                                   const float* __restrict__ skb,
                                                   float* __restrict__ yv) {
    int lane = threadIdx.x;
    int mt = blockIdx.x, nt = blockIdx.y;
    const unsigned short* pa = h2b + (size_t)(mt * 16 + (lane & 15)) * 512 + (lane >> 4) * 8;
    const unsigned short* pb3 = W3t + (size_t)(nt * 16 + (lane & 15)) * 512 + (lane >> 4) * 8;
    const unsigned short* pb4 = W4t + (size_t)(nt * 16 + (lane & 15)) * 512 + (lane >> 4) * 8;
    f32x4 acc3 = (f32x4)(0.f), acc4 = (f32x4)(0.f);
#pragma unroll
    for (int t = 0; t < 16; ++t) {
        bf16x8 a = *(const bf16x8*)(pa + t * 32);
        bf16x8 b3f = *(const bf16x8*)(pb3 + t * 32);
        bf16x8 b4f = *(const bf16x8*)(pb4 + t * 32);
        acc3 = __builtin_amdgcn_mfma_f32_16x16x32_bf16(a, b3f, acc3, 0, 0, 0);
        acc4 = __builtin_amdgcn_mfma_f32_16x16x32_bf16(a, b4f, acc4, 0, 0, 0);
    }
    int col = lane & 15, quad = lane >> 4;
    int j = nt * 16 + col;
    float bb3 = b3[j], bb4 = b4[j], sb = skb[j];
#pragma unroll
    for (int reg = 0; reg < 4; ++reg) {
        int row = mt * 16 + quad * 4 + reg;
        float g = sigmoidf(acc3[reg] + bb3);
        yv[(size_t)row * UU + j] = skippre[(size_t)row * UU + j] + sb + g * (acc4[reg] + bb4);
    }
}

// ---------------------------------------------------------------------------
// K9: layernorm + softmax -> attn
// ---------------------------------------------------------------------------
__device__ __forceinline__ float block_sum(float v, float* red) {
    int tid = threadIdx.x;
#pragma unroll
    for (int off = 32; off > 0; off >>= 1) v += __shfl_down(v, off);
    __syncthreads();
    if ((tid & 63) == 0) red[tid >> 6] = v;
    __syncthreads();
    float r = red[0];
#pragma unroll
    for (int i = 1; i < 8; ++i) r += red[i];
    return r;
}
__device__ __forceinline__ float block_max(float v, float* red) {
    int tid = threadIdx.x;
#pragma unroll
    for (int off = 32; off > 0; off >>= 1) v = fmaxf(v, __shfl_down(v, off));
    __syncthreads();
    if ((tid & 63) == 0) red[tid >> 6] = v;
    __syncthreads();
    float r = red[0];
#pragma unroll
    for (int i = 1; i < 8; ++i) r = fmaxf(r, red[i]);
    return r;
}

__global__ void k_lnsm(const float* __restrict__ yv, const float* __restrict__ gamma,
                       const float* __restrict__ beta, float* __restrict__ attn) {
    int b = blockIdx.x, u = threadIdx.x;
    __shared__ float red[8];
    float v = yv[(size_t)b * UU + u];
    float mu = block_sum(v, red) * (1.0f / UU);
    float d = v - mu;
    float var = block_sum(d * d, red) * (1.0f / UU);
    float z = d * rsqrtf(var + 1e-3f) * gamma[u] + beta[u];
    float m = block_max(z, red);
    float e = expf(z - m);
    float Z = block_sum(e, red);
    attn[(size_t)b * UU + u] = e / Z;
}

// ---------------------------------------------------------------------------
// K10: attn-weighted KAN-feature reduction, closed-form cubic B-spline.
// For x in cell c (c = floor((x+2.2)/0.4), u = frac), the only nonzero bases
// are bas[c-3..c] with the standard uniform cubic segment polynomials.
// grid (64 b, 32 chunks of 16 s) x 128 thr (f).
// ---------------------------------------------------------------------------
__global__ __launch_bounds__(128) void k_attn_red(const float* __restrict__ inp,
                                                  const float* __restrict__ tk,
                                                  const float* __restrict__ attn,
                                                  float* __restrict__ Apart) {
    int b = blockIdx.x, ch = blockIdx.y;
    int f = threadIdx.x;
    __shared__ float attnS[16], tkS[16];
    if (f < 16) { attnS[f] = attn[(size_t)b * UU + ch * 16 + f]; tkS[f] = tk[ch * 16 + f]; }
    __syncthreads();
    const float* ib = inp + ((size_t)b * SS + ch * 16) * FF + f;
    float acc[9] = {};
#pragma unroll
    for (int s = 0; s < 16; ++s) {
        float w = tkS[s] * ib[(size_t)s * FF];
        float a = attnS[s];
        float t = (w + 2.2f) * 2.5f;
        float cf = floorf(fminf(fmaxf(t, -2.f), 13.f));
        int c = (int)cf;
        float u = t - cf;
        float u2 = u * u, u3 = u2 * u;
        float p0 = u3 * (1.f / 6.f);
        float p1 = (-3.f * u3 + 3.f * u2 + 3.f * u + 1.f) * (1.f / 6.f);
        float p2 = (3.f * u3 - 6.f * u2 + 4.f) * (1.f / 6.f);
        float onemu = 1.f - u;
        float p3 = onemu * onemu * onemu * (1.f / 6.f);
#pragma unroll
        for (int k2 = 0; k2 < 8; ++k2) {
            int d = c - k2;
            float v = (d == 0) ? p0 : (d == 1) ? p1 : (d == 2) ? p2 : (d == 3) ? p3 : 0.f;
            acc[k2] += a * v;
        }
        acc[8] += a * (w * sigmoidf(w));
    }
    float* op = Apart + ((size_t)ch * BB + b) * KK;
    float4 v0 = { acc[0], acc[1], acc[2], acc[3] };
    float4 v1 = { acc[4], acc[5], acc[6], acc[7] };
    *(float4*)(op + f * 8) = v0;
    *(float4*)(op + f * 8 + 4) = v1;
    op[1024 + f] = acc[8];
}

// ---------------------------------------------------------------------------
// K11: reduce 32 chunks, /S, -> bf16 Aredb[64][1152]
// ---------------------------------------------------------------------------
__global__ void k_ared_red(const float* __restrict__ Apart, unsigned short* __restrict__ Aredb) {
    int idx = blockIdx.x * 256 + threadIdx.x;
    if (idx >= BB * KK) return;
    int b = idx / KK, c = idx % KK;
    float s = 0.f;
#pragma unroll
    for (int ch = 0; ch < NCH; ++ch) s += Apart[((size_t)ch * BB + b) * KK + c];
    Aredb[idx] = f2bf(s * (1.0f / SS));
}

// ---------------------------------------------------------------------------
// K12: direct current = Aredb[64][1152] @ Wt^T -> bf16 into comb_b left half.
// grid (4,32) x 64.
// ---------------------------------------------------------------------------
__global__ __launch_bounds__(64) void k_cur_direct(const unsigned short* __restrict__ Aredb,
                                                   const unsigned short* __restrict__ Wt,
                                                   unsigned short* __restrict__ comb_b) {
    int lane = threadIdx.x;
    int mt = blockIdx.x, nt = blockIdx.y;
    const unsigned short* pa = Aredb + (size_t)(mt * 16 + (lane & 15)) * KK + (lane >> 4) * 8;
    const unsigned short* pb = Wt + (size_t)(nt * 16 + (lane & 15)) * KK + (lane >> 4) * 8;
    f32x4 acc0 = (f32x4)(0.f), acc1 = (f32x4)(0.f);
#pragma unroll 6
    for (int t = 0; t < KK / 32; t += 2) {
        bf16x8 a0 = *(const bf16x8*)(pa + t * 32);
        bf16x8 b0 = *(const bf16x8*)(pb + t * 32);
        bf16x8 a1 = *(const bf16x8*)(pa + t * 32 + 32);
        bf16x8 b1v = *(const bf16x8*)(pb + t * 32 + 32);
        acc0 = __builtin_amdgcn_mfma_f32_16x16x32_bf16(a0, b0, acc0, 0, 0, 0);
        acc1 = __builtin_amdgcn_mfma_f32_16x16x32_bf16(a1, b1v, acc1, 0, 0, 0);
    }
    int col = lane & 15, quad = lane >> 4;
    int j = nt * 16 + col;
#pragma unroll
    for (int reg = 0; reg < 4; ++reg) {
        int row = mt * 16 + quad * 4 + reg;
        comb_b[(size_t)row * 1024 + j] = f2bf(acc0[reg] + acc1[reg]);
    }
}

// ---------------------------------------------------------------------------
// K13: direct gates[64][2048] = comb_b[64][1024] @ Wgt^T. grid (4,128) x 64.
// ---------------------------------------------------------------------------
__global__ __launch_bounds__(64) void k_gates_direct(const unsigned short* __restrict__ comb_b,
                                                     const unsigned short* __restrict__ Wgt,
                                                     float* __restrict__ gates) {
    int lane = threadIdx.x;
    int mt = blockIdx.x, nt = blockIdx.y;
    const unsigned short* pa = comb_b + (size_t)(mt * 16 + (lane & 15)) * 1024 + (lane >> 4) * 8;
    const unsigned short* pb = Wgt + (size_t)(nt * 16 + (lane & 15)) * 1024 + (lane >> 4) * 8;
    f32x4 acc0 = (f32x4)(0.f), acc1 = (f32x4)(0.f);
#pragma unroll 8
    for (int t = 0; t < 32; t += 2) {
        bf16x8 a0 = *(const bf16x8*)(pa + t * 32);
        bf16x8 b0 = *(const bf16x8*)(pb + t * 32);
        bf16x8 a1 = *(const bf16x8*)(pa + t * 32 + 32);
        bf16x8 b1v = *(const bf16x8*)(pb + t * 32 + 32);
        acc0 = __builtin_amdgcn_mfma_f32_16x16x32_bf16(a0, b0, acc0, 0, 0, 0);
        acc1 = __builtin_amdgcn_mfma_f32_16x16x32_bf16(a1, b1v, acc1, 0, 0, 0);
    }
    int col = lane & 15, quad = lane >> 4;
    int j = nt * 16 + col;
#pragma unroll
    for (int reg = 0; reg < 4; ++reg) {
        int row = mt * 16 + quad * 4 + reg;
        gates[(size_t)row * 2048 + j] = acc0[reg] + acc1[reg];
    }
}

// ---------------------------------------------------------------------------
// K14: elementwise cell update
// ---------------------------------------------------------------------------
__global__ void k_cell(const float* __restrict__ gates,
                       const float* __restrict__ bf_, const float* __restrict__ bi_,
                       const float* __restrict__ bc_, const float* __restrict__ bo_,
                       const float* __restrict__ c_prev, float* __restrict__ out) {
    int idx = blockIdx.x * 256 + threadIdx.x;
    if (idx >= BB * UU) return;
    int b = idx >> 9, u = idx & 511;
    const float* g = gates + (size_t)b * 2048;
    float f = sigmoidf(g[u] + bf_[u]);
    float ii = sigmoidf(g[512 + u] + bi_[u]);
    float cd = tanhf(g[1024 + u] + bc_[u]);
    float o = sigmoidf(g[1536 + u] + bo_[u]);
    float cn = f * c_prev[idx] + ii * cd;
    out[idx] = o * tanhf(cn);
    out[(size_t)BB * UU + idx] = cn;
}

// ---------------------------------------------------------------------------
extern "C" void kernel_launch(void* const* d_in, const int* in_sizes, int n_in,
                              void* d_out, int out_size, void* d_ws, size_t ws_size,
                              hipStream_t stream) {
    const float* inp   = (const float*)d_in[0];
    const float* hprev = (const float*)d_in[1];
    const float* cprev = (const float*)d_in[2];
    const float* tk    = (const float*)d_in[3];
    const float* basew = (const float*)d_in[4];
    const float* splw  = (const float*)d_in[5];
    const float* gw1   = (const float*)d_in[6];
    const float* gb1   = (const float*)d_in[7];
    const float* gw2   = (const float*)d_in[8];
    const float* gb2   = (const float*)d_in[9];
    const float* gw3   = (const float*)d_in[10];
    const float* gb3   = (const float*)d_in[11];
    const float* gw4   = (const float*)d_in[12];
    const float* gb4   = (const float*)d_in[13];
    const float* gsw   = (const float*)d_in[14];
    const float* gsb   = (const float*)d_in[15];
    const float* lng   = (const float*)d_in[16];
    const float* lnb   = (const float*)d_in[17];
    const float* wf    = (const float*)d_in[18];
    const float* bf_   = (const float*)d_in[19];
    const float* wi    = (const float*)d_in[20];
    const float* bi_   = (const float*)d_in[21];
    const float* wc    = (const float*)d_in[22];
    const float* bc_   = (const float*)d_in[23];
    const float* wo    = (const float*)d_in[24];
    const float* bo_   = (const float*)d_in[25];
    float* out = (float*)d_out;

    float* ws = (float*)d_ws;
    size_t o = 0;
    unsigned short* W1t = (unsigned short*)(ws + o); o += (size_t)UU * K3 / 2;   // 16.9 MB
    unsigned short* Wst = (unsigned short*)(ws + o); o += (size_t)UU * K3 / 2;   // 16.9 MB
    unsigned short* Wt  = (unsigned short*)(ws + o); o += (size_t)UU * KK / 2;
    float* s2part   = ws + o; o += (size_t)4 * BB * FF * FF;                     // 16.78 MB
    unsigned short* sigb = (unsigned short*)(ws + o); o += (size_t)BB * K3 / 2;
    float* skippre  = ws + o; o += (size_t)BB * UU;
    unsigned short* h1b = (unsigned short*)(ws + o); o += (size_t)BB * UU / 2;
    unsigned short* h2b = (unsigned short*)(ws + o); o += (size_t)BB * UU / 2;
    float* yv       = ws + o; o += (size_t)BB * UU;
    float* attn     = ws + o; o += (size_t)BB * UU;
    float* Apart    = ws + o; o += (size_t)NCH * BB * KK;                        // 9.4 MB
    unsigned short* Aredb = (unsigned short*)(ws + o); o += (size_t)BB * KK / 2;
    unsigned short* W2t = (unsigned short*)(ws + o); o += (size_t)512 * 512 / 2;
    unsigned short* W3t = (unsigned short*)(ws + o); o += (size_t)512 * 512 / 2;
    unsigned short* W4t = (unsigned short*)(ws + o); o += (size_t)512 * 512 / 2;
    unsigned short* Wgt = (unsigned short*)(ws + o); o += (size_t)2048 * 1024 / 2;
    unsigned short* comb_b = (unsigned short*)(ws + o); o += (size_t)BB * 1024 / 2;
    float* gates    = ws + o; o += (size_t)BB * 2048;
    (void)ws_size; (void)in_sizes; (void)n_in; (void)out_size;

    k_wprep<<<(UU * KK + 255) / 256, 256, 0, stream>>>(splw, basew, hprev, Wt, comb_b);
    k_wt3<<<dim3(16, 8, 7), 256, 0, stream>>>(gw2, gw3, gw4, wf, wi, wc, wo, W2t, W3t, W4t, Wgt);
    k_wt2<<<dim3(K3 / 64, UU / 64, 2), 256, 0, stream>>>(gw1, gsw, W1t, Wst);
    k_sig_part<<<dim3(4, BB), 256, 0, stream>>>(inp, tk, s2part);
    k_sig_reduce<<<(BB * SIGDIM + 255) / 256, 256, 0, stream>>>(inp, tk, s2part, sigb);
    k_sig_direct<<<dim3(4, 32, 2), 64, 0, stream>>>(sigb, W1t, Wst, gb1, h1b, skippre);
    k_h2_direct<<<dim3(4, 32), 64, 0, stream>>>(h1b, W2t, gb2, h2b);
    k_glu_direct<<<dim3(4, 32), 64, 0, stream>>>(h2b, W3t, W4t, gb3, gb4, skippre, gsb, yv);
    k_lnsm<<<BB, UU, 0, stream>>>(yv, lng, lnb, attn);
    k_attn_red<<<dim3(BB, NCH), 128, 0, stream>>>(inp, tk, attn, Apart);
    k_ared_red<<<(BB * KK + 255) / 256, 256, 0, stream>>>(Apart, Aredb);
    k_cur_direct<<<dim3(4, 32), 64, 0, stream>>>(Aredb, Wt, comb_b);
    k_gates_direct<<<dim3(4, 128), 64, 0, stream>>>(comb_b, Wgt, gates);
    k_cell<<<(BB * UU + 255) / 256, 256, 0, stream>>>(gates, bf_, bi_, bc_, bo_, cprev, out);
}

// Round 7
// 298.000 us; speedup vs baseline: 6.6925x; 1.1187x over previous
//
#include <hip/hip_runtime.h>
#include <math.h>

#define BB 64
#define SS 512
#define FF 128
#define UU 512
#define NBB 8
#define SIGDIM (FF + FF*FF)   // 16512
#define K3 16512              // sig GEMM K
#define KK 1152               // KAN GEMM K: 1024 spline + 128 base
#define NCH 32                // attn-reduction s-chunks

typedef __attribute__((ext_vector_type(8))) __bf16 bf16x8;
typedef __attribute__((ext_vector_type(4))) float f32x4;

__device__ __forceinline__ unsigned short f2bf(float x) {
    unsigned int u = __float_as_uint(x);
    unsigned int r = u + 0x7FFFu + ((u >> 16) & 1u);   // RNE
    return (unsigned short)(r >> 16);
}

__device__ __forceinline__ float sigmoidf(float x) { return 1.0f / (1.0f + expf(-x)); }

// ---------------------------------------------------------------------------
// K1: Wt bf16 [512 u][1152 k] = [splw(u,:,:) flat | base_w^T]
//     + copy h_prev into right half of comb_b
// ---------------------------------------------------------------------------
__global__ void k_wprep(const float* __restrict__ splw, const float* __restrict__ basew,
                        const float* __restrict__ h_prev,
                        unsigned short* __restrict__ Wt, unsigned short* __restrict__ comb_b) {
    int idx = blockIdx.x * 256 + threadIdx.x;
    if (idx >= UU * KK) return;
    int u = idx / KK, c = idx % KK;
    float v = (c < 1024) ? splw[(size_t)u * 1024 + c] : basew[(size_t)(c - 1024) * UU + u];
    Wt[idx] = f2bf(v);
    if (idx < BB * UU) {
        int b = idx >> 9, uu = idx & 511;
        comb_b[(size_t)b * 1024 + 512 + uu] = f2bf(h_prev[idx]);
    }
}

// ---------------------------------------------------------------------------
// K2: transpose small weights -> bf16 B^T.
// ---------------------------------------------------------------------------
__global__ __launch_bounds__(256) void k_wt3(const float* __restrict__ w2, const float* __restrict__ w3,
                                             const float* __restrict__ w4, const float* __restrict__ wf,
                                             const float* __restrict__ wi, const float* __restrict__ wc,
                                             const float* __restrict__ wo,
                                             unsigned short* __restrict__ W2t,
                                             unsigned short* __restrict__ W3t,
                                             unsigned short* __restrict__ W4t,
                                             unsigned short* __restrict__ Wgt) {
    int kt = blockIdx.x, ut = blockIdx.y, z = blockIdx.z;
    int Kdim = (z < 3) ? 512 : 1024;
    if (kt * 64 >= Kdim) return;
    const float* src;
    unsigned short* dst;
    switch (z) {
        case 0: src = w2; dst = W2t; break;
        case 1: src = w3; dst = W3t; break;
        case 2: src = w4; dst = W4t; break;
        case 3: src = wf; dst = Wgt; break;
        case 4: src = wi; dst = Wgt + (size_t)512 * 1024; break;
        case 5: src = wc; dst = Wgt + (size_t)1024 * 1024; break;
        default: src = wo; dst = Wgt + (size_t)1536 * 1024; break;
    }
    __shared__ float tile[64][65];
    int tid = threadIdx.x;
    int k0 = kt * 64, u0 = ut * 64;
#pragma unroll
    for (int p = 0; p < 16; ++p) {
        int e = p * 256 + tid;
        int kk = e >> 6, uu = e & 63;
        tile[kk][uu] = src[(size_t)(k0 + kk) * UU + u0 + uu];
    }
    __syncthreads();
#pragma unroll
    for (int p = 0; p < 16; ++p) {
        int e = p * 256 + tid;
        int uu = e >> 6, kk = e & 63;
        dst[(size_t)(u0 + uu) * Kdim + k0 + kk] = f2bf(tile[kk][uu]);
    }
}

// ---------------------------------------------------------------------------
// K3: transpose w1 / skip_w (16512 x 512 fp32) -> bf16 [512][16512]
// ---------------------------------------------------------------------------
__global__ __launch_bounds__(256) void k_wt2(const float* __restrict__ w1,
                                             const float* __restrict__ gsw,
                                             unsigned short* __restrict__ W1t,
                                             unsigned short* __restrict__ Wst) {
    int kt = blockIdx.x, ut = blockIdx.y, mat = blockIdx.z;
    const float* src = mat ? gsw : w1;
    unsigned short* dst = mat ? Wst : W1t;
    __shared__ float tile[64][65];
    int tid = threadIdx.x;
    int k0 = kt * 64, u0 = ut * 64;
#pragma unroll
    for (int p = 0; p < 16; ++p) {
        int e = p * 256 + tid;
        int kk = e >> 6, uu = e & 63;
        tile[kk][uu] = src[(size_t)(k0 + kk) * UU + u0 + uu];
    }
    __syncthreads();
#pragma unroll
    for (int p = 0; p < 16; ++p) {
        int e = p * 256 + tid;
        int uu = e >> 6, kk = e & 63;
        dst[(size_t)(u0 + uu) * K3 + k0 + kk] = f2bf(tile[kk][uu]);
    }
}

// ---------------------------------------------------------------------------
// K4a: a/d prep for signature GEMM.
// a_t = 0.5(w_t + w_{t+1}) - w_0, d_t = w_{t+1} - w_t  (fp32), transposed to
// bf16 aT/dT [b][f][512] (t=511 zero).  grid (8 ttile, 2 ftile, 64 b) x 256.
// ---------------------------------------------------------------------------
__global__ __launch_bounds__(256) void k_adprep(const float* __restrict__ inp,
                                                const float* __restrict__ tk,
                                                unsigned short* __restrict__ aT,
                                                unsigned short* __restrict__ dT) {
    int tt0 = blockIdx.x * 64, f0 = blockIdx.y * 64, b = blockIdx.z;
    __shared__ float aS[64][65], dS[64][65];
    __shared__ float tkS[65];
    int tid = threadIdx.x;
    if (tid < 65) { int t = tt0 + tid; tkS[tid] = (t < SS) ? tk[t] : 0.f; }
    __syncthreads();
    const float* ib = inp + (size_t)b * SS * FF;
    float tk0 = tk[0];
    for (int e = tid; e < 64 * 64; e += 256) {
        int tt = e >> 6, ff = e & 63;
        int t = tt0 + tt;
        int f = f0 + ff;
        float av = 0.f, dv = 0.f;
        if (t < SS - 1) {
            float wa = tkS[tt] * ib[(size_t)t * FF + f];
            float wn = tkS[tt + 1] * ib[(size_t)(t + 1) * FF + f];
            float w0 = tk0 * ib[f];
            av = 0.5f * (wa + wn) - w0;
            dv = wn - wa;
        }
        aS[tt][ff] = av; dS[tt][ff] = dv;
    }
    __syncthreads();
    for (int e = tid; e < 64 * 64; e += 256) {
        int ff = e >> 6, tt = e & 63;
        size_t o = ((size_t)b * FF + f0 + ff) * SS + tt0 + tt;
        aT[o] = f2bf(aS[tt][ff]);
        dT[o] = f2bf(dS[tt][ff]);
    }
}

// ---------------------------------------------------------------------------
// K4b: signature MFMA GEMM: s2part[kc][b] = aT[b](128x128 K-slice) . dT[b]^T
// grid (4 kc, 64 b) x 256 (4 waves, 64x64 quadrant each).  Direct global
// fragment loads, no LDS, no barriers.
// ---------------------------------------------------------------------------
__global__ __launch_bounds__(256) void k_sig_mfma(const unsigned short* __restrict__ aT,
                                                  const unsigned short* __restrict__ dT,
                                                  float* __restrict__ s2part) {
    int kc = blockIdx.x, b = blockIdx.y;
    int tid = threadIdx.x, lane = tid & 63;
    int wv = __builtin_amdgcn_readfirstlane(tid >> 6);
    int wrow = (wv & 1) * 64, wcol = (wv >> 1) * 64;
    int k0 = kc * 128;
    const unsigned short* pa = aT + ((size_t)b * FF + wrow + (lane & 15)) * SS + k0 + (lane >> 4) * 8;
    const unsigned short* pd = dT + ((size_t)b * FF + wcol + (lane & 15)) * SS + k0 + (lane >> 4) * 8;
    f32x4 acc[4][4];
#pragma unroll
    for (int i = 0; i < 4; ++i)
#pragma unroll
        for (int j = 0; j < 4; ++j) acc[i][j] = (f32x4)(0.f);
#pragma unroll
    for (int t = 0; t < 4; ++t) {
        bf16x8 af[4], df[4];
#pragma unroll
        for (int rt = 0; rt < 4; ++rt) af[rt] = *(const bf16x8*)(pa + (size_t)rt * 16 * SS + t * 32);
#pragma unroll
        for (int ct = 0; ct < 4; ++ct) df[ct] = *(const bf16x8*)(pd + (size_t)ct * 16 * SS + t * 32);
#pragma unroll
        for (int rt = 0; rt < 4; ++rt)
#pragma unroll
            for (int ct = 0; ct < 4; ++ct)
                acc[rt][ct] = __builtin_amdgcn_mfma_f32_16x16x32_bf16(af[rt], df[ct], acc[rt][ct], 0, 0, 0);
    }
    float* outp = s2part + ((size_t)kc * BB + b) * (FF * FF);
    int quad = lane >> 4, col = lane & 15;
#pragma unroll
    for (int rt = 0; rt < 4; ++rt)
#pragma unroll
        for (int ct = 0; ct < 4; ++ct)
#pragma unroll
            for (int reg = 0; reg < 4; ++reg)
                outp[(wrow + rt * 16 + quad * 4 + reg) * FF + wcol + ct * 16 + col] = acc[rt][ct][reg];
}

// ---------------------------------------------------------------------------
// K5: assemble sig directly as bf16
// ---------------------------------------------------------------------------
__global__ void k_sig_reduce(const float* __restrict__ inp, const float* __restrict__ tk,
                             const float* __restrict__ s2part, unsigned short* __restrict__ sigb) {
    int idx = blockIdx.x * 256 + threadIdx.x;
    if (idx >= BB * SIGDIM) return;
    int b = idx / SIGDIM, r = idx % SIGDIM;
    float v;
    if (r < FF) {
        v = tk[SS - 1] * inp[((size_t)b * SS + SS - 1) * FF + r] - tk[0] * inp[(size_t)b * SS * FF + r];
    } else {
        int ij = r - FF;
        v = 0.f;
#pragma unroll
        for (int c = 0; c < 4; ++c) v += s2part[((size_t)c * BB + b) * (FF * FF) + ij];
    }
    sigb[idx] = f2bf(v);
}

// ---------------------------------------------------------------------------
// K6: direct single-wave MFMA: {h1,skip} = sigb[64][16512] @ {W1t,Wst}^T
// ---------------------------------------------------------------------------
__global__ __launch_bounds__(64) void k_sig_direct(const unsigned short* __restrict__ sigb,
                                                   const unsigned short* __restrict__ W1t,
                                                   const unsigned short* __restrict__ Wst,
                                                   const float* __restrict__ b1,
                                                   unsigned short* __restrict__ h1b,
                                                   float* __restrict__ skippre) {
    int lane = threadIdx.x;
    int mt = blockIdx.x, nt = blockIdx.y, mat = blockIdx.z;
    const unsigned short* Bp = mat ? Wst : W1t;
    const unsigned short* pa = sigb + (size_t)(mt * 16 + (lane & 15)) * K3 + (lane >> 4) * 8;
    const unsigned short* pb = Bp + (size_t)(nt * 16 + (lane & 15)) * K3 + (lane >> 4) * 8;
    f32x4 acc0 = (f32x4)(0.f), acc1 = (f32x4)(0.f);
#pragma unroll 8
    for (int t = 0; t < K3 / 32; t += 2) {
        bf16x8 a0 = *(const bf16x8*)(pa + t * 32);
        bf16x8 b0 = *(const bf16x8*)(pb + t * 32);
        bf16x8 a1 = *(const bf16x8*)(pa + t * 32 + 32);
        bf16x8 b1v = *(const bf16x8*)(pb + t * 32 + 32);
        acc0 = __builtin_amdgcn_mfma_f32_16x16x32_bf16(a0, b0, acc0, 0, 0, 0);
        acc1 = __builtin_amdgcn_mfma_f32_16x16x32_bf16(a1, b1v, acc1, 0, 0, 0);
    }
    int col = lane & 15, quad = lane >> 4;
    int j = nt * 16 + col;
    if (mat == 0) {
        float bb = b1[j];
#pragma unroll
        for (int reg = 0; reg < 4; ++reg) {
            int row = mt * 16 + quad * 4 + reg;
            float v = acc0[reg] + acc1[reg] + bb;
            h1b[(size_t)row * UU + j] = f2bf(v > 0.f ? v : expf(v) - 1.0f);
        }
    } else {
#pragma unroll
        for (int reg = 0; reg < 4; ++reg) {
            int row = mt * 16 + quad * 4 + reg;
            skippre[(size_t)row * UU + j] = acc0[reg] + acc1[reg];
        }
    }
}

// ---------------------------------------------------------------------------
// K7: direct h2 = h1b @ W2t^T + b2 -> bf16
// ---------------------------------------------------------------------------
__global__ __launch_bounds__(64) void k_h2_direct(const unsigned short* __restrict__ h1b,
                                                  const unsigned short* __restrict__ W2t,
                                                  const float* __restrict__ b2,
                                                  unsigned short* __restrict__ h2b) {
    int lane = threadIdx.x;
    int mt = blockIdx.x, nt = blockIdx.y;
    const unsigned short* pa = h1b + (size_t)(mt * 16 + (lane & 15)) * 512 + (lane >> 4) * 8;
    const unsigned short* pb = W2t + (size_t)(nt * 16 + (lane & 15)) * 512 + (lane >> 4) * 8;
    f32x4 acc0 = (f32x4)(0.f), acc1 = (f32x4)(0.f);
#pragma unroll
    for (int t = 0; t < 16; t += 2) {
        bf16x8 a0 = *(const bf16x8*)(pa + t * 32);
        bf16x8 b0 = *(const bf16x8*)(pb + t * 32);
        bf16x8 a1 = *(const bf16x8*)(pa + t * 32 + 32);
        bf16x8 b1v = *(const bf16x8*)(pb + t * 32 + 32);
        acc0 = __builtin_amdgcn_mfma_f32_16x16x32_bf16(a0, b0, acc0, 0, 0, 0);
        acc1 = __builtin_amdgcn_mfma_f32_16x16x32_bf16(a1, b1v, acc1, 0, 0, 0);
    }
    int col = lane & 15, quad = lane >> 4;
    int j = nt * 16 + col;
    float bb = b2[j];
#pragma unroll
    for (int reg = 0; reg < 4; ++reg) {
        int row = mt * 16 + quad * 4 + reg;
        h2b[(size_t)row * UU + j] = f2bf(acc0[reg] + acc1[reg] + bb);
    }
}

// ---------------------------------------------------------------------------
// K8: direct GLU
// ---------------------------------------------------------------------------
__global__ __launch_bounds__(64) void k_glu_direct(const unsigned short* __restrict__ h2b,
                                                   const unsigned short* __restrict__ W3t,
                                                   const unsigned short* __restrict__ W4t,
                                                   const float* __restrict__ b3,
                                                   const float* __restrict__ b4,
                                                   const float* __restrict__ skippre,
                                                   const float* __restrict__ skb,
                                                   float* __restrict__ yv) {
    int lane = threadIdx.x;
    int mt = blockIdx.x, nt = blockIdx.y;
    const unsigned short* pa = h2b + (size_t)(mt * 16 + (lane & 15)) * 512 + (lane >> 4) * 8;
    const unsigned short* pb3 = W3t + (size_t)(nt * 16 + (lane & 15)) * 512 + (lane >> 4) * 8;
    const unsigned short* pb4 = W4t + (size_t)(nt * 16 + (lane & 15)) * 512 + (lane >> 4) * 8;
    f32x4 acc3 = (f32x4)(0.f), acc4 = (f32x4)(0.f);
#pragma unroll
    for (int t = 0; t < 16; ++t) {
        bf16x8 a = *(const bf16x8*)(pa + t * 32);
        bf16x8 b3f = *(const bf16x8*)(pb3 + t * 32);
        bf16x8 b4f = *(const bf16x8*)(pb4 + t * 32);
        acc3 = __builtin_amdgcn_mfma_f32_16x16x32_bf16(a, b3f, acc3, 0, 0, 0);
        acc4 = __builtin_amdgcn_mfma_f32_16x16x32_bf16(a, b4f, acc4, 0, 0, 0);
    }
    int col = lane & 15, quad = lane >> 4;
    int j = nt * 16 + col;
    float bb3 = b3[j], bb4 = b4[j], sb = skb[j];
#pragma unroll
    for (int reg = 0; reg < 4; ++reg) {
        int row = mt * 16 + quad * 4 + reg;
        float g = sigmoidf(acc3[reg] + bb3);
        yv[(size_t)row * UU + j] = skippre[(size_t)row * UU + j] + sb + g * (acc4[reg] + bb4);
    }
}

// ---------------------------------------------------------------------------
// K9: layernorm + softmax -> attn
// ---------------------------------------------------------------------------
__device__ __forceinline__ float block_sum(float v, float* red) {
    int tid = threadIdx.x;
#pragma unroll
    for (int off = 32; off > 0; off >>= 1) v += __shfl_down(v, off);
    __syncthreads();
    if ((tid & 63) == 0) red[tid >> 6] = v;
    __syncthreads();
    float r = red[0];
#pragma unroll
    for (int i = 1; i < 8; ++i) r += red[i];
    return r;
}
__device__ __forceinline__ float block_max(float v, float* red) {
    int tid = threadIdx.x;
#pragma unroll
    for (int off = 32; off > 0; off >>= 1) v = fmaxf(v, __shfl_down(v, off));
    __syncthreads();
    if ((tid & 63) == 0) red[tid >> 6] = v;
    __syncthreads();
    float r = red[0];
#pragma unroll
    for (int i = 1; i < 8; ++i) r = fmaxf(r, red[i]);
    return r;
}

__global__ void k_lnsm(const float* __restrict__ yv, const float* __restrict__ gamma,
                       const float* __restrict__ beta, float* __restrict__ attn) {
    int b = blockIdx.x, u = threadIdx.x;
    __shared__ float red[8];
    float v = yv[(size_t)b * UU + u];
    float mu = block_sum(v, red) * (1.0f / UU);
    float d = v - mu;
    float var = block_sum(d * d, red) * (1.0f / UU);
    float z = d * rsqrtf(var + 1e-3f) * gamma[u] + beta[u];
    float m = block_max(z, red);
    float e = expf(z - m);
    float Z = block_sum(e, red);
    attn[(size_t)b * UU + u] = e / Z;
}

// ---------------------------------------------------------------------------
// K10: attn-weighted KAN-feature reduction, closed-form cubic B-spline.
// ---------------------------------------------------------------------------
__global__ __launch_bounds__(128) void k_attn_red(const float* __restrict__ inp,
                                                  const float* __restrict__ tk,
                                                  const float* __restrict__ attn,
                                                  float* __restrict__ Apart) {
    int b = blockIdx.x, ch = blockIdx.y;
    int f = threadIdx.x;
    __shared__ float attnS[16], tkS[16];
    if (f < 16) { attnS[f] = attn[(size_t)b * UU + ch * 16 + f]; tkS[f] = tk[ch * 16 + f]; }
    __syncthreads();
    const float* ib = inp + ((size_t)b * SS + ch * 16) * FF + f;
    float acc[9] = {};
#pragma unroll
    for (int s = 0; s < 16; ++s) {
        float w = tkS[s] * ib[(size_t)s * FF];
        float a = attnS[s];
        float t = (w + 2.2f) * 2.5f;
        float cf = floorf(fminf(fmaxf(t, -2.f), 13.f));
        int c = (int)cf;
        float u = t - cf;
        float u2 = u * u, u3 = u2 * u;
        float p0 = u3 * (1.f / 6.f);
        float p1 = (-3.f * u3 + 3.f * u2 + 3.f * u + 1.f) * (1.f / 6.f);
        float p2 = (3.f * u3 - 6.f * u2 + 4.f) * (1.f / 6.f);
        float onemu = 1.f - u;
        float p3 = onemu * onemu * onemu * (1.f / 6.f);
#pragma unroll
        for (int k2 = 0; k2 < 8; ++k2) {
            int d = c - k2;
            float v = (d == 0) ? p0 : (d == 1) ? p1 : (d == 2) ? p2 : (d == 3) ? p3 : 0.f;
            acc[k2] += a * v;
        }
        acc[8] += a * (w * sigmoidf(w));
    }
    float* op = Apart + ((size_t)ch * BB + b) * KK;
    float4 v0 = { acc[0], acc[1], acc[2], acc[3] };
    float4 v1 = { acc[4], acc[5], acc[6], acc[7] };
    *(float4*)(op + f * 8) = v0;
    *(float4*)(op + f * 8 + 4) = v1;
    op[1024 + f] = acc[8];
}

// ---------------------------------------------------------------------------
// K11: reduce 32 chunks, /S, -> bf16 Aredb[64][1152]
// ---------------------------------------------------------------------------
__global__ void k_ared_red(const float* __restrict__ Apart, unsigned short* __restrict__ Aredb) {
    int idx = blockIdx.x * 256 + threadIdx.x;
    if (idx >= BB * KK) return;
    int b = idx / KK, c = idx % KK;
    float s = 0.f;
#pragma unroll
    for (int ch = 0; ch < NCH; ++ch) s += Apart[((size_t)ch * BB + b) * KK + c];
    Aredb[idx] = f2bf(s * (1.0f / SS));
}

// ---------------------------------------------------------------------------
// K12: direct current = Aredb @ Wt^T -> bf16 into comb_b left half
// ---------------------------------------------------------------------------
__global__ __launch_bounds__(64) void k_cur_direct(const unsigned short* __restrict__ Aredb,
                                                   const unsigned short* __restrict__ Wt,
                                                   unsigned short* __restrict__ comb_b) {
    int lane = threadIdx.x;
    int mt = blockIdx.x, nt = blockIdx.y;
    const unsigned short* pa = Aredb + (size_t)(mt * 16 + (lane & 15)) * KK + (lane >> 4) * 8;
    const unsigned short* pb = Wt + (size_t)(nt * 16 + (lane & 15)) * KK + (lane >> 4) * 8;
    f32x4 acc0 = (f32x4)(0.f), acc1 = (f32x4)(0.f);
#pragma unroll 6
    for (int t = 0; t < KK / 32; t += 2) {
        bf16x8 a0 = *(const bf16x8*)(pa + t * 32);
        bf16x8 b0 = *(const bf16x8*)(pb + t * 32);
        bf16x8 a1 = *(const bf16x8*)(pa + t * 32 + 32);
        bf16x8 b1v = *(const bf16x8*)(pb + t * 32 + 32);
        acc0 = __builtin_amdgcn_mfma_f32_16x16x32_bf16(a0, b0, acc0, 0, 0, 0);
        acc1 = __builtin_amdgcn_mfma_f32_16x16x32_bf16(a1, b1v, acc1, 0, 0, 0);
    }
    int col = lane & 15, quad = lane >> 4;
    int j = nt * 16 + col;
#pragma unroll
    for (int reg = 0; reg < 4; ++reg) {
        int row = mt * 16 + quad * 4 + reg;
        comb_b[(size_t)row * 1024 + j] = f2bf(acc0[reg] + acc1[reg]);
    }
}

// ---------------------------------------------------------------------------
// K13: direct gates = comb_b @ Wgt^T
// ---------------------------------------------------------------------------
__global__ __launch_bounds__(64) void k_gates_direct(const unsigned short* __restrict__ comb_b,
                                                     const unsigned short* __restrict__ Wgt,
                                                     float* __restrict__ gates) {
    int lane = threadIdx.x;
    int mt = blockIdx.x, nt = blockIdx.y;
    const unsigned short* pa = comb_b + (size_t)(mt * 16 + (lane & 15)) * 1024 + (lane >> 4) * 8;
    const unsigned short* pb = Wgt + (size_t)(nt * 16 + (lane & 15)) * 1024 + (lane >> 4) * 8;
    f32x4 acc0 = (f32x4)(0.f), acc1 = (f32x4)(0.f);
#pragma unroll 8
    for (int t = 0; t < 32; t += 2) {
        bf16x8 a0 = *(const bf16x8*)(pa + t * 32);
        bf16x8 b0 = *(const bf16x8*)(pb + t * 32);
        bf16x8 a1 = *(const bf16x8*)(pa + t * 32 + 32);
        bf16x8 b1v = *(const bf16x8*)(pb + t * 32 + 32);
        acc0 = __builtin_amdgcn_mfma_f32_16x16x32_bf16(a0, b0, acc0, 0, 0, 0);
        acc1 = __builtin_amdgcn_mfma_f32_16x16x32_bf16(a1, b1v, acc1, 0, 0, 0);
    }
    int col = lane & 15, quad = lane >> 4;
    int j = nt * 16 + col;
#pragma unroll
    for (int reg = 0; reg < 4; ++reg) {
        int row = mt * 16 + quad * 4 + reg;
        gates[(size_t)row * 2048 + j] = acc0[reg] + acc1[reg];
    }
}

// ---------------------------------------------------------------------------
// K14: elementwise cell update
// ---------------------------------------------------------------------------
__global__ void k_cell(const float* __restrict__ gates,
                       const float* __restrict__ bf_, const float* __restrict__ bi_,
                       const float* __restrict__ bc_, const float* __restrict__ bo_,
                       const float* __restrict__ c_prev, float* __restrict__ out) {
    int idx = blockIdx.x * 256 + threadIdx.x;
    if (idx >= BB * UU) return;
    int b = idx >> 9, u = idx & 511;
    const float* g = gates + (size_t)b * 2048;
    float f = sigmoidf(g[u] + bf_[u]);
    float ii = sigmoidf(g[512 + u] + bi_[u]);
    float cd = tanhf(g[1024 + u] + bc_[u]);
    float o = sigmoidf(g[1536 + u] + bo_[u]);
    float cn = f * c_prev[idx] + ii * cd;
    out[idx] = o * tanhf(cn);
    out[(size_t)BB * UU + idx] = cn;
}

// ---------------------------------------------------------------------------
extern "C" void kernel_launch(void* const* d_in, const int* in_sizes, int n_in,
                              void* d_out, int out_size, void* d_ws, size_t ws_size,
                              hipStream_t stream) {
    const float* inp   = (const float*)d_in[0];
    const float* hprev = (const float*)d_in[1];
    const float* cprev = (const float*)d_in[2];
    const float* tk    = (const float*)d_in[3];
    const float* basew = (const float*)d_in[4];
    const float* splw  = (const float*)d_in[5];
    const float* gw1   = (const float*)d_in[6];
    const float* gb1   = (const float*)d_in[7];
    const float* gw2   = (const float*)d_in[8];
    const float* gb2   = (const float*)d_in[9];
    const float* gw3   = (const float*)d_in[10];
    const float* gb3   = (const float*)d_in[11];
    const float* gw4   = (const float*)d_in[12];
    const float* gb4   = (const float*)d_in[13];
    const float* gsw   = (const float*)d_in[14];
    const float* gsb   = (const float*)d_in[15];
    const float* lng   = (const float*)d_in[16];
    const float* lnb   = (const float*)d_in[17];
    const float* wf    = (const float*)d_in[18];
    const float* bf_   = (const float*)d_in[19];
    const float* wi    = (const float*)d_in[20];
    const float* bi_   = (const float*)d_in[21];
    const float* wc    = (const float*)d_in[22];
    const float* bc_   = (const float*)d_in[23];
    const float* wo    = (const float*)d_in[24];
    const float* bo_   = (const float*)d_in[25];
    float* out = (float*)d_out;

    float* ws = (float*)d_ws;
    size_t o = 0;
    unsigned short* W1t = (unsigned short*)(ws + o); o += (size_t)UU * K3 / 2;   // 16.9 MB
    unsigned short* Wst = (unsigned short*)(ws + o); o += (size_t)UU * K3 / 2;   // 16.9 MB
    unsigned short* Wt  = (unsigned short*)(ws + o); o += (size_t)UU * KK / 2;
    float* s2part   = ws + o; o += (size_t)4 * BB * FF * FF;                     // 16.78 MB
    unsigned short* aT = (unsigned short*)(ws + o); o += (size_t)BB * FF * SS / 2;  // 8.4 MB
    unsigned short* dT = (unsigned short*)(ws + o); o += (size_t)BB * FF * SS / 2;  // 8.4 MB
    unsigned short* sigb = (unsigned short*)(ws + o); o += (size_t)BB * K3 / 2;
    float* skippre  = ws + o; o += (size_t)BB * UU;
    unsigned short* h1b = (unsigned short*)(ws + o); o += (size_t)BB * UU / 2;
    unsigned short* h2b = (unsigned short*)(ws + o); o += (size_t)BB * UU / 2;
    float* yv       = ws + o; o += (size_t)BB * UU;
    float* attn     = ws + o; o += (size_t)BB * UU;
    float* Apart    = ws + o; o += (size_t)NCH * BB * KK;                        // 9.4 MB
    unsigned short* Aredb = (unsigned short*)(ws + o); o += (size_t)BB * KK / 2;
    unsigned short* W2t = (unsigned short*)(ws + o); o += (size_t)512 * 512 / 2;
    unsigned short* W3t = (unsigned short*)(ws + o); o += (size_t)512 * 512 / 2;
    unsigned short* W4t = (unsigned short*)(ws + o); o += (size_t)512 * 512 / 2;
    unsigned short* Wgt = (unsigned short*)(ws + o); o += (size_t)2048 * 1024 / 2;
    unsigned short* comb_b = (unsigned short*)(ws + o); o += (size_t)BB * 1024 / 2;
    float* gates    = ws + o; o += (size_t)BB * 2048;
    (void)ws_size; (void)in_sizes; (void)n_in; (void)out_size;

    k_wprep<<<(UU * KK + 255) / 256, 256, 0, stream>>>(splw, basew, hprev, Wt, comb_b);
    k_wt3<<<dim3(16, 8, 7), 256, 0, stream>>>(gw2, gw3, gw4, wf, wi, wc, wo, W2t, W3t, W4t, Wgt);
    k_wt2<<<dim3(K3 / 64, UU / 64, 2), 256, 0, stream>>>(gw1, gsw, W1t, Wst);
    k_adprep<<<dim3(8, 2, BB), 256, 0, stream>>>(inp, tk, aT, dT);
    k_sig_mfma<<<dim3(4, BB), 256, 0, stream>>>(aT, dT, s2part);
    k_sig_reduce<<<(BB * SIGDIM + 255) / 256, 256, 0, stream>>>(inp, tk, s2part, sigb);
    k_sig_direct<<<dim3(4, 32, 2), 64, 0, stream>>>(sigb, W1t, Wst, gb1, h1b, skippre);
    k_h2_direct<<<dim3(4, 32), 64, 0, stream>>>(h1b, W2t, gb2, h2b);
    k_glu_direct<<<dim3(4, 32), 64, 0, stream>>>(h2b, W3t, W4t, gb3, gb4, skippre, gsb, yv);
    k_lnsm<<<BB, UU, 0, stream>>>(yv, lng, lnb, attn);
    k_attn_red<<<dim3(BB, NCH), 128, 0, stream>>>(inp, tk, attn, Apart);
    k_ared_red<<<(BB * KK + 255) / 256, 256, 0, stream>>>(Apart, Aredb);
    k_cur_direct<<<dim3(4, 32), 64, 0, stream>>>(Aredb, Wt, comb_b);
    k_gates_direct<<<dim3(4, 128), 64, 0, stream>>>(comb_b, Wgt, gates);
    k_cell<<<(BB * UU + 255) / 256, 256, 0, stream>>>(gates, bf_, bi_, bc_, bo_, cprev, out);
}